// Round 2
// baseline (280.027 us; speedup 1.0000x reference)
//
#include <hip/hip_runtime.h>
#include <math.h>

// Problem constants (B=8, N=2048, D_IN=D_V=256, H=8, HD=32, D_FF=512)
#define RTOT 16384   // B*N rows
#define NSEQ 2048
#define NHEAD 8
#define HDIM 32
// Q pre-scale: log2(e)/sqrt(256) so S_mfma = S_true*log2e, softmax via exp2
#define QSCALE 0.09017132252479462f
#define QINV (1.0f / QSCALE)

typedef __attribute__((ext_vector_type(8))) short short8;
typedef __attribute__((ext_vector_type(4))) float f32x4;
typedef __attribute__((ext_vector_type(4))) unsigned uint4v;

#define GLOBAL_AS(p) ((__attribute__((address_space(1))) void*)(p))
#define LDS_AS(p) ((__attribute__((address_space(3))) void*)(p))

__device__ __forceinline__ unsigned pack_bf16(float a, float b) {
  unsigned ua = __float_as_uint(a) + 0x8000u;
  unsigned ub = __float_as_uint(b) + 0x8000u;
  return (ua >> 16) | (ub & 0xffff0000u);
}
// truncating pack via byte-perm (positive values; bias cancels in softmax ratio)
// result = [a.b2,a.b3,b.b2,b.b3] : low16 = bf16(a), high16 = bf16(b)
__device__ __forceinline__ unsigned pack_bf16_perm(float a, float b) {
  return __builtin_amdgcn_perm(__float_as_uint(b), __float_as_uint(a),
                               0x07060302u);
}
__device__ __forceinline__ ushort bf16_1(float a) {
  return (ushort)((__float_as_uint(a) + 0x8000u) >> 16);
}
__device__ __forceinline__ float bf16_to_f(ushort u) {
  return __uint_as_float(((unsigned)u) << 16);
}
__device__ __forceinline__ short8 frag4(unsigned a0, unsigned a1, unsigned a2,
                                        unsigned a3) {
  uint4v t = {a0, a1, a2, a3};
  return __builtin_bit_cast(short8, t);
}

// ---------------- stage0: fused weight-transpose + cvt(y) + ln0(x) ----------------
// blocks [0,112): weight transpose; [112,4208): y->bf16; [4208,8304): LN0(x)->bf16
__global__ __launch_bounds__(256) void stage0_kernel(
    const float* __restrict__ x, const float* __restrict__ y,
    const float* __restrict__ Wq, const float* __restrict__ Wk,
    const float* __restrict__ Wv, const float* __restrict__ W1,
    const float* __restrict__ W2, const float* __restrict__ ln0g,
    const float* __restrict__ ln0b, ushort* __restrict__ Wqt,
    ushort* __restrict__ Wkt, ushort* __restrict__ Wvt,
    ushort* __restrict__ W1t, ushort* __restrict__ W2t,
    ushort* __restrict__ yh, ushort* __restrict__ xh) {
  const int bid = blockIdx.x;
  const int t = threadIdx.x;
  if (bid < 112) {
    const float* W;
    ushort* Wt;
    int K, N, tile;
    if (bid < 16) { W = Wq; Wt = Wqt; K = 256; N = 256; tile = bid; }
    else if (bid < 32) { W = Wk; Wt = Wkt; K = 256; N = 256; tile = bid - 16; }
    else if (bid < 48) { W = Wv; Wt = Wvt; K = 256; N = 256; tile = bid - 32; }
    else if (bid < 80) { W = W1; Wt = W1t; K = 256; N = 512; tile = bid - 48; }
    else { W = W2; Wt = W2t; K = 512; N = 256; tile = bid - 80; }
    const int tn = N >> 6;
    const int k0 = (tile / tn) << 6, n0 = (tile % tn) << 6;
    __shared__ float T[64][65];
#pragma unroll
    for (int i = 0; i < 16; ++i) {
      const int idx = t + i * 256;
      const int r = idx >> 6, c = idx & 63;
      T[r][c] = W[(size_t)(k0 + r) * N + n0 + c];
    }
    __syncthreads();
#pragma unroll
    for (int i = 0; i < 16; ++i) {
      const int idx = t + i * 256;
      const int r = idx >> 6, c = idx & 63;
      Wt[(size_t)(n0 + r) * K + k0 + c] = bf16_1(T[c][r]);
    }
  } else if (bid < 4208) {
    const size_t i = ((size_t)(bid - 112) * 256 + t) * 4;
    const float4 v = *(const float4*)&y[i];
    uint2 pk;
    pk.x = pack_bf16(v.x, v.y);
    pk.y = pack_bf16(v.z, v.w);
    *(uint2*)&yh[i] = pk;
  } else {
    const int lane = t & 63, wave = t >> 6;
    const size_t row = (size_t)(bid - 4208) * 4 + wave;
    const float* xr = x + row * 256;
    float4 v = *(const float4*)&xr[lane * 4];
    float s = v.x + v.y + v.z + v.w;
#pragma unroll
    for (int m = 1; m < 64; m <<= 1) s += __shfl_xor(s, m, 64);
    const float mu = s * (1.0f / 256.0f);
    const float dx = v.x - mu, dy = v.y - mu, dz = v.z - mu, dw = v.w - mu;
    float ss = dx * dx + dy * dy + dz * dz + dw * dw;
#pragma unroll
    for (int m = 1; m < 64; m <<= 1) ss += __shfl_xor(ss, m, 64);
    const float rstd = rsqrtf(ss * (1.0f / 256.0f) + 1e-5f);
    const float4 gv = *(const float4*)&ln0g[lane * 4];
    const float4 bv = *(const float4*)&ln0b[lane * 4];
    uint2 pk;
    pk.x = pack_bf16(dx * rstd * gv.x + bv.x, dy * rstd * gv.y + bv.y);
    pk.y = pack_bf16(dz * rstd * gv.z + bv.z, dw * rstd * gv.w + bv.w);
    *(uint2*)&xh[row * 256 + lane * 4] = pk;
  }
}

// ---------------- LayerNorm over D=256, bf16 output ----------------
__global__ __launch_bounds__(256) void ln_kernel(
    const float* __restrict__ X, const float* __restrict__ g,
    const float* __restrict__ bt, ushort* __restrict__ Yh) {
  const int lane = threadIdx.x & 63;
  const int wave = threadIdx.x >> 6;
  const size_t row = (size_t)blockIdx.x * 4 + wave;
  const float* xr = X + row * 256;
  float4 v = *(const float4*)&xr[lane * 4];
  float s = v.x + v.y + v.z + v.w;
#pragma unroll
  for (int m = 1; m < 64; m <<= 1) s += __shfl_xor(s, m, 64);
  const float mu = s * (1.0f / 256.0f);
  const float dx = v.x - mu, dy = v.y - mu, dz = v.z - mu, dw = v.w - mu;
  float ss = dx * dx + dy * dy + dz * dz + dw * dw;
#pragma unroll
  for (int m = 1; m < 64; m <<= 1) ss += __shfl_xor(ss, m, 64);
  const float rstd = rsqrtf(ss * (1.0f / 256.0f) + 1e-5f);
  const float4 gv = *(const float4*)&g[lane * 4];
  const float4 bv = *(const float4*)&bt[lane * 4];
  uint2 pk;
  pk.x = pack_bf16(dx * rstd * gv.x + bv.x, dy * rstd * gv.y + bv.y);
  pk.y = pack_bf16(dz * rstd * gv.z + bv.z, dw * rstd * gv.w + bv.w);
  *(uint2*)&Yh[row * 256 + lane * 4] = pk;
}

// ---------------- merged QKV GEMM ----------------
// grid (128, 12): ny>>2 = 0:K 1:V 2:Q ; 128x64 tile, BK=32, 4 waves.
// K: Kh=bf16(v) ; Q: Qh=bf16(v*QSCALE) ; V: transpose -> VhT[b*256+n][nseq]
__global__ __launch_bounds__(256) void qkv_kernel(
    const ushort* __restrict__ xh, const ushort* __restrict__ yh,
    const ushort* __restrict__ Wqt, const ushort* __restrict__ Wkt,
    const ushort* __restrict__ Wvt, const float* __restrict__ bq,
    const float* __restrict__ bk, const float* __restrict__ bv,
    ushort* __restrict__ Qh, ushort* __restrict__ Kh,
    ushort* __restrict__ VhT) {
  __shared__ union UU {
    struct { ushort As[128 * 32]; ushort Bs[64 * 32]; } s;
    ushort Ct[64 * 136];  // V-transpose tile [n_local][m_local]
  } u;
  const int t = threadIdx.x;
  const int lane = t & 63, wave = t >> 6;
  const int l16 = lane & 15, quad = lane >> 4;
  const int row0 = blockIdx.x * 128;
  const int ny = blockIdx.y;
  const int which = ny >> 2;  // 0=K 1=V 2=Q
  const int n0 = (ny & 3) << 6;
  const ushort* A = (which == 2) ? xh : yh;
  const ushort* W = (which == 0) ? Wkt : (which == 1) ? Wvt : Wqt;
  const float* bs = (which == 0) ? bk : (which == 1) ? bv : bq;
  const int mrow = (wave & 1) * 64, ncol = (wave >> 1) * 32;

  const ushort* gA0 = A + (size_t)(row0 + (t >> 2)) * 256 + ((t & 3) << 3);
  const ushort* gA1 = gA0 + (size_t)64 * 256;
  const ushort* gB = W + (size_t)(n0 + (t >> 2)) * 256 + ((t & 3) << 3);
  ushort* lA0 = u.s.As + 8 * t;
  ushort* lA1 = u.s.As + 2048 + 8 * t;
  ushort* lB = u.s.Bs + 8 * t;

  f32x4 acc[4][2] = {};
  for (int kc = 0; kc < 256; kc += 32) {
    __builtin_amdgcn_global_load_lds(GLOBAL_AS(gA0 + kc), LDS_AS(lA0), 16, 0, 0);
    __builtin_amdgcn_global_load_lds(GLOBAL_AS(gA1 + kc), LDS_AS(lA1), 16, 0, 0);
    __builtin_amdgcn_global_load_lds(GLOBAL_AS(gB + kc), LDS_AS(lB), 16, 0, 0);
    __syncthreads();
    short8 af[4], bfr[2];
#pragma unroll
    for (int mi = 0; mi < 4; ++mi)
      af[mi] = *(const short8*)&u.s.As[(mrow + mi * 16 + l16) * 32 + quad * 8];
#pragma unroll
    for (int nj = 0; nj < 2; ++nj)
      bfr[nj] = *(const short8*)&u.s.Bs[(ncol + nj * 16 + l16) * 32 + quad * 8];
#pragma unroll
    for (int mi = 0; mi < 4; ++mi)
#pragma unroll
      for (int nj = 0; nj < 2; ++nj)
        acc[mi][nj] = __builtin_amdgcn_mfma_f32_16x16x32_bf16(
            af[mi], bfr[nj], acc[mi][nj], 0, 0, 0);
    __syncthreads();
  }

  if (which == 1) {
    // V: bias + transpose via LDS, coalesced write to VhT[b*256+n][nseq]
#pragma unroll
    for (int nj = 0; nj < 2; ++nj) {
      const int nloc = ncol + nj * 16 + l16;
      const float bvv = bs[n0 + nloc];
#pragma unroll
      for (int mi = 0; mi < 4; ++mi)
#pragma unroll
        for (int r = 0; r < 4; ++r)
          u.Ct[nloc * 136 + mrow + mi * 16 + quad * 4 + r] =
              bf16_1(acc[mi][nj][r] + bvv);
    }
    __syncthreads();
    const int bb = row0 >> 11, ns0 = row0 & 2047;
#pragma unroll
    for (int i = 0; i < 4; ++i) {
      const int c = t + i * 256;
      const int rr = c >> 4, c8 = (c & 15) << 3;
      *(float4*)&VhT[(size_t)(bb * 256 + n0 + rr) * 2048 + ns0 + c8] =
          *(const float4*)&u.Ct[rr * 136 + c8];
    }
  } else {
#pragma unroll
    for (int nj = 0; nj < 2; ++nj) {
      const int n = n0 + ncol + nj * 16 + l16;
      const float bvv = bs[n];
#pragma unroll
      for (int mi = 0; mi < 4; ++mi) {
#pragma unroll
        for (int r = 0; r < 4; ++r) {
          const size_t m = (size_t)row0 + mrow + mi * 16 + quad * 4 + r;
          const float v = acc[mi][nj][r] + bvv;
          if (which == 2) Qh[m * 256 + n] = bf16_1(v * QSCALE);
          else Kh[m * 256 + n] = bf16_1(v);
        }
      }
    }
  }
}

// ---------------- FFN GEMM: 128x64 tile, BK=32 ----------------
// MODE 2: Ch=bf16(gelu(v)) (FFN1) ; MODE 3: Cf=v+res (FFN2 -> out)
template <int MODE>
__global__ __launch_bounds__(256) void mgemm_kernel(
    const ushort* __restrict__ A, const ushort* __restrict__ Wt,
    const float* __restrict__ bias, const float* __restrict__ res,
    float* __restrict__ Cf, ushort* __restrict__ Ch, int K, int N) {
  __shared__ ushort As[128 * 32];
  __shared__ ushort Bs[64 * 32];
  const int t = threadIdx.x;
  const int lane = t & 63, wave = t >> 6;
  const int l16 = lane & 15, quad = lane >> 4;
  const int row0 = blockIdx.x * 128;
  const int n0 = blockIdx.y << 6;
  const int mrow = (wave & 1) * 64, ncol = (wave >> 1) * 32;

  const ushort* gA0 = A + (size_t)(row0 + (t >> 2)) * K + ((t & 3) << 3);
  const ushort* gA1 = gA0 + (size_t)64 * K;
  const ushort* gB = Wt + (size_t)(n0 + (t >> 2)) * K + ((t & 3) << 3);
  ushort* lA0 = As + 8 * t;
  ushort* lA1 = As + 2048 + 8 * t;
  ushort* lB = Bs + 8 * t;

  f32x4 acc[4][2] = {};
  for (int kc = 0; kc < K; kc += 32) {
    __builtin_amdgcn_global_load_lds(GLOBAL_AS(gA0 + kc), LDS_AS(lA0), 16, 0, 0);
    __builtin_amdgcn_global_load_lds(GLOBAL_AS(gA1 + kc), LDS_AS(lA1), 16, 0, 0);
    __builtin_amdgcn_global_load_lds(GLOBAL_AS(gB + kc), LDS_AS(lB), 16, 0, 0);
    __syncthreads();
    short8 af[4], bfr[2];
#pragma unroll
    for (int mi = 0; mi < 4; ++mi)
      af[mi] = *(const short8*)&As[(mrow + mi * 16 + l16) * 32 + quad * 8];
#pragma unroll
    for (int nj = 0; nj < 2; ++nj)
      bfr[nj] = *(const short8*)&Bs[(ncol + nj * 16 + l16) * 32 + quad * 8];
#pragma unroll
    for (int mi = 0; mi < 4; ++mi)
#pragma unroll
      for (int nj = 0; nj < 2; ++nj)
        acc[mi][nj] = __builtin_amdgcn_mfma_f32_16x16x32_bf16(
            af[mi], bfr[nj], acc[mi][nj], 0, 0, 0);
    __syncthreads();
  }
#pragma unroll
  for (int nj = 0; nj < 2; ++nj) {
    const int n = n0 + ncol + nj * 16 + l16;
    const float bvv = bias[n];
#pragma unroll
    for (int mi = 0; mi < 4; ++mi) {
#pragma unroll
      for (int r = 0; r < 4; ++r) {
        const size_t m = (size_t)row0 + mrow + mi * 16 + quad * 4 + r;
        float v = acc[mi][nj][r] + bvv;
        if (MODE == 2) {
          v = 0.5f * v * (1.0f + erff(v * 0.70710678118654752f));
          Ch[m * N + n] = bf16_1(v);
        }
        if (MODE == 3) Cf[m * N + n] = v + res[m * N + n];
      }
    }
  }
}

// ---------------- Flash attention (bf16 MFMA, zero-max, barrier-free) ----------
// O = Q + softmax(Q K^T / 16) V.  Qh pre-scaled by log2(e)/16 (bf16); residual
// recovered as Qh/QSCALE. No max shift (p = exp2(S*log2e), ratio-invariant);
// l via ones-MFMA.
// 1-wave blocks, ZERO LDS, ZERO barriers: K/V per (b,h) is 256KB and all 64
// q-blocks of a bh share an XCD (bh = idx&63 -> stride-64 same-XCD) => K/V is
// L2-resident; MFMA fragments are loaded DIRECTLY from global (each wave-instr
// reads 16 full 64B lines, perfect utilization). K-row bits 2<=>3 swizzle is
// folded into the per-lane base address (identical data placement as the LDS
// version, so the permlane32-only P routing is unchanged). kf double-buffered
// across kt; vf issued at body top so exp2/pack covers L2 latency.
__global__ __launch_bounds__(64, 4) void attn_kernel(
    const ushort* __restrict__ Qh, const ushort* __restrict__ Kh,
    const ushort* __restrict__ VhT, float* __restrict__ O) {
  const int lane = threadIdx.x & 63;
  const int l16 = lane & 15, quad = lane >> 4;
  const int bh = blockIdx.x & 63;
  const int wq = blockIdx.x >> 6;  // 0..63, 32 q rows each
  const int b = bh >> 3, h = bh & 7;

  const size_t rowQ0 = (size_t)(b * NSEQ + wq * 32 + l16);
  const short8 qfrag0 = *(const short8*)&Qh[rowQ0 * 256 + h * HDIM + quad * 8];
  const short8 qfrag1 =
      *(const short8*)&Qh[(rowQ0 + 16) * 256 + h * HDIM + quad * 8];
  const short8 ones = {16256, 16256, 16256, 16256,
                       16256, 16256, 16256, 16256};  // bf16 1.0 x8
  const f32x4 zf = {0.f, 0.f, 0.f, 0.f};

  f32x4 o00 = zf, o01 = zf, o10 = zf, o11 = zf;
  f32x4 s0 = zf, s1 = zf;

  // per-lane K fragment base with row bits 2<=>3 swizzle (self-inverse):
  // kf[sub] lane(l16,quad) = Kh[b*NSEQ + kt*64 + sub*16 + swz(l16)][h*32+quad*8..]
  const int swz = (l16 & 3) | ((l16 & 4) << 1) | ((l16 & 8) >> 1);
  const ushort* gK = Kh + ((size_t)b * NSEQ + swz) * 256 + h * HDIM + quad * 8;
  // V fragment base: vf(rs,ch) = VhT[bh*32 + rs*16 + l16][kt*64 + ch*32 + quad*8..]
  const ushort* gV = VhT + ((size_t)(bh * 32 + l16)) * 2048 + quad * 8;

  short8 kfA[4], kfB[4];
#pragma unroll
  for (int s = 0; s < 4; ++s)
    kfA[s] = *(const short8*)(gK + (size_t)(s * 16) * 256);

  auto body = [&](short8* kfc, short8* kfn, int ktc) {
    // vf loads for this kt (latency covered by S-MFMA + exp2 phase)
    const ushort* gv = gV + ktc * 64;
    const short8 vf00 = *(const short8*)(gv);
    const short8 vf01 = *(const short8*)(gv + 32);
    const short8 vf10 = *(const short8*)(gv + 16 * 2048);
    const short8 vf11 = *(const short8*)(gv + 16 * 2048 + 32);
    // kf prefetch for kt+1 (one full body of cover; last issue reads
    // past-K garbage that is mapped workspace and never used)
    const ushort* gk = gK + (size_t)(ktc + 1) * 64 * 256;
#pragma unroll
    for (int s = 0; s < 4; ++s)
      kfn[s] = *(const short8*)(gk + (size_t)(s * 16) * 256);

    // ---- S-MFMAs for BOTH groups ----
    f32x4 sa0[4], sa1[4];
#pragma unroll
    for (int s = 0; s < 4; ++s)
      sa0[s] =
          __builtin_amdgcn_mfma_f32_16x16x32_bf16(kfc[s], qfrag0, zf, 0, 0, 0);
#pragma unroll
    for (int s = 0; s < 4; ++s)
      sa1[s] =
          __builtin_amdgcn_mfma_f32_16x16x32_bf16(kfc[s], qfrag1, zf, 0, 0, 0);

    // ---- exp2 + pack + in-register route (permlane32 swap) ----
    unsigned p0[4][2], p1[4][2];
#pragma unroll
    for (int s = 0; s < 4; ++s) {
      p0[s][0] = pack_bf16_perm(__builtin_amdgcn_exp2f(sa0[s][0]),
                                __builtin_amdgcn_exp2f(sa0[s][1]));
      p0[s][1] = pack_bf16_perm(__builtin_amdgcn_exp2f(sa0[s][2]),
                                __builtin_amdgcn_exp2f(sa0[s][3]));
    }
#pragma unroll
    for (int s = 0; s < 4; ++s) {
      p1[s][0] = pack_bf16_perm(__builtin_amdgcn_exp2f(sa1[s][0]),
                                __builtin_amdgcn_exp2f(sa1[s][1]));
      p1[s][1] = pack_bf16_perm(__builtin_amdgcn_exp2f(sa1[s][2]),
                                __builtin_amdgcn_exp2f(sa1[s][3]));
    }
    unsigned u00 = p0[0][0], w00 = p0[1][0];
    asm("v_permlane32_swap_b32 %0, %1" : "+v"(u00), "+v"(w00));
    unsigned u01 = p0[0][1], w01 = p0[1][1];
    asm("v_permlane32_swap_b32 %0, %1" : "+v"(u01), "+v"(w01));
    unsigned u02 = p0[2][0], w02 = p0[3][0];
    asm("v_permlane32_swap_b32 %0, %1" : "+v"(u02), "+v"(w02));
    unsigned u03 = p0[2][1], w03 = p0[3][1];
    asm("v_permlane32_swap_b32 %0, %1" : "+v"(u03), "+v"(w03));
    const short8 pf00 = frag4(u00, u01, w00, w01);
    const short8 pf01 = frag4(u02, u03, w02, w03);

    unsigned u10 = p1[0][0], w10 = p1[1][0];
    asm("v_permlane32_swap_b32 %0, %1" : "+v"(u10), "+v"(w10));
    unsigned u11 = p1[0][1], w11 = p1[1][1];
    asm("v_permlane32_swap_b32 %0, %1" : "+v"(u11), "+v"(w11));
    unsigned u12 = p1[2][0], w12 = p1[3][0];
    asm("v_permlane32_swap_b32 %0, %1" : "+v"(u12), "+v"(w12));
    unsigned u13 = p1[2][1], w13 = p1[3][1];
    asm("v_permlane32_swap_b32 %0, %1" : "+v"(u13), "+v"(w13));
    const short8 pf10 = frag4(u10, u11, w10, w11);
    const short8 pf11 = frag4(u12, u13, w12, w13);

    // ---- PV + row-sum MFMAs, both groups ----
    o00 = __builtin_amdgcn_mfma_f32_16x16x32_bf16(pf00, vf00, o00, 0, 0, 0);
    o00 = __builtin_amdgcn_mfma_f32_16x16x32_bf16(pf01, vf01, o00, 0, 0, 0);
    o01 = __builtin_amdgcn_mfma_f32_16x16x32_bf16(pf00, vf10, o01, 0, 0, 0);
    o01 = __builtin_amdgcn_mfma_f32_16x16x32_bf16(pf01, vf11, o01, 0, 0, 0);
    o10 = __builtin_amdgcn_mfma_f32_16x16x32_bf16(pf10, vf00, o10, 0, 0, 0);
    o10 = __builtin_amdgcn_mfma_f32_16x16x32_bf16(pf11, vf01, o10, 0, 0, 0);
    o11 = __builtin_amdgcn_mfma_f32_16x16x32_bf16(pf10, vf10, o11, 0, 0, 0);
    o11 = __builtin_amdgcn_mfma_f32_16x16x32_bf16(pf11, vf11, o11, 0, 0, 0);
    s0 = __builtin_amdgcn_mfma_f32_16x16x32_bf16(pf00, ones, s0, 0, 0, 0);
    s0 = __builtin_amdgcn_mfma_f32_16x16x32_bf16(pf01, ones, s0, 0, 0, 0);
    s1 = __builtin_amdgcn_mfma_f32_16x16x32_bf16(pf10, ones, s1, 0, 0, 0);
    s1 = __builtin_amdgcn_mfma_f32_16x16x32_bf16(pf11, ones, s1, 0, 0, 0);
  };

  for (int kt = 0; kt < 32; kt += 2) {
    body(kfA, kfB, kt);
    body(kfB, kfA, kt + 1);
  }

  // ---- epilogue: O = Q + oacc/l ; Q re-read directly (L2-hot) ----
#pragma unroll
  for (int g = 0; g < 2; ++g) {
    const f32x4 oS = g ? s1 : s0;
    const f32x4 oa = g ? o10 : o00;
    const f32x4 ob = g ? o11 : o01;
    const size_t row0 = (size_t)(b * NSEQ + wq * 32 + g * 16 + quad * 4);
#pragma unroll
    for (int r = 0; r < 4; ++r) {
      const float il = 1.0f / oS[r];
      const size_t ro = (row0 + r) * 256 + h * HDIM + l16;
      O[ro] = bf16_to_f(Qh[ro]) * QINV + oa[r] * il;
      O[ro + 16] = bf16_to_f(Qh[ro + 16]) * QINV + ob[r] * il;
    }
  }
}

extern "C" void kernel_launch(void* const* d_in, const int* in_sizes, int n_in,
                              void* d_out, int out_size, void* d_ws, size_t ws_size,
                              hipStream_t stream) {
  const float* x = (const float*)d_in[0];
  const float* y = (const float*)d_in[1];
  const float* Wq = (const float*)d_in[2];
  const float* bq = (const float*)d_in[3];
  const float* Wk = (const float*)d_in[4];
  const float* bk = (const float*)d_in[5];
  const float* Wv = (const float*)d_in[6];
  const float* bv = (const float*)d_in[7];
  const float* W1 = (const float*)d_in[8];
  const float* b1 = (const float*)d_in[9];
  const float* W2 = (const float*)d_in[10];
  const float* b2 = (const float*)d_in[11];
  const float* ln0g = (const float*)d_in[12];
  const float* ln0b = (const float*)d_in[13];
  const float* ln1g = (const float*)d_in[14];
  const float* ln1b = (const float*)d_in[15];
  float* out = (float*)d_out;
  char* base = (char*)d_ws;

  const size_t RM = (size_t)RTOT * 256;
  // region0: yh (bf16, stage0->qkv) then overwritten by Ob (fp32, attn out)
  ushort* yh = (ushort*)base;
  float* Ob = (float*)base;
  ushort* Qh = (ushort*)(base + 2 * RM * 4);
  ushort* Kh = (ushort*)(base + 2 * RM * 4 + RM * 2);
  ushort* VhT = (ushort*)(base + 3 * RM * 4);
  ushort* xh = (ushort*)(base + 3 * RM * 4 + RM * 2);  // LN0 out; reused as On
  ushort* Onh = xh;
  ushort* Hidh = Qh;  // [R,512] bf16 overlays Qh+Kh (dead after attn)
  char* wbase = base + 4 * RM * 4;
  ushort* Wqt = (ushort*)wbase;  // [256,256]
  ushort* Wkt = Wqt + 65536;
  ushort* Wvt = Wkt + 65536;
  ushort* W1t = Wvt + 65536;   // [512,256]
  ushort* W2t = W1t + 131072;  // [256,512]

  stage0_kernel<<<8304, 256, 0, stream>>>(x, y, Wq, Wk, Wv, W1, W2, ln0g, ln0b,
                                          Wqt, Wkt, Wvt, W1t, W2t, yh, xh);
  qkv_kernel<<<dim3(128, 12), 256, 0, stream>>>(xh, yh, Wqt, Wkt, Wvt, bq, bk,
                                                bv, Qh, Kh, VhT);
  attn_kernel<<<4096, 64, 0, stream>>>(Qh, Kh, VhT, Ob);
  ln_kernel<<<RTOT / 4, 256, 0, stream>>>(Ob, ln1g, ln1b, Onh);
  mgemm_kernel<2><<<dim3(128, 8), 256, 0, stream>>>(Onh, W1t, b1, nullptr,
                                                    nullptr, Hidh, 256, 512);
  mgemm_kernel<3><<<dim3(128, 4), 256, 0, stream>>>(Hidh, W2t, b2, Ob, out,
                                                    nullptr, 512, 256);
}

// Round 4
// 249.342 us; speedup vs baseline: 1.1231x; 1.1231x over previous
//
#include <hip/hip_runtime.h>
#include <math.h>

// Problem constants (B=8, N=2048, D_IN=D_V=256, H=8, HD=32, D_FF=512)
#define RTOT 16384   // B*N rows
#define NSEQ 2048
#define NHEAD 8
#define HDIM 32
// Q pre-scale: log2(e)/sqrt(256) so S_mfma = S_true*log2e, softmax via exp2
#define QSCALE 0.09017132252479462f
#define QINV (1.0f / QSCALE)

typedef __attribute__((ext_vector_type(8))) short short8;
typedef __attribute__((ext_vector_type(4))) float f32x4;
typedef __attribute__((ext_vector_type(4))) unsigned uint4v;

#define GLOBAL_AS(p) ((__attribute__((address_space(1))) void*)(p))
#define LDS_AS(p) ((__attribute__((address_space(3))) void*)(p))

__device__ __forceinline__ unsigned pack_bf16(float a, float b) {
  unsigned ua = __float_as_uint(a) + 0x8000u;
  unsigned ub = __float_as_uint(b) + 0x8000u;
  return (ua >> 16) | (ub & 0xffff0000u);
}
// truncating pack via byte-perm (positive values; bias cancels in softmax ratio)
// result = [a.b2,a.b3,b.b2,b.b3] : low16 = bf16(a), high16 = bf16(b)
__device__ __forceinline__ unsigned pack_bf16_perm(float a, float b) {
  return __builtin_amdgcn_perm(__float_as_uint(b), __float_as_uint(a),
                               0x07060302u);
}
__device__ __forceinline__ ushort bf16_1(float a) {
  return (ushort)((__float_as_uint(a) + 0x8000u) >> 16);
}
__device__ __forceinline__ float bf16_to_f(ushort u) {
  return __uint_as_float(((unsigned)u) << 16);
}
__device__ __forceinline__ short8 frag4(unsigned a0, unsigned a1, unsigned a2,
                                        unsigned a3) {
  uint4v t = {a0, a1, a2, a3};
  return __builtin_bit_cast(short8, t);
}

// ---------------- stage0: fused weight-transpose + cvt(y) + ln0(x) ----------------
// blocks [0,112): weight transpose; [112,4208): y->bf16; [4208,8304): LN0(x)->bf16
__global__ __launch_bounds__(256) void stage0_kernel(
    const float* __restrict__ x, const float* __restrict__ y,
    const float* __restrict__ Wq, const float* __restrict__ Wk,
    const float* __restrict__ Wv, const float* __restrict__ W1,
    const float* __restrict__ W2, const float* __restrict__ ln0g,
    const float* __restrict__ ln0b, ushort* __restrict__ Wqt,
    ushort* __restrict__ Wkt, ushort* __restrict__ Wvt,
    ushort* __restrict__ W1t, ushort* __restrict__ W2t,
    ushort* __restrict__ yh, ushort* __restrict__ xh) {
  const int bid = blockIdx.x;
  const int t = threadIdx.x;
  if (bid < 112) {
    const float* W;
    ushort* Wt;
    int K, N, tile;
    if (bid < 16) { W = Wq; Wt = Wqt; K = 256; N = 256; tile = bid; }
    else if (bid < 32) { W = Wk; Wt = Wkt; K = 256; N = 256; tile = bid - 16; }
    else if (bid < 48) { W = Wv; Wt = Wvt; K = 256; N = 256; tile = bid - 32; }
    else if (bid < 80) { W = W1; Wt = W1t; K = 256; N = 512; tile = bid - 48; }
    else { W = W2; Wt = W2t; K = 512; N = 256; tile = bid - 80; }
    const int tn = N >> 6;
    const int k0 = (tile / tn) << 6, n0 = (tile % tn) << 6;
    __shared__ float T[64][65];
#pragma unroll
    for (int i = 0; i < 16; ++i) {
      const int idx = t + i * 256;
      const int r = idx >> 6, c = idx & 63;
      T[r][c] = W[(size_t)(k0 + r) * N + n0 + c];
    }
    __syncthreads();
#pragma unroll
    for (int i = 0; i < 16; ++i) {
      const int idx = t + i * 256;
      const int r = idx >> 6, c = idx & 63;
      Wt[(size_t)(n0 + r) * K + k0 + c] = bf16_1(T[c][r]);
    }
  } else if (bid < 4208) {
    const size_t i = ((size_t)(bid - 112) * 256 + t) * 4;
    const float4 v = *(const float4*)&y[i];
    uint2 pk;
    pk.x = pack_bf16(v.x, v.y);
    pk.y = pack_bf16(v.z, v.w);
    *(uint2*)&yh[i] = pk;
  } else {
    const int lane = t & 63, wave = t >> 6;
    const size_t row = (size_t)(bid - 4208) * 4 + wave;
    const float* xr = x + row * 256;
    float4 v = *(const float4*)&xr[lane * 4];
    float s = v.x + v.y + v.z + v.w;
#pragma unroll
    for (int m = 1; m < 64; m <<= 1) s += __shfl_xor(s, m, 64);
    const float mu = s * (1.0f / 256.0f);
    const float dx = v.x - mu, dy = v.y - mu, dz = v.z - mu, dw = v.w - mu;
    float ss = dx * dx + dy * dy + dz * dz + dw * dw;
#pragma unroll
    for (int m = 1; m < 64; m <<= 1) ss += __shfl_xor(ss, m, 64);
    const float rstd = rsqrtf(ss * (1.0f / 256.0f) + 1e-5f);
    const float4 gv = *(const float4*)&ln0g[lane * 4];
    const float4 bv = *(const float4*)&ln0b[lane * 4];
    uint2 pk;
    pk.x = pack_bf16(dx * rstd * gv.x + bv.x, dy * rstd * gv.y + bv.y);
    pk.y = pack_bf16(dz * rstd * gv.z + bv.z, dw * rstd * gv.w + bv.w);
    *(uint2*)&xh[row * 256 + lane * 4] = pk;
  }
}

// ---------------- LayerNorm over D=256, bf16 output ----------------
__global__ __launch_bounds__(256) void ln_kernel(
    const float* __restrict__ X, const float* __restrict__ g,
    const float* __restrict__ bt, ushort* __restrict__ Yh) {
  const int lane = threadIdx.x & 63;
  const int wave = threadIdx.x >> 6;
  const size_t row = (size_t)blockIdx.x * 4 + wave;
  const float* xr = X + row * 256;
  float4 v = *(const float4*)&xr[lane * 4];
  float s = v.x + v.y + v.z + v.w;
#pragma unroll
  for (int m = 1; m < 64; m <<= 1) s += __shfl_xor(s, m, 64);
  const float mu = s * (1.0f / 256.0f);
  const float dx = v.x - mu, dy = v.y - mu, dz = v.z - mu, dw = v.w - mu;
  float ss = dx * dx + dy * dy + dz * dz + dw * dw;
#pragma unroll
  for (int m = 1; m < 64; m <<= 1) ss += __shfl_xor(ss, m, 64);
  const float rstd = rsqrtf(ss * (1.0f / 256.0f) + 1e-5f);
  const float4 gv = *(const float4*)&g[lane * 4];
  const float4 bv = *(const float4*)&bt[lane * 4];
  uint2 pk;
  pk.x = pack_bf16(dx * rstd * gv.x + bv.x, dy * rstd * gv.y + bv.y);
  pk.y = pack_bf16(dz * rstd * gv.z + bv.z, dw * rstd * gv.w + bv.w);
  *(uint2*)&Yh[row * 256 + lane * 4] = pk;
}

// ---------------- merged QKV GEMM ----------------
// grid (128, 12): ny>>2 = 0:K 1:V 2:Q ; 128x64 tile, BK=32, 4 waves.
// K: Kh=bf16(v) ; Q: Qh=bf16(v*QSCALE) ; V: transpose -> VhT[b*256+n][nseq]
__global__ __launch_bounds__(256) void qkv_kernel(
    const ushort* __restrict__ xh, const ushort* __restrict__ yh,
    const ushort* __restrict__ Wqt, const ushort* __restrict__ Wkt,
    const ushort* __restrict__ Wvt, const float* __restrict__ bq,
    const float* __restrict__ bk, const float* __restrict__ bv,
    ushort* __restrict__ Qh, ushort* __restrict__ Kh,
    ushort* __restrict__ VhT) {
  __shared__ union UU {
    struct { ushort As[128 * 32]; ushort Bs[64 * 32]; } s;
    ushort Ct[64 * 136];  // V-transpose tile [n_local][m_local]
  } u;
  const int t = threadIdx.x;
  const int lane = t & 63, wave = t >> 6;
  const int l16 = lane & 15, quad = lane >> 4;
  const int row0 = blockIdx.x * 128;
  const int ny = blockIdx.y;
  const int which = ny >> 2;  // 0=K 1=V 2=Q
  const int n0 = (ny & 3) << 6;
  const ushort* A = (which == 2) ? xh : yh;
  const ushort* W = (which == 0) ? Wkt : (which == 1) ? Wvt : Wqt;
  const float* bs = (which == 0) ? bk : (which == 1) ? bv : bq;
  const int mrow = (wave & 1) * 64, ncol = (wave >> 1) * 32;

  const ushort* gA0 = A + (size_t)(row0 + (t >> 2)) * 256 + ((t & 3) << 3);
  const ushort* gA1 = gA0 + (size_t)64 * 256;
  const ushort* gB = W + (size_t)(n0 + (t >> 2)) * 256 + ((t & 3) << 3);
  ushort* lA0 = u.s.As + 8 * t;
  ushort* lA1 = u.s.As + 2048 + 8 * t;
  ushort* lB = u.s.Bs + 8 * t;

  f32x4 acc[4][2] = {};
  for (int kc = 0; kc < 256; kc += 32) {
    __builtin_amdgcn_global_load_lds(GLOBAL_AS(gA0 + kc), LDS_AS(lA0), 16, 0, 0);
    __builtin_amdgcn_global_load_lds(GLOBAL_AS(gA1 + kc), LDS_AS(lA1), 16, 0, 0);
    __builtin_amdgcn_global_load_lds(GLOBAL_AS(gB + kc), LDS_AS(lB), 16, 0, 0);
    __syncthreads();
    short8 af[4], bfr[2];
#pragma unroll
    for (int mi = 0; mi < 4; ++mi)
      af[mi] = *(const short8*)&u.s.As[(mrow + mi * 16 + l16) * 32 + quad * 8];
#pragma unroll
    for (int nj = 0; nj < 2; ++nj)
      bfr[nj] = *(const short8*)&u.s.Bs[(ncol + nj * 16 + l16) * 32 + quad * 8];
#pragma unroll
    for (int mi = 0; mi < 4; ++mi)
#pragma unroll
      for (int nj = 0; nj < 2; ++nj)
        acc[mi][nj] = __builtin_amdgcn_mfma_f32_16x16x32_bf16(
            af[mi], bfr[nj], acc[mi][nj], 0, 0, 0);
    __syncthreads();
  }

  if (which == 1) {
    // V: bias + transpose via LDS, coalesced write to VhT[b*256+n][nseq]
#pragma unroll
    for (int nj = 0; nj < 2; ++nj) {
      const int nloc = ncol + nj * 16 + l16;
      const float bvv = bs[n0 + nloc];
#pragma unroll
      for (int mi = 0; mi < 4; ++mi)
#pragma unroll
        for (int r = 0; r < 4; ++r)
          u.Ct[nloc * 136 + mrow + mi * 16 + quad * 4 + r] =
              bf16_1(acc[mi][nj][r] + bvv);
    }
    __syncthreads();
    const int bb = row0 >> 11, ns0 = row0 & 2047;
#pragma unroll
    for (int i = 0; i < 4; ++i) {
      const int c = t + i * 256;
      const int rr = c >> 4, c8 = (c & 15) << 3;
      *(float4*)&VhT[(size_t)(bb * 256 + n0 + rr) * 2048 + ns0 + c8] =
          *(const float4*)&u.Ct[rr * 136 + c8];
    }
  } else {
#pragma unroll
    for (int nj = 0; nj < 2; ++nj) {
      const int n = n0 + ncol + nj * 16 + l16;
      const float bvv = bs[n];
#pragma unroll
      for (int mi = 0; mi < 4; ++mi) {
#pragma unroll
        for (int r = 0; r < 4; ++r) {
          const size_t m = (size_t)row0 + mrow + mi * 16 + quad * 4 + r;
          const float v = acc[mi][nj][r] + bvv;
          if (which == 2) Qh[m * 256 + n] = bf16_1(v * QSCALE);
          else Kh[m * 256 + n] = bf16_1(v);
        }
      }
    }
  }
}

// ---------------- FFN GEMM: 128x64 tile, BK=32 ----------------
// MODE 2: Ch=bf16(gelu(v)) (FFN1) ; MODE 3: Cf=v+res (FFN2 -> out)
template <int MODE>
__global__ __launch_bounds__(256) void mgemm_kernel(
    const ushort* __restrict__ A, const ushort* __restrict__ Wt,
    const float* __restrict__ bias, const float* __restrict__ res,
    float* __restrict__ Cf, ushort* __restrict__ Ch, int K, int N) {
  __shared__ ushort As[128 * 32];
  __shared__ ushort Bs[64 * 32];
  const int t = threadIdx.x;
  const int lane = t & 63, wave = t >> 6;
  const int l16 = lane & 15, quad = lane >> 4;
  const int row0 = blockIdx.x * 128;
  const int n0 = blockIdx.y << 6;
  const int mrow = (wave & 1) * 64, ncol = (wave >> 1) * 32;

  const ushort* gA0 = A + (size_t)(row0 + (t >> 2)) * K + ((t & 3) << 3);
  const ushort* gA1 = gA0 + (size_t)64 * K;
  const ushort* gB = Wt + (size_t)(n0 + (t >> 2)) * K + ((t & 3) << 3);
  ushort* lA0 = As + 8 * t;
  ushort* lA1 = As + 2048 + 8 * t;
  ushort* lB = Bs + 8 * t;

  f32x4 acc[4][2] = {};
  for (int kc = 0; kc < K; kc += 32) {
    __builtin_amdgcn_global_load_lds(GLOBAL_AS(gA0 + kc), LDS_AS(lA0), 16, 0, 0);
    __builtin_amdgcn_global_load_lds(GLOBAL_AS(gA1 + kc), LDS_AS(lA1), 16, 0, 0);
    __builtin_amdgcn_global_load_lds(GLOBAL_AS(gB + kc), LDS_AS(lB), 16, 0, 0);
    __syncthreads();
    short8 af[4], bfr[2];
#pragma unroll
    for (int mi = 0; mi < 4; ++mi)
      af[mi] = *(const short8*)&As[(mrow + mi * 16 + l16) * 32 + quad * 8];
#pragma unroll
    for (int nj = 0; nj < 2; ++nj)
      bfr[nj] = *(const short8*)&Bs[(ncol + nj * 16 + l16) * 32 + quad * 8];
#pragma unroll
    for (int mi = 0; mi < 4; ++mi)
#pragma unroll
      for (int nj = 0; nj < 2; ++nj)
        acc[mi][nj] = __builtin_amdgcn_mfma_f32_16x16x32_bf16(
            af[mi], bfr[nj], acc[mi][nj], 0, 0, 0);
    __syncthreads();
  }
#pragma unroll
  for (int nj = 0; nj < 2; ++nj) {
    const int n = n0 + ncol + nj * 16 + l16;
    const float bvv = bias[n];
#pragma unroll
    for (int mi = 0; mi < 4; ++mi) {
#pragma unroll
      for (int r = 0; r < 4; ++r) {
        const size_t m = (size_t)row0 + mrow + mi * 16 + quad * 4 + r;
        float v = acc[mi][nj][r] + bvv;
        if (MODE == 2) {
          v = 0.5f * v * (1.0f + erff(v * 0.70710678118654752f));
          Ch[m * N + n] = bf16_1(v);
        }
        if (MODE == 3) Cf[m * N + n] = v + res[m * N + n];
      }
    }
  }
}

// ---------------- Flash attention (bf16 MFMA, zero-max, 64q, high-occupancy) ----
// O = Q + softmax(Q K^T / 16) V.  Qh pre-scaled by log2(e)/16 (bf16); residual
// recovered as Qh/QSCALE. No max shift (p = exp2(S*log2e), ratio-invariant);
// l via ones-MFMA.
// 64 q rows/block, 4 waves, each wave owns ONE 16-row q-group (round-1 group-0
// path verbatim). LDS 19456B + low VGPR -> 8 blocks/CU = 32 waves/CU (2x the
// 128q version): 8 mutually-unsynchronized blocks per CU fill each other's
// barrier/trans stalls. K rows staged with bits 2<=>3 swapped so the P
// redistribution after swapped QK^T is permlane32-only (in-register).
// Grid 2048: bh = idx&63 (XCD locality), qt = idx>>6.
__global__ __launch_bounds__(256, 8) void attn_kernel(
    const ushort* __restrict__ Qh, const ushort* __restrict__ Kh,
    const ushort* __restrict__ VhT, float* __restrict__ O) {
  __shared__ ushort Ks[2][64][40];  // 10240 B
  __shared__ ushort Vt[2][32][72];  // 9216 B

  const int t = threadIdx.x;
  const int lane = t & 63, wave = t >> 6;
  const int l16 = lane & 15, quad = lane >> 4;
  const int bh = blockIdx.x & 63;
  const int qt = blockIdx.x >> 6;  // 0..31
  const int b = bh >> 3, h = bh & 7;

  const size_t rowQ = (size_t)(b * NSEQ + qt * 64 + wave * 16 + l16);
  const short8 qfrag = *(const short8*)&Qh[rowQ * 256 + h * HDIM + quad * 8];
  const short8 ones = {16256, 16256, 16256, 16256,
                       16256, 16256, 16256, 16256};  // bf16 1.0 x8
  const f32x4 zf = {0.f, 0.f, 0.f, 0.f};

  f32x4 oa = zf, ob = zf, sl = zf;

  // staging coords (cooperative, coalesced): K tile [64][32], V tile [32][64]
  // K rows land permuted: LDS row p holds logical key with bits 2<=>3 swapped
  // (self-inverse), which makes the post-QK^T lane shuffle permlane32-only.
  const int kr = t >> 2, kc8 = (t & 3) << 3;
  const int krL = (kr & ~12) | ((kr & 4) << 1) | ((kr & 8) >> 1);
  const int vd = t >> 3, vc8 = (t & 7) << 3;
  const ushort* gK = Kh + ((size_t)(b * NSEQ + krL)) * 256 + h * HDIM + kc8;
  const ushort* gV = VhT + ((size_t)(bh * 32 + vd)) * 2048 + vc8;

  float4 kreg = *(const float4*)gK;
  float4 vreg = *(const float4*)gV;

  for (int kt = 0; kt < 32; ++kt) {
    const int bf = kt & 1;
    *(float4*)&Ks[bf][kr][kc8] = kreg;
    *(float4*)&Vt[bf][vd][vc8] = vreg;
    __syncthreads();  // buf visible; prev readers done (prev barrier)
    if (kt < 31) {    // register prefetch, in flight over compute
      kreg = *(const float4*)(gK + (size_t)(kt + 1) * 64 * 256);
      vreg = *(const float4*)(gV + (kt + 1) * 64);
    }

    // fragments (wave-independent LDS reads; identical addrs across waves)
    short8 kf[4];
#pragma unroll
    for (int sub = 0; sub < 4; ++sub)
      kf[sub] = *(const short8*)&Ks[bf][sub * 16 + l16][quad * 8];
    const short8 vf00 = *(const short8*)&Vt[bf][l16][quad * 8];
    const short8 vf01 = *(const short8*)&Vt[bf][l16][32 + quad * 8];
    const short8 vf10 = *(const short8*)&Vt[bf][16 + l16][quad * 8];
    const short8 vf11 = *(const short8*)&Vt[bf][16 + l16][32 + quad * 8];

    // ---- S-MFMAs (latency overlaps exp2 below) ----
    f32x4 sa[4];
#pragma unroll
    for (int sub = 0; sub < 4; ++sub)
      sa[sub] =
          __builtin_amdgcn_mfma_f32_16x16x32_bf16(kf[sub], qfrag, zf, 0, 0, 0);

    // ---- exp2 + pack + in-register route (permlane32 swap) ----
    unsigned p[4][2];
#pragma unroll
    for (int sub = 0; sub < 4; ++sub) {
      p[sub][0] = pack_bf16_perm(__builtin_amdgcn_exp2f(sa[sub][0]),
                                 __builtin_amdgcn_exp2f(sa[sub][1]));
      p[sub][1] = pack_bf16_perm(__builtin_amdgcn_exp2f(sa[sub][2]),
                                 __builtin_amdgcn_exp2f(sa[sub][3]));
    }
    unsigned u0 = p[0][0], w0 = p[1][0];
    asm("v_permlane32_swap_b32 %0, %1" : "+v"(u0), "+v"(w0));
    unsigned u1 = p[0][1], w1 = p[1][1];
    asm("v_permlane32_swap_b32 %0, %1" : "+v"(u1), "+v"(w1));
    unsigned u2 = p[2][0], w2 = p[3][0];
    asm("v_permlane32_swap_b32 %0, %1" : "+v"(u2), "+v"(w2));
    unsigned u3 = p[2][1], w3 = p[3][1];
    asm("v_permlane32_swap_b32 %0, %1" : "+v"(u3), "+v"(w3));
    const short8 pf0 = frag4(u0, u1, w0, w1);   // keys 0..31 chunk
    const short8 pf1 = frag4(u2, u3, w2, w3);   // keys 32..63 chunk

    // ---- PV + row-sum MFMAs (pure-MFMA cluster; setprio = T5) ----
    __builtin_amdgcn_s_setprio(1);
    oa = __builtin_amdgcn_mfma_f32_16x16x32_bf16(pf0, vf00, oa, 0, 0, 0);
    oa = __builtin_amdgcn_mfma_f32_16x16x32_bf16(pf1, vf01, oa, 0, 0, 0);
    ob = __builtin_amdgcn_mfma_f32_16x16x32_bf16(pf0, vf10, ob, 0, 0, 0);
    ob = __builtin_amdgcn_mfma_f32_16x16x32_bf16(pf1, vf11, ob, 0, 0, 0);
    sl = __builtin_amdgcn_mfma_f32_16x16x32_bf16(pf0, ones, sl, 0, 0, 0);
    sl = __builtin_amdgcn_mfma_f32_16x16x32_bf16(pf1, ones, sl, 0, 0, 0);
    __builtin_amdgcn_s_setprio(0);
  }

  // ---- epilogue: O = Q + oacc/l ; Q re-read directly (L2-hot) ----
  const size_t row0 = (size_t)(b * NSEQ + qt * 64 + wave * 16 + quad * 4);
#pragma unroll
  for (int r = 0; r < 4; ++r) {
    const float il = 1.0f / sl[r];
    const size_t ro = (row0 + r) * 256 + h * HDIM + l16;
    O[ro] = bf16_to_f(Qh[ro]) * QINV + oa[r] * il;
    O[ro + 16] = bf16_to_f(Qh[ro + 16]) * QINV + ob[r] * il;
  }
}

extern "C" void kernel_launch(void* const* d_in, const int* in_sizes, int n_in,
                              void* d_out, int out_size, void* d_ws, size_t ws_size,
                              hipStream_t stream) {
  const float* x = (const float*)d_in[0];
  const float* y = (const float*)d_in[1];
  const float* Wq = (const float*)d_in[2];
  const float* bq = (const float*)d_in[3];
  const float* Wk = (const float*)d_in[4];
  const float* bk = (const float*)d_in[5];
  const float* Wv = (const float*)d_in[6];
  const float* bv = (const float*)d_in[7];
  const float* W1 = (const float*)d_in[8];
  const float* b1 = (const float*)d_in[9];
  const float* W2 = (const float*)d_in[10];
  const float* b2 = (const float*)d_in[11];
  const float* ln0g = (const float*)d_in[12];
  const float* ln0b = (const float*)d_in[13];
  const float* ln1g = (const float*)d_in[14];
  const float* ln1b = (const float*)d_in[15];
  float* out = (float*)d_out;
  char* base = (char*)d_ws;

  const size_t RM = (size_t)RTOT * 256;
  // region0: yh (bf16, stage0->qkv) then overwritten by Ob (fp32, attn out)
  ushort* yh = (ushort*)base;
  float* Ob = (float*)base;
  ushort* Qh = (ushort*)(base + 2 * RM * 4);
  ushort* Kh = (ushort*)(base + 2 * RM * 4 + RM * 2);
  ushort* VhT = (ushort*)(base + 3 * RM * 4);
  ushort* xh = (ushort*)(base + 3 * RM * 4 + RM * 2);  // LN0 out; reused as On
  ushort* Onh = xh;
  ushort* Hidh = Qh;  // [R,512] bf16 overlays Qh+Kh (dead after attn)
  char* wbase = base + 4 * RM * 4;
  ushort* Wqt = (ushort*)wbase;  // [256,256]
  ushort* Wkt = Wqt + 65536;
  ushort* Wvt = Wkt + 65536;
  ushort* W1t = Wvt + 65536;   // [512,256]
  ushort* W2t = W1t + 131072;  // [256,512]

  stage0_kernel<<<8304, 256, 0, stream>>>(x, y, Wq, Wk, Wv, W1, W2, ln0g, ln0b,
                                          Wqt, Wkt, Wvt, W1t, W2t, yh, xh);
  qkv_kernel<<<dim3(128, 12), 256, 0, stream>>>(xh, yh, Wqt, Wkt, Wvt, bq, bk,
                                                bv, Qh, Kh, VhT);
  attn_kernel<<<2048, 256, 0, stream>>>(Qh, Kh, VhT, Ob);
  ln_kernel<<<RTOT / 4, 256, 0, stream>>>(Ob, ln1g, ln1b, Onh);
  mgemm_kernel<2><<<dim3(128, 8), 256, 0, stream>>>(Onh, W1t, b1, nullptr,
                                                    nullptr, Hidh, 256, 512);
  mgemm_kernel<3><<<dim3(128, 4), 256, 0, stream>>>(Hidh, W2t, b2, Ob, out,
                                                    nullptr, 512, 256);
}

// Round 5
// 244.111 us; speedup vs baseline: 1.1471x; 1.0214x over previous
//
#include <hip/hip_runtime.h>
#include <math.h>

// Problem constants (B=8, N=2048, D_IN=D_V=256, H=8, HD=32, D_FF=512)
#define RTOT 16384   // B*N rows
#define NSEQ 2048
#define NHEAD 8
#define HDIM 32
// Q pre-scale: log2(e)/sqrt(256) so S_mfma = S_true*log2e, softmax via exp2
#define QSCALE 0.09017132252479462f
#define QINV (1.0f / QSCALE)

typedef __attribute__((ext_vector_type(8))) short short8;
typedef __attribute__((ext_vector_type(4))) float f32x4;
typedef __attribute__((ext_vector_type(4))) unsigned uint4v;

#define GLOBAL_AS(p) ((__attribute__((address_space(1))) void*)(p))
#define LDS_AS(p) ((__attribute__((address_space(3))) void*)(p))

__device__ __forceinline__ unsigned pack_bf16(float a, float b) {
  unsigned ua = __float_as_uint(a) + 0x8000u;
  unsigned ub = __float_as_uint(b) + 0x8000u;
  return (ua >> 16) | (ub & 0xffff0000u);
}
// truncating pack via byte-perm (positive values; bias cancels in softmax ratio)
// result = [a.b2,a.b3,b.b2,b.b3] : low16 = bf16(a), high16 = bf16(b)
__device__ __forceinline__ unsigned pack_bf16_perm(float a, float b) {
  return __builtin_amdgcn_perm(__float_as_uint(b), __float_as_uint(a),
                               0x07060302u);
}
__device__ __forceinline__ ushort bf16_1(float a) {
  return (ushort)((__float_as_uint(a) + 0x8000u) >> 16);
}
__device__ __forceinline__ float bf16_to_f(ushort u) {
  return __uint_as_float(((unsigned)u) << 16);
}
__device__ __forceinline__ short8 frag4(unsigned a0, unsigned a1, unsigned a2,
                                        unsigned a3) {
  uint4v t = {a0, a1, a2, a3};
  return __builtin_bit_cast(short8, t);
}

// ---------------- stage0: weight-transpose + cvt(y) + ln0(x) + acc-zero ---------
// blocks [0,112): weight transpose; [112,4208): y->bf16; [4208,8304): LN0(x)->bf16
// [8304,9360): zero the split-K accumulators (Lacc+Oacc, 16.5 MB contiguous)
__global__ __launch_bounds__(256) void stage0_kernel(
    const float* __restrict__ x, const float* __restrict__ y,
    const float* __restrict__ Wq, const float* __restrict__ Wk,
    const float* __restrict__ Wv, const float* __restrict__ W1,
    const float* __restrict__ W2, const float* __restrict__ ln0g,
    const float* __restrict__ ln0b, ushort* __restrict__ Wqt,
    ushort* __restrict__ Wkt, ushort* __restrict__ Wvt,
    ushort* __restrict__ W1t, ushort* __restrict__ W2t,
    ushort* __restrict__ yh, ushort* __restrict__ xh,
    float* __restrict__ zacc) {
  const int bid = blockIdx.x;
  const int t = threadIdx.x;
  if (bid < 112) {
    const float* W;
    ushort* Wt;
    int K, N, tile;
    if (bid < 16) { W = Wq; Wt = Wqt; K = 256; N = 256; tile = bid; }
    else if (bid < 32) { W = Wk; Wt = Wkt; K = 256; N = 256; tile = bid - 16; }
    else if (bid < 48) { W = Wv; Wt = Wvt; K = 256; N = 256; tile = bid - 32; }
    else if (bid < 80) { W = W1; Wt = W1t; K = 256; N = 512; tile = bid - 48; }
    else { W = W2; Wt = W2t; K = 512; N = 256; tile = bid - 80; }
    const int tn = N >> 6;
    const int k0 = (tile / tn) << 6, n0 = (tile % tn) << 6;
    __shared__ float T[64][65];
#pragma unroll
    for (int i = 0; i < 16; ++i) {
      const int idx = t + i * 256;
      const int r = idx >> 6, c = idx & 63;
      T[r][c] = W[(size_t)(k0 + r) * N + n0 + c];
    }
    __syncthreads();
#pragma unroll
    for (int i = 0; i < 16; ++i) {
      const int idx = t + i * 256;
      const int r = idx >> 6, c = idx & 63;
      Wt[(size_t)(n0 + r) * K + k0 + c] = bf16_1(T[c][r]);
    }
  } else if (bid < 4208) {
    const size_t i = ((size_t)(bid - 112) * 256 + t) * 4;
    const float4 v = *(const float4*)&y[i];
    uint2 pk;
    pk.x = pack_bf16(v.x, v.y);
    pk.y = pack_bf16(v.z, v.w);
    *(uint2*)&yh[i] = pk;
  } else if (bid < 8304) {
    const int lane = t & 63, wave = t >> 6;
    const size_t row = (size_t)(bid - 4208) * 4 + wave;
    const float* xr = x + row * 256;
    float4 v = *(const float4*)&xr[lane * 4];
    float s = v.x + v.y + v.z + v.w;
#pragma unroll
    for (int m = 1; m < 64; m <<= 1) s += __shfl_xor(s, m, 64);
    const float mu = s * (1.0f / 256.0f);
    const float dx = v.x - mu, dy = v.y - mu, dz = v.z - mu, dw = v.w - mu;
    float ss = dx * dx + dy * dy + dz * dz + dw * dw;
#pragma unroll
    for (int m = 1; m < 64; m <<= 1) ss += __shfl_xor(ss, m, 64);
    const float rstd = rsqrtf(ss * (1.0f / 256.0f) + 1e-5f);
    const float4 gv = *(const float4*)&ln0g[lane * 4];
    const float4 bv = *(const float4*)&ln0b[lane * 4];
    uint2 pk;
    pk.x = pack_bf16(dx * rstd * gv.x + bv.x, dy * rstd * gv.y + bv.y);
    pk.y = pack_bf16(dz * rstd * gv.z + bv.z, dw * rstd * gv.w + bv.w);
    *(uint2*)&xh[row * 256 + lane * 4] = pk;
  } else {
    // zero 16.5 MB accumulator span: 1056 blocks x 256 threads x 4 float4
    const float4 z = {0.f, 0.f, 0.f, 0.f};
    const size_t idx = (size_t)(bid - 8304) * 256 + t;
    float4* zb = (float4*)zacc;
#pragma unroll
    for (int k = 0; k < 4; ++k) zb[idx + (size_t)k * 270336] = z;
  }
}

// ---------------- combine + residual + LayerNorm (replaces ln_kernel) ----------
// O = Qh*QINV + Oacc/Lacc (split-K combine), written in-place to Oacc (-> Ob
// residual for FFN2), then LN -> bf16 Yh.
__global__ __launch_bounds__(256) void combine_ln_kernel(
    const ushort* __restrict__ Qh, float* __restrict__ Oacc,
    const float* __restrict__ Lacc, const float* __restrict__ g,
    const float* __restrict__ bt, ushort* __restrict__ Yh) {
  const int lane = threadIdx.x & 63;
  const int wave = threadIdx.x >> 6;
  const size_t row = (size_t)blockIdx.x * 4 + wave;
  const int d0 = lane * 4;
  float4 o4 = *(const float4*)&Oacc[row * 256 + d0];
  const float il = 1.0f / Lacc[row * 8 + (lane >> 3)];
  const uint2 qb = *(const uint2*)&Qh[row * 256 + d0];
  const float vx = bf16_to_f((ushort)(qb.x & 0xffff)) * QINV + o4.x * il;
  const float vy = bf16_to_f((ushort)(qb.x >> 16)) * QINV + o4.y * il;
  const float vz = bf16_to_f((ushort)(qb.y & 0xffff)) * QINV + o4.z * il;
  const float vw = bf16_to_f((ushort)(qb.y >> 16)) * QINV + o4.w * il;
  float4 ov = {vx, vy, vz, vw};
  *(float4*)&Oacc[row * 256 + d0] = ov;  // final O (FFN2 residual)
  float s = vx + vy + vz + vw;
#pragma unroll
  for (int m = 1; m < 64; m <<= 1) s += __shfl_xor(s, m, 64);
  const float mu = s * (1.0f / 256.0f);
  const float dx = vx - mu, dy = vy - mu, dz = vz - mu, dw = vw - mu;
  float ss = dx * dx + dy * dy + dz * dz + dw * dw;
#pragma unroll
  for (int m = 1; m < 64; m <<= 1) ss += __shfl_xor(ss, m, 64);
  const float rstd = rsqrtf(ss * (1.0f / 256.0f) + 1e-5f);
  const float4 gv = *(const float4*)&g[d0];
  const float4 bv = *(const float4*)&bt[d0];
  uint2 pk;
  pk.x = pack_bf16(dx * rstd * gv.x + bv.x, dy * rstd * gv.y + bv.y);
  pk.y = pack_bf16(dz * rstd * gv.z + bv.z, dw * rstd * gv.w + bv.w);
  *(uint2*)&Yh[row * 256 + d0] = pk;
}

// ---------------- merged QKV GEMM ----------------
// grid (128, 12): ny>>2 = 0:K 1:V 2:Q ; 128x64 tile, BK=32, 4 waves.
// K: Kh=bf16(v) ; Q: Qh=bf16(v*QSCALE) ; V: transpose -> VhT[b*256+n][nseq]
__global__ __launch_bounds__(256) void qkv_kernel(
    const ushort* __restrict__ xh, const ushort* __restrict__ yh,
    const ushort* __restrict__ Wqt, const ushort* __restrict__ Wkt,
    const ushort* __restrict__ Wvt, const float* __restrict__ bq,
    const float* __restrict__ bk, const float* __restrict__ bv,
    ushort* __restrict__ Qh, ushort* __restrict__ Kh,
    ushort* __restrict__ VhT) {
  __shared__ union UU {
    struct { ushort As[128 * 32]; ushort Bs[64 * 32]; } s;
    ushort Ct[64 * 136];  // V-transpose tile [n_local][m_local]
  } u;
  const int t = threadIdx.x;
  const int lane = t & 63, wave = t >> 6;
  const int l16 = lane & 15, quad = lane >> 4;
  const int row0 = blockIdx.x * 128;
  const int ny = blockIdx.y;
  const int which = ny >> 2;  // 0=K 1=V 2=Q
  const int n0 = (ny & 3) << 6;
  const ushort* A = (which == 2) ? xh : yh;
  const ushort* W = (which == 0) ? Wkt : (which == 1) ? Wvt : Wqt;
  const float* bs = (which == 0) ? bk : (which == 1) ? bv : bq;
  const int mrow = (wave & 1) * 64, ncol = (wave >> 1) * 32;

  const ushort* gA0 = A + (size_t)(row0 + (t >> 2)) * 256 + ((t & 3) << 3);
  const ushort* gA1 = gA0 + (size_t)64 * 256;
  const ushort* gB = W + (size_t)(n0 + (t >> 2)) * 256 + ((t & 3) << 3);
  ushort* lA0 = u.s.As + 8 * t;
  ushort* lA1 = u.s.As + 2048 + 8 * t;
  ushort* lB = u.s.Bs + 8 * t;

  f32x4 acc[4][2] = {};
  for (int kc = 0; kc < 256; kc += 32) {
    __builtin_amdgcn_global_load_lds(GLOBAL_AS(gA0 + kc), LDS_AS(lA0), 16, 0, 0);
    __builtin_amdgcn_global_load_lds(GLOBAL_AS(gA1 + kc), LDS_AS(lA1), 16, 0, 0);
    __builtin_amdgcn_global_load_lds(GLOBAL_AS(gB + kc), LDS_AS(lB), 16, 0, 0);
    __syncthreads();
    short8 af[4], bfr[2];
#pragma unroll
    for (int mi = 0; mi < 4; ++mi)
      af[mi] = *(const short8*)&u.s.As[(mrow + mi * 16 + l16) * 32 + quad * 8];
#pragma unroll
    for (int nj = 0; nj < 2; ++nj)
      bfr[nj] = *(const short8*)&u.s.Bs[(ncol + nj * 16 + l16) * 32 + quad * 8];
#pragma unroll
    for (int mi = 0; mi < 4; ++mi)
#pragma unroll
      for (int nj = 0; nj < 2; ++nj)
        acc[mi][nj] = __builtin_amdgcn_mfma_f32_16x16x32_bf16(
            af[mi], bfr[nj], acc[mi][nj], 0, 0, 0);
    __syncthreads();
  }

  if (which == 1) {
    // V: bias + transpose via LDS, coalesced write to VhT[b*256+n][nseq]
#pragma unroll
    for (int nj = 0; nj < 2; ++nj) {
      const int nloc = ncol + nj * 16 + l16;
      const float bvv = bs[n0 + nloc];
#pragma unroll
      for (int mi = 0; mi < 4; ++mi)
#pragma unroll
        for (int r = 0; r < 4; ++r)
          u.Ct[nloc * 136 + mrow + mi * 16 + quad * 4 + r] =
              bf16_1(acc[mi][nj][r] + bvv);
    }
    __syncthreads();
    const int bb = row0 >> 11, ns0 = row0 & 2047;
#pragma unroll
    for (int i = 0; i < 4; ++i) {
      const int c = t + i * 256;
      const int rr = c >> 4, c8 = (c & 15) << 3;
      *(float4*)&VhT[(size_t)(bb * 256 + n0 + rr) * 2048 + ns0 + c8] =
          *(const float4*)&u.Ct[rr * 136 + c8];
    }
  } else {
#pragma unroll
    for (int nj = 0; nj < 2; ++nj) {
      const int n = n0 + ncol + nj * 16 + l16;
      const float bvv = bs[n];
#pragma unroll
      for (int mi = 0; mi < 4; ++mi) {
#pragma unroll
        for (int r = 0; r < 4; ++r) {
          const size_t m = (size_t)row0 + mrow + mi * 16 + quad * 4 + r;
          const float v = acc[mi][nj][r] + bvv;
          if (which == 2) Qh[m * 256 + n] = bf16_1(v * QSCALE);
          else Kh[m * 256 + n] = bf16_1(v);
        }
      }
    }
  }
}

// ---------------- FFN GEMM: 128x64 tile, BK=32 ----------------
// MODE 2: Ch=bf16(gelu(v)) (FFN1) ; MODE 3: Cf=v+res (FFN2 -> out)
template <int MODE>
__global__ __launch_bounds__(256) void mgemm_kernel(
    const ushort* __restrict__ A, const ushort* __restrict__ Wt,
    const float* __restrict__ bias, const float* __restrict__ res,
    float* __restrict__ Cf, ushort* __restrict__ Ch, int K, int N) {
  __shared__ ushort As[128 * 32];
  __shared__ ushort Bs[64 * 32];
  const int t = threadIdx.x;
  const int lane = t & 63, wave = t >> 6;
  const int l16 = lane & 15, quad = lane >> 4;
  const int row0 = blockIdx.x * 128;
  const int n0 = blockIdx.y << 6;
  const int mrow = (wave & 1) * 64, ncol = (wave >> 1) * 32;

  const ushort* gA0 = A + (size_t)(row0 + (t >> 2)) * K + ((t & 3) << 3);
  const ushort* gA1 = gA0 + (size_t)64 * K;
  const ushort* gB = Wt + (size_t)(n0 + (t >> 2)) * K + ((t & 3) << 3);
  ushort* lA0 = As + 8 * t;
  ushort* lA1 = As + 2048 + 8 * t;
  ushort* lB = Bs + 8 * t;

  f32x4 acc[4][2] = {};
  for (int kc = 0; kc < K; kc += 32) {
    __builtin_amdgcn_global_load_lds(GLOBAL_AS(gA0 + kc), LDS_AS(lA0), 16, 0, 0);
    __builtin_amdgcn_global_load_lds(GLOBAL_AS(gA1 + kc), LDS_AS(lA1), 16, 0, 0);
    __builtin_amdgcn_global_load_lds(GLOBAL_AS(gB + kc), LDS_AS(lB), 16, 0, 0);
    __syncthreads();
    short8 af[4], bfr[2];
#pragma unroll
    for (int mi = 0; mi < 4; ++mi)
      af[mi] = *(const short8*)&As[(mrow + mi * 16 + l16) * 32 + quad * 8];
#pragma unroll
    for (int nj = 0; nj < 2; ++nj)
      bfr[nj] = *(const short8*)&Bs[(ncol + nj * 16 + l16) * 32 + quad * 8];
#pragma unroll
    for (int mi = 0; mi < 4; ++mi)
#pragma unroll
      for (int nj = 0; nj < 2; ++nj)
        acc[mi][nj] = __builtin_amdgcn_mfma_f32_16x16x32_bf16(
            af[mi], bfr[nj], acc[mi][nj], 0, 0, 0);
    __syncthreads();
  }
#pragma unroll
  for (int nj = 0; nj < 2; ++nj) {
    const int n = n0 + ncol + nj * 16 + l16;
    const float bvv = bias[n];
#pragma unroll
    for (int mi = 0; mi < 4; ++mi) {
#pragma unroll
      for (int r = 0; r < 4; ++r) {
        const size_t m = (size_t)row0 + mrow + mi * 16 + quad * 4 + r;
        float v = acc[mi][nj][r] + bvv;
        if (MODE == 2) {
          v = 0.5f * v * (1.0f + erff(v * 0.70710678118654752f));
          Ch[m * N + n] = bf16_1(v);
        }
        if (MODE == 3) Cf[m * N + n] = v + res[m * N + n];
      }
    }
  }
}

// ---------------- Flash attention, split-K over keys (bf16 MFMA, zero-max) ----
// Identical wave structure to the 66.5us round-1 kernel (128q, 4 waves, 2
// q-groups/wave, ~72 VGPR ILP) but each block handles HALF the keys (1024).
// Grid 2048 -> ~7 blocks/CU co-resident (vs 4), mutually unsynchronized.
// Zero-max softmax => partial (o,l) sums are exactly additive: both halves
// unsafeAtomicAdd (HW global_atomic_add_f32; 2 commutative contributions =
// deterministic) into Oacc/Lacc zeroed by stage0. Residual+normalization
// happen in combine_ln_kernel. K rows staged with bits 2<=>3 swapped so the
// post-QK^T P redistribution is permlane32-only.
__global__ __launch_bounds__(256) void attn_kernel(
    const ushort* __restrict__ Qh, const ushort* __restrict__ Kh,
    const ushort* __restrict__ VhT, float* __restrict__ Oacc,
    float* __restrict__ Lacc) {
  __shared__ ushort Ks[2][64][40];  // 10240 B
  __shared__ ushort Vt[2][32][72];  // 9216 B

  const int t = threadIdx.x;
  const int lane = t & 63, wave = t >> 6;
  const int l16 = lane & 15, quad = lane >> 4;
  const int bh = blockIdx.x & 63;
  const int rest = blockIdx.x >> 6;  // 0..31
  const int qt = rest & 15;          // q tile 0..15
  const int half = rest >> 4;        // key half 0..1
  const int b = bh >> 3, h = bh & 7;

  const size_t rowQ0 = (size_t)(b * NSEQ + qt * 128 + wave * 32 + l16);
  const short8 qfrag0 = *(const short8*)&Qh[rowQ0 * 256 + h * HDIM + quad * 8];
  const short8 qfrag1 =
      *(const short8*)&Qh[(rowQ0 + 16) * 256 + h * HDIM + quad * 8];
  const short8 ones = {16256, 16256, 16256, 16256,
                       16256, 16256, 16256, 16256};  // bf16 1.0 x8
  const f32x4 zf = {0.f, 0.f, 0.f, 0.f};

  f32x4 o00 = zf, o01 = zf, o10 = zf, o11 = zf;
  f32x4 s0 = zf, s1 = zf;

  // staging coords (cooperative, coalesced): K tile [64][32], V tile [32][64]
  // K rows land permuted: LDS row p holds logical key with bits 2<=>3 swapped
  // (self-inverse), which makes the post-QK^T lane shuffle permlane32-only.
  const int kr = t >> 2, kc8 = (t & 3) << 3;
  const int krL = (kr & ~12) | ((kr & 4) << 1) | ((kr & 8) >> 1);
  const int vd = t >> 3, vc8 = (t & 7) << 3;
  const ushort* gK =
      Kh + ((size_t)(b * NSEQ + half * 1024 + krL)) * 256 + h * HDIM + kc8;
  const ushort* gV =
      VhT + ((size_t)(bh * 32 + vd)) * 2048 + half * 1024 + vc8;

  float4 kreg = *(const float4*)gK;
  float4 vreg = *(const float4*)gV;

  for (int kt = 0; kt < 16; ++kt) {
    const int bf = kt & 1;
    *(float4*)&Ks[bf][kr][kc8] = kreg;
    *(float4*)&Vt[bf][vd][vc8] = vreg;
    __syncthreads();  // buf visible; prev readers done (prev barrier)
    if (kt < 15) {    // register prefetch, in flight over compute
      kreg = *(const float4*)(gK + (size_t)(kt + 1) * 64 * 256);
      vreg = *(const float4*)(gV + (kt + 1) * 64);
    }

    // shared fragments for both q-groups (wave-independent LDS reads)
    short8 kf[4];
#pragma unroll
    for (int sub = 0; sub < 4; ++sub)
      kf[sub] = *(const short8*)&Ks[bf][sub * 16 + l16][quad * 8];
    const short8 vf00 = *(const short8*)&Vt[bf][l16][quad * 8];
    const short8 vf01 = *(const short8*)&Vt[bf][l16][32 + quad * 8];
    const short8 vf10 = *(const short8*)&Vt[bf][16 + l16][quad * 8];
    const short8 vf11 = *(const short8*)&Vt[bf][16 + l16][32 + quad * 8];

    // ---- S-MFMAs for BOTH groups (MFMA latency overlaps exp2 below) ----
    f32x4 sa0[4], sa1[4];
#pragma unroll
    for (int sub = 0; sub < 4; ++sub)
      sa0[sub] =
          __builtin_amdgcn_mfma_f32_16x16x32_bf16(kf[sub], qfrag0, zf, 0, 0, 0);
#pragma unroll
    for (int sub = 0; sub < 4; ++sub)
      sa1[sub] =
          __builtin_amdgcn_mfma_f32_16x16x32_bf16(kf[sub], qfrag1, zf, 0, 0, 0);

    // ---- exp2 + pack + in-register route (permlane32 swap) ----
    unsigned p0[4][2], p1[4][2];
#pragma unroll
    for (int sub = 0; sub < 4; ++sub) {
      p0[sub][0] = pack_bf16_perm(__builtin_amdgcn_exp2f(sa0[sub][0]),
                                  __builtin_amdgcn_exp2f(sa0[sub][1]));
      p0[sub][1] = pack_bf16_perm(__builtin_amdgcn_exp2f(sa0[sub][2]),
                                  __builtin_amdgcn_exp2f(sa0[sub][3]));
    }
#pragma unroll
    for (int sub = 0; sub < 4; ++sub) {
      p1[sub][0] = pack_bf16_perm(__builtin_amdgcn_exp2f(sa1[sub][0]),
                                  __builtin_amdgcn_exp2f(sa1[sub][1]));
      p1[sub][1] = pack_bf16_perm(__builtin_amdgcn_exp2f(sa1[sub][2]),
                                  __builtin_amdgcn_exp2f(sa1[sub][3]));
    }
    unsigned u00 = p0[0][0], w00 = p0[1][0];
    asm("v_permlane32_swap_b32 %0, %1" : "+v"(u00), "+v"(w00));
    unsigned u01 = p0[0][1], w01 = p0[1][1];
    asm("v_permlane32_swap_b32 %0, %1" : "+v"(u01), "+v"(w01));
    unsigned u02 = p0[2][0], w02 = p0[3][0];
    asm("v_permlane32_swap_b32 %0, %1" : "+v"(u02), "+v"(w02));
    unsigned u03 = p0[2][1], w03 = p0[3][1];
    asm("v_permlane32_swap_b32 %0, %1" : "+v"(u03), "+v"(w03));
    const short8 pf00 = frag4(u00, u01, w00, w01);
    const short8 pf01 = frag4(u02, u03, w02, w03);

    unsigned u10 = p1[0][0], w10 = p1[1][0];
    asm("v_permlane32_swap_b32 %0, %1" : "+v"(u10), "+v"(w10));
    unsigned u11 = p1[0][1], w11 = p1[1][1];
    asm("v_permlane32_swap_b32 %0, %1" : "+v"(u11), "+v"(w11));
    unsigned u12 = p1[2][0], w12 = p1[3][0];
    asm("v_permlane32_swap_b32 %0, %1" : "+v"(u12), "+v"(w12));
    unsigned u13 = p1[2][1], w13 = p1[3][1];
    asm("v_permlane32_swap_b32 %0, %1" : "+v"(u13), "+v"(w13));
    const short8 pf10 = frag4(u10, u11, w10, w11);
    const short8 pf11 = frag4(u12, u13, w12, w13);

    // ---- PV + row-sum MFMAs, both groups (pure-MFMA cluster; T5 setprio) ----
    __builtin_amdgcn_s_setprio(1);
    o00 = __builtin_amdgcn_mfma_f32_16x16x32_bf16(pf00, vf00, o00, 0, 0, 0);
    o00 = __builtin_amdgcn_mfma_f32_16x16x32_bf16(pf01, vf01, o00, 0, 0, 0);
    o01 = __builtin_amdgcn_mfma_f32_16x16x32_bf16(pf00, vf10, o01, 0, 0, 0);
    o01 = __builtin_amdgcn_mfma_f32_16x16x32_bf16(pf01, vf11, o01, 0, 0, 0);
    o10 = __builtin_amdgcn_mfma_f32_16x16x32_bf16(pf10, vf00, o10, 0, 0, 0);
    o10 = __builtin_amdgcn_mfma_f32_16x16x32_bf16(pf11, vf01, o10, 0, 0, 0);
    o11 = __builtin_amdgcn_mfma_f32_16x16x32_bf16(pf10, vf10, o11, 0, 0, 0);
    o11 = __builtin_amdgcn_mfma_f32_16x16x32_bf16(pf11, vf11, o11, 0, 0, 0);
    s0 = __builtin_amdgcn_mfma_f32_16x16x32_bf16(pf00, ones, s0, 0, 0, 0);
    s0 = __builtin_amdgcn_mfma_f32_16x16x32_bf16(pf01, ones, s0, 0, 0, 0);
    s1 = __builtin_amdgcn_mfma_f32_16x16x32_bf16(pf10, ones, s1, 0, 0, 0);
    s1 = __builtin_amdgcn_mfma_f32_16x16x32_bf16(pf11, ones, s1, 0, 0, 0);
    __builtin_amdgcn_s_setprio(0);
  }

  // ---- epilogue: atomic-accumulate partial (o, l) into Oacc/Lacc ----
#pragma unroll
  for (int g = 0; g < 2; ++g) {
    const f32x4 oS = g ? s1 : s0;
    const f32x4 oa = g ? o10 : o00;
    const f32x4 ob = g ? o11 : o01;
    const size_t row0 =
        (size_t)(b * NSEQ + qt * 128 + wave * 32 + g * 16 + quad * 4);
#pragma unroll
    for (int r = 0; r < 4; ++r) {
      const size_t ro = (row0 + r) * 256 + h * HDIM + l16;
      unsafeAtomicAdd(&Oacc[ro], oa[r]);
      unsafeAtomicAdd(&Oacc[ro + 16], ob[r]);
      if (l16 == 0) unsafeAtomicAdd(&Lacc[(row0 + r) * 8 + h], oS[r]);
    }
  }
}

extern "C" void kernel_launch(void* const* d_in, const int* in_sizes, int n_in,
                              void* d_out, int out_size, void* d_ws, size_t ws_size,
                              hipStream_t stream) {
  const float* x = (const float*)d_in[0];
  const float* y = (const float*)d_in[1];
  const float* Wq = (const float*)d_in[2];
  const float* bq = (const float*)d_in[3];
  const float* Wk = (const float*)d_in[4];
  const float* bk = (const float*)d_in[5];
  const float* Wv = (const float*)d_in[6];
  const float* bv = (const float*)d_in[7];
  const float* W1 = (const float*)d_in[8];
  const float* b1 = (const float*)d_in[9];
  const float* W2 = (const float*)d_in[10];
  const float* b2 = (const float*)d_in[11];
  const float* ln0g = (const float*)d_in[12];
  const float* ln0b = (const float*)d_in[13];
  const float* ln1g = (const float*)d_in[14];
  const float* ln1b = (const float*)d_in[15];
  float* out = (float*)d_out;
  char* base = (char*)d_ws;

  const size_t RM = (size_t)RTOT * 256;
  // region0 (32 MB): yh (bf16, stage0->qkv, 8MB) | Lacc @15.5MB (0.5MB) |
  //                  Oacc @16MB (16MB, split-K accum -> final O in-place)
  ushort* yh = (ushort*)base;
  float* Lacc = (float*)(base + 16252928);   // 16MB - 512KB
  float* Oacc = (float*)(base + 16777216);   // 16MB
  ushort* Qh = (ushort*)(base + 2 * RM * 4);
  ushort* Kh = (ushort*)(base + 2 * RM * 4 + RM * 2);
  ushort* VhT = (ushort*)(base + 3 * RM * 4);
  ushort* xh = (ushort*)(base + 3 * RM * 4 + RM * 2);  // LN0 out; reused as On
  ushort* Onh = xh;
  ushort* Hidh = Qh;  // [R,512] bf16 overlays Qh+Kh (dead after attn)
  char* wbase = base + 4 * RM * 4;
  ushort* Wqt = (ushort*)wbase;  // [256,256]
  ushort* Wkt = Wqt + 65536;
  ushort* Wvt = Wkt + 65536;
  ushort* W1t = Wvt + 65536;   // [512,256]
  ushort* W2t = W1t + 131072;  // [256,512]

  stage0_kernel<<<9360, 256, 0, stream>>>(x, y, Wq, Wk, Wv, W1, W2, ln0g, ln0b,
                                          Wqt, Wkt, Wvt, W1t, W2t, yh, xh,
                                          Lacc);
  qkv_kernel<<<dim3(128, 12), 256, 0, stream>>>(xh, yh, Wqt, Wkt, Wvt, bq, bk,
                                                bv, Qh, Kh, VhT);
  attn_kernel<<<2048, 256, 0, stream>>>(Qh, Kh, VhT, Oacc, Lacc);
  combine_ln_kernel<<<RTOT / 4, 256, 0, stream>>>(Qh, Oacc, Lacc, ln1g, ln1b,
                                                  Onh);
  mgemm_kernel<2><<<dim3(128, 8), 256, 0, stream>>>(Onh, W1t, b1, nullptr,
                                                    nullptr, Hidh, 256, 512);
  mgemm_kernel<3><<<dim3(128, 4), 256, 0, stream>>>(Hidh, W2t, b2, Oacc, out,
                                                    nullptr, 512, 256);
}

// Round 6
// 232.077 us; speedup vs baseline: 1.2066x; 1.0519x over previous
//
#include <hip/hip_runtime.h>
#include <math.h>

// Problem constants (B=8, N=2048, D_IN=D_V=256, H=8, HD=32, D_FF=512)
#define RTOT 16384   // B*N rows
#define NSEQ 2048
#define NHEAD 8
#define HDIM 32
// Q pre-scale: log2(e)/sqrt(256) so S_mfma = S_true*log2e, softmax via exp2
#define QSCALE 0.09017132252479462f
#define QINV (1.0f / QSCALE)

typedef __attribute__((ext_vector_type(8))) short short8;
typedef __attribute__((ext_vector_type(4))) float f32x4;
typedef __attribute__((ext_vector_type(4))) unsigned uint4v;

#define GLOBAL_AS(p) ((__attribute__((address_space(1))) void*)(p))
#define LDS_AS(p) ((__attribute__((address_space(3))) void*)(p))

__device__ __forceinline__ unsigned pack_bf16(float a, float b) {
  unsigned ua = __float_as_uint(a) + 0x8000u;
  unsigned ub = __float_as_uint(b) + 0x8000u;
  return (ua >> 16) | (ub & 0xffff0000u);
}
// truncating pack via byte-perm (positive values; bias cancels in softmax ratio)
// result = [a.b2,a.b3,b.b2,b.b3] : low16 = bf16(a), high16 = bf16(b)
__device__ __forceinline__ unsigned pack_bf16_perm(float a, float b) {
  return __builtin_amdgcn_perm(__float_as_uint(b), __float_as_uint(a),
                               0x07060302u);
}
__device__ __forceinline__ ushort bf16_1(float a) {
  return (ushort)((__float_as_uint(a) + 0x8000u) >> 16);
}
__device__ __forceinline__ float bf16_to_f(ushort u) {
  return __uint_as_float(((unsigned)u) << 16);
}
__device__ __forceinline__ short8 frag4(unsigned a0, unsigned a1, unsigned a2,
                                        unsigned a3) {
  uint4v t = {a0, a1, a2, a3};
  return __builtin_bit_cast(short8, t);
}

// ---------------- stage0: fused weight-transpose + cvt(y) + ln0(x) ----------------
// blocks [0,112): weight transpose; [112,4208): y->bf16; [4208,8304): LN0(x)->bf16
__global__ __launch_bounds__(256) void stage0_kernel(
    const float* __restrict__ x, const float* __restrict__ y,
    const float* __restrict__ Wq, const float* __restrict__ Wk,
    const float* __restrict__ Wv, const float* __restrict__ W1,
    const float* __restrict__ W2, const float* __restrict__ ln0g,
    const float* __restrict__ ln0b, ushort* __restrict__ Wqt,
    ushort* __restrict__ Wkt, ushort* __restrict__ Wvt,
    ushort* __restrict__ W1t, ushort* __restrict__ W2t,
    ushort* __restrict__ yh, ushort* __restrict__ xh) {
  const int bid = blockIdx.x;
  const int t = threadIdx.x;
  if (bid < 112) {
    const float* W;
    ushort* Wt;
    int K, N, tile;
    if (bid < 16) { W = Wq; Wt = Wqt; K = 256; N = 256; tile = bid; }
    else if (bid < 32) { W = Wk; Wt = Wkt; K = 256; N = 256; tile = bid - 16; }
    else if (bid < 48) { W = Wv; Wt = Wvt; K = 256; N = 256; tile = bid - 32; }
    else if (bid < 80) { W = W1; Wt = W1t; K = 256; N = 512; tile = bid - 48; }
    else { W = W2; Wt = W2t; K = 512; N = 256; tile = bid - 80; }
    const int tn = N >> 6;
    const int k0 = (tile / tn) << 6, n0 = (tile % tn) << 6;
    __shared__ float T[64][65];
#pragma unroll
    for (int i = 0; i < 16; ++i) {
      const int idx = t + i * 256;
      const int r = idx >> 6, c = idx & 63;
      T[r][c] = W[(size_t)(k0 + r) * N + n0 + c];
    }
    __syncthreads();
#pragma unroll
    for (int i = 0; i < 16; ++i) {
      const int idx = t + i * 256;
      const int r = idx >> 6, c = idx & 63;
      Wt[(size_t)(n0 + r) * K + k0 + c] = bf16_1(T[c][r]);
    }
  } else if (bid < 4208) {
    const size_t i = ((size_t)(bid - 112) * 256 + t) * 4;
    const float4 v = *(const float4*)&y[i];
    uint2 pk;
    pk.x = pack_bf16(v.x, v.y);
    pk.y = pack_bf16(v.z, v.w);
    *(uint2*)&yh[i] = pk;
  } else {
    const int lane = t & 63, wave = t >> 6;
    const size_t row = (size_t)(bid - 4208) * 4 + wave;
    const float* xr = x + row * 256;
    float4 v = *(const float4*)&xr[lane * 4];
    float s = v.x + v.y + v.z + v.w;
#pragma unroll
    for (int m = 1; m < 64; m <<= 1) s += __shfl_xor(s, m, 64);
    const float mu = s * (1.0f / 256.0f);
    const float dx = v.x - mu, dy = v.y - mu, dz = v.z - mu, dw = v.w - mu;
    float ss = dx * dx + dy * dy + dz * dz + dw * dw;
#pragma unroll
    for (int m = 1; m < 64; m <<= 1) ss += __shfl_xor(ss, m, 64);
    const float rstd = rsqrtf(ss * (1.0f / 256.0f) + 1e-5f);
    const float4 gv = *(const float4*)&ln0g[lane * 4];
    const float4 bv = *(const float4*)&ln0b[lane * 4];
    uint2 pk;
    pk.x = pack_bf16(dx * rstd * gv.x + bv.x, dy * rstd * gv.y + bv.y);
    pk.y = pack_bf16(dz * rstd * gv.z + bv.z, dw * rstd * gv.w + bv.w);
    *(uint2*)&xh[row * 256 + lane * 4] = pk;
  }
}

// ---------------- LayerNorm over D=256, bf16 output ----------------
__global__ __launch_bounds__(256) void ln_kernel(
    const float* __restrict__ X, const float* __restrict__ g,
    const float* __restrict__ bt, ushort* __restrict__ Yh) {
  const int lane = threadIdx.x & 63;
  const int wave = threadIdx.x >> 6;
  const size_t row = (size_t)blockIdx.x * 4 + wave;
  const float* xr = X + row * 256;
  float4 v = *(const float4*)&xr[lane * 4];
  float s = v.x + v.y + v.z + v.w;
#pragma unroll
  for (int m = 1; m < 64; m <<= 1) s += __shfl_xor(s, m, 64);
  const float mu = s * (1.0f / 256.0f);
  const float dx = v.x - mu, dy = v.y - mu, dz = v.z - mu, dw = v.w - mu;
  float ss = dx * dx + dy * dy + dz * dz + dw * dw;
#pragma unroll
  for (int m = 1; m < 64; m <<= 1) ss += __shfl_xor(ss, m, 64);
  const float rstd = rsqrtf(ss * (1.0f / 256.0f) + 1e-5f);
  const float4 gv = *(const float4*)&g[lane * 4];
  const float4 bv = *(const float4*)&bt[lane * 4];
  uint2 pk;
  pk.x = pack_bf16(dx * rstd * gv.x + bv.x, dy * rstd * gv.y + bv.y);
  pk.y = pack_bf16(dz * rstd * gv.z + bv.z, dw * rstd * gv.w + bv.w);
  *(uint2*)&Yh[row * 256 + lane * 4] = pk;
}

// ---------------- merged QKV GEMM, 128x128 tile, BK=32 ----------------
// grid (128, 6): ny>>1 = 0:K 1:V 2:Q ; n0 = (ny&1)*128 ; 4 waves (2x2).
// K: Kh=bf16(v) ; Q: Qh=bf16(v*QSCALE) ; V: transpose -> VhT[b*256+n][nseq]
__global__ __launch_bounds__(256) void qkv_kernel(
    const ushort* __restrict__ xh, const ushort* __restrict__ yh,
    const ushort* __restrict__ Wqt, const ushort* __restrict__ Wkt,
    const ushort* __restrict__ Wvt, const float* __restrict__ bq,
    const float* __restrict__ bk, const float* __restrict__ bv,
    ushort* __restrict__ Qh, ushort* __restrict__ Kh,
    ushort* __restrict__ VhT) {
  __shared__ union UU {
    struct { ushort As[128 * 32]; ushort Bs[128 * 32]; } s;
    ushort Ct[128 * 136];  // V-transpose tile [n_local][m_local], 34.8 KB
  } u;
  const int t = threadIdx.x;
  const int lane = t & 63, wave = t >> 6;
  const int l16 = lane & 15, quad = lane >> 4;
  const int row0 = blockIdx.x * 128;
  const int ny = blockIdx.y;
  const int which = ny >> 1;  // 0=K 1=V 2=Q
  const int n0 = (ny & 1) << 7;
  const ushort* A = (which == 2) ? xh : yh;
  const ushort* W = (which == 0) ? Wkt : (which == 1) ? Wvt : Wqt;
  const float* bs = (which == 0) ? bk : (which == 1) ? bv : bq;
  const int mrow = (wave & 1) * 64, ncol = (wave >> 1) * 64;

  const ushort* gA0 = A + (size_t)(row0 + (t >> 2)) * 256 + ((t & 3) << 3);
  const ushort* gA1 = gA0 + (size_t)64 * 256;
  const ushort* gB0 = W + (size_t)(n0 + (t >> 2)) * 256 + ((t & 3) << 3);
  const ushort* gB1 = gB0 + (size_t)64 * 256;
  ushort* lA0 = u.s.As + 8 * t;
  ushort* lA1 = u.s.As + 2048 + 8 * t;
  ushort* lB0 = u.s.Bs + 8 * t;
  ushort* lB1 = u.s.Bs + 2048 + 8 * t;

  f32x4 acc[4][4] = {};
  for (int kc = 0; kc < 256; kc += 32) {
    __builtin_amdgcn_global_load_lds(GLOBAL_AS(gA0 + kc), LDS_AS(lA0), 16, 0, 0);
    __builtin_amdgcn_global_load_lds(GLOBAL_AS(gA1 + kc), LDS_AS(lA1), 16, 0, 0);
    __builtin_amdgcn_global_load_lds(GLOBAL_AS(gB0 + kc), LDS_AS(lB0), 16, 0, 0);
    __builtin_amdgcn_global_load_lds(GLOBAL_AS(gB1 + kc), LDS_AS(lB1), 16, 0, 0);
    __syncthreads();
    short8 af[4], bfr[4];
#pragma unroll
    for (int mi = 0; mi < 4; ++mi)
      af[mi] = *(const short8*)&u.s.As[(mrow + mi * 16 + l16) * 32 + quad * 8];
#pragma unroll
    for (int nj = 0; nj < 4; ++nj)
      bfr[nj] = *(const short8*)&u.s.Bs[(ncol + nj * 16 + l16) * 32 + quad * 8];
#pragma unroll
    for (int mi = 0; mi < 4; ++mi)
#pragma unroll
      for (int nj = 0; nj < 4; ++nj)
        acc[mi][nj] = __builtin_amdgcn_mfma_f32_16x16x32_bf16(
            af[mi], bfr[nj], acc[mi][nj], 0, 0, 0);
    __syncthreads();
  }

  if (which == 1) {
    // V: bias + transpose via LDS, coalesced write to VhT[b*256+n][nseq]
#pragma unroll
    for (int nj = 0; nj < 4; ++nj) {
      const int nloc = ncol + nj * 16 + l16;
      const float bvv = bs[n0 + nloc];
#pragma unroll
      for (int mi = 0; mi < 4; ++mi)
#pragma unroll
        for (int r = 0; r < 4; ++r)
          u.Ct[nloc * 136 + mrow + mi * 16 + quad * 4 + r] =
              bf16_1(acc[mi][nj][r] + bvv);
    }
    __syncthreads();
    const int bb = row0 >> 11, ns0 = row0 & 2047;
#pragma unroll
    for (int i = 0; i < 8; ++i) {
      const int c = t + i * 256;
      const int rr = c >> 4, c8 = (c & 15) << 3;
      *(float4*)&VhT[(size_t)(bb * 256 + n0 + rr) * 2048 + ns0 + c8] =
          *(const float4*)&u.Ct[rr * 136 + c8];
    }
  } else {
#pragma unroll
    for (int nj = 0; nj < 4; ++nj) {
      const int n = n0 + ncol + nj * 16 + l16;
      const float bvv = bs[n];
#pragma unroll
      for (int mi = 0; mi < 4; ++mi) {
#pragma unroll
        for (int r = 0; r < 4; ++r) {
          const size_t m = (size_t)row0 + mrow + mi * 16 + quad * 4 + r;
          const float v = acc[mi][nj][r] + bvv;
          if (which == 2) Qh[m * 256 + n] = bf16_1(v * QSCALE);
          else Kh[m * 256 + n] = bf16_1(v);
        }
      }
    }
  }
}

// ---------------- FFN GEMM: 128x128 tile, BK=32 ----------------
// MODE 2: Ch=bf16(gelu(v)) (FFN1) ; MODE 3: Cf=v+res (FFN2 -> out)
template <int MODE>
__global__ __launch_bounds__(256) void mgemm_kernel(
    const ushort* __restrict__ A, const ushort* __restrict__ Wt,
    const float* __restrict__ bias, const float* __restrict__ res,
    float* __restrict__ Cf, ushort* __restrict__ Ch, int K, int N) {
  __shared__ ushort As[128 * 32];
  __shared__ ushort Bs[128 * 32];
  const int t = threadIdx.x;
  const int lane = t & 63, wave = t >> 6;
  const int l16 = lane & 15, quad = lane >> 4;
  const int row0 = blockIdx.x * 128;
  const int n0 = blockIdx.y << 7;
  const int mrow = (wave & 1) * 64, ncol = (wave >> 1) * 64;

  const ushort* gA0 = A + (size_t)(row0 + (t >> 2)) * K + ((t & 3) << 3);
  const ushort* gA1 = gA0 + (size_t)64 * K;
  const ushort* gB0 = Wt + (size_t)(n0 + (t >> 2)) * K + ((t & 3) << 3);
  const ushort* gB1 = gB0 + (size_t)64 * K;
  ushort* lA0 = As + 8 * t;
  ushort* lA1 = As + 2048 + 8 * t;
  ushort* lB0 = Bs + 8 * t;
  ushort* lB1 = Bs + 2048 + 8 * t;

  f32x4 acc[4][4] = {};
  for (int kc = 0; kc < K; kc += 32) {
    __builtin_amdgcn_global_load_lds(GLOBAL_AS(gA0 + kc), LDS_AS(lA0), 16, 0, 0);
    __builtin_amdgcn_global_load_lds(GLOBAL_AS(gA1 + kc), LDS_AS(lA1), 16, 0, 0);
    __builtin_amdgcn_global_load_lds(GLOBAL_AS(gB0 + kc), LDS_AS(lB0), 16, 0, 0);
    __builtin_amdgcn_global_load_lds(GLOBAL_AS(gB1 + kc), LDS_AS(lB1), 16, 0, 0);
    __syncthreads();
    short8 af[4], bfr[4];
#pragma unroll
    for (int mi = 0; mi < 4; ++mi)
      af[mi] = *(const short8*)&As[(mrow + mi * 16 + l16) * 32 + quad * 8];
#pragma unroll
    for (int nj = 0; nj < 4; ++nj)
      bfr[nj] = *(const short8*)&Bs[(ncol + nj * 16 + l16) * 32 + quad * 8];
#pragma unroll
    for (int mi = 0; mi < 4; ++mi)
#pragma unroll
      for (int nj = 0; nj < 4; ++nj)
        acc[mi][nj] = __builtin_amdgcn_mfma_f32_16x16x32_bf16(
            af[mi], bfr[nj], acc[mi][nj], 0, 0, 0);
    __syncthreads();
  }
#pragma unroll
  for (int nj = 0; nj < 4; ++nj) {
    const int n = n0 + ncol + nj * 16 + l16;
    const float bvv = bias[n];
#pragma unroll
    for (int mi = 0; mi < 4; ++mi) {
#pragma unroll
      for (int r = 0; r < 4; ++r) {
        const size_t m = (size_t)row0 + mrow + mi * 16 + quad * 4 + r;
        float v = acc[mi][nj][r] + bvv;
        if (MODE == 2) {
          v = 0.5f * v * (1.0f + erff(v * 0.70710678118654752f));
          Ch[m * N + n] = bf16_1(v);
        }
        if (MODE == 3) Cf[m * N + n] = v + res[m * N + n];
      }
    }
  }
}

// ---------------- Flash attention (bf16 MFMA, zero-max, 128q, pipelined groups) ----
// O = Q + softmax(Q K^T / 16) V.  Qh pre-scaled by log2(e)/16 (bf16); residual
// recovered as Qh/QSCALE. No max shift (p = exp2(S*log2e), ratio-invariant);
// l via ones-MFMA.  (round-1 verified structure, 66.5us)
// NOTE: VGPR=72 -> 128-reg granule -> 16 waves/CU cap regardless of grid; this
// formulation is occupancy-pinned (round-4: VGPR<=64 kills ILP; round-5:
// split-K adds atomics at same occupancy). Do not re-attempt without changing
// the register economy.
__global__ __launch_bounds__(256) void attn_kernel(
    const ushort* __restrict__ Qh, const ushort* __restrict__ Kh,
    const ushort* __restrict__ VhT, float* __restrict__ O) {
  __shared__ ushort Ks[2][64][40];  // 10240 B
  __shared__ ushort Vt[2][32][72];  // 9216 B

  const int t = threadIdx.x;
  const int lane = t & 63, wave = t >> 6;
  const int l16 = lane & 15, quad = lane >> 4;
  const int bh = blockIdx.x & 63;
  const int qt = blockIdx.x >> 6;  // 0..15
  const int b = bh >> 3, h = bh & 7;

  const size_t rowQ0 = (size_t)(b * NSEQ + qt * 128 + wave * 32 + l16);
  const short8 qfrag0 = *(const short8*)&Qh[rowQ0 * 256 + h * HDIM + quad * 8];
  const short8 qfrag1 =
      *(const short8*)&Qh[(rowQ0 + 16) * 256 + h * HDIM + quad * 8];
  const short8 ones = {16256, 16256, 16256, 16256,
                       16256, 16256, 16256, 16256};  // bf16 1.0 x8
  const f32x4 zf = {0.f, 0.f, 0.f, 0.f};

  f32x4 o00 = zf, o01 = zf, o10 = zf, o11 = zf;
  f32x4 s0 = zf, s1 = zf;

  // staging coords (cooperative, coalesced): K tile [64][32], V tile [32][64]
  // K rows land permuted: LDS row p holds logical key with bits 2<=>3 swapped
  // (self-inverse), which makes the post-QK^T lane shuffle permlane32-only.
  const int kr = t >> 2, kc8 = (t & 3) << 3;
  const int krL = (kr & ~12) | ((kr & 4) << 1) | ((kr & 8) >> 1);
  const int vd = t >> 3, vc8 = (t & 7) << 3;
  const ushort* gK = Kh + ((size_t)(b * NSEQ + krL)) * 256 + h * HDIM + kc8;
  const ushort* gV = VhT + ((size_t)(bh * 32 + vd)) * 2048 + vc8;

  float4 kreg = *(const float4*)gK;
  float4 vreg = *(const float4*)gV;

  for (int kt = 0; kt < 32; ++kt) {
    const int bf = kt & 1;
    *(float4*)&Ks[bf][kr][kc8] = kreg;
    *(float4*)&Vt[bf][vd][vc8] = vreg;
    __syncthreads();  // buf visible; prev readers done (prev barrier)
    if (kt < 31) {    // register prefetch, in flight over compute
      kreg = *(const float4*)(gK + (size_t)(kt + 1) * 64 * 256);
      vreg = *(const float4*)(gV + (kt + 1) * 64);
    }

    // shared fragments for both q-groups (wave-independent LDS reads)
    short8 kf[4];
#pragma unroll
    for (int sub = 0; sub < 4; ++sub)
      kf[sub] = *(const short8*)&Ks[bf][sub * 16 + l16][quad * 8];
    const short8 vf00 = *(const short8*)&Vt[bf][l16][quad * 8];
    const short8 vf01 = *(const short8*)&Vt[bf][l16][32 + quad * 8];
    const short8 vf10 = *(const short8*)&Vt[bf][16 + l16][quad * 8];
    const short8 vf11 = *(const short8*)&Vt[bf][16 + l16][32 + quad * 8];

    // ---- S-MFMAs for BOTH groups (MFMA latency overlaps exp2 below) ----
    f32x4 sa0[4], sa1[4];
#pragma unroll
    for (int sub = 0; sub < 4; ++sub)
      sa0[sub] =
          __builtin_amdgcn_mfma_f32_16x16x32_bf16(kf[sub], qfrag0, zf, 0, 0, 0);
#pragma unroll
    for (int sub = 0; sub < 4; ++sub)
      sa1[sub] =
          __builtin_amdgcn_mfma_f32_16x16x32_bf16(kf[sub], qfrag1, zf, 0, 0, 0);

    // ---- exp2 + pack + in-register route (permlane32 swap) ----
    unsigned p0[4][2], p1[4][2];
#pragma unroll
    for (int sub = 0; sub < 4; ++sub) {
      p0[sub][0] = pack_bf16_perm(__builtin_amdgcn_exp2f(sa0[sub][0]),
                                  __builtin_amdgcn_exp2f(sa0[sub][1]));
      p0[sub][1] = pack_bf16_perm(__builtin_amdgcn_exp2f(sa0[sub][2]),
                                  __builtin_amdgcn_exp2f(sa0[sub][3]));
    }
#pragma unroll
    for (int sub = 0; sub < 4; ++sub) {
      p1[sub][0] = pack_bf16_perm(__builtin_amdgcn_exp2f(sa1[sub][0]),
                                  __builtin_amdgcn_exp2f(sa1[sub][1]));
      p1[sub][1] = pack_bf16_perm(__builtin_amdgcn_exp2f(sa1[sub][2]),
                                  __builtin_amdgcn_exp2f(sa1[sub][3]));
    }
    unsigned u00 = p0[0][0], w00 = p0[1][0];
    asm("v_permlane32_swap_b32 %0, %1" : "+v"(u00), "+v"(w00));
    unsigned u01 = p0[0][1], w01 = p0[1][1];
    asm("v_permlane32_swap_b32 %0, %1" : "+v"(u01), "+v"(w01));
    unsigned u02 = p0[2][0], w02 = p0[3][0];
    asm("v_permlane32_swap_b32 %0, %1" : "+v"(u02), "+v"(w02));
    unsigned u03 = p0[2][1], w03 = p0[3][1];
    asm("v_permlane32_swap_b32 %0, %1" : "+v"(u03), "+v"(w03));
    const short8 pf00 = frag4(u00, u01, w00, w01);
    const short8 pf01 = frag4(u02, u03, w02, w03);

    unsigned u10 = p1[0][0], w10 = p1[1][0];
    asm("v_permlane32_swap_b32 %0, %1" : "+v"(u10), "+v"(w10));
    unsigned u11 = p1[0][1], w11 = p1[1][1];
    asm("v_permlane32_swap_b32 %0, %1" : "+v"(u11), "+v"(w11));
    unsigned u12 = p1[2][0], w12 = p1[3][0];
    asm("v_permlane32_swap_b32 %0, %1" : "+v"(u12), "+v"(w12));
    unsigned u13 = p1[2][1], w13 = p1[3][1];
    asm("v_permlane32_swap_b32 %0, %1" : "+v"(u13), "+v"(w13));
    const short8 pf10 = frag4(u10, u11, w10, w11);
    const short8 pf11 = frag4(u12, u13, w12, w13);

    // ---- PV + row-sum MFMAs, both groups ----
    o00 = __builtin_amdgcn_mfma_f32_16x16x32_bf16(pf00, vf00, o00, 0, 0, 0);
    o00 = __builtin_amdgcn_mfma_f32_16x16x32_bf16(pf01, vf01, o00, 0, 0, 0);
    o01 = __builtin_amdgcn_mfma_f32_16x16x32_bf16(pf00, vf10, o01, 0, 0, 0);
    o01 = __builtin_amdgcn_mfma_f32_16x16x32_bf16(pf01, vf11, o01, 0, 0, 0);
    o10 = __builtin_amdgcn_mfma_f32_16x16x32_bf16(pf10, vf00, o10, 0, 0, 0);
    o10 = __builtin_amdgcn_mfma_f32_16x16x32_bf16(pf11, vf01, o10, 0, 0, 0);
    o11 = __builtin_amdgcn_mfma_f32_16x16x32_bf16(pf10, vf10, o11, 0, 0, 0);
    o11 = __builtin_amdgcn_mfma_f32_16x16x32_bf16(pf11, vf11, o11, 0, 0, 0);
    s0 = __builtin_amdgcn_mfma_f32_16x16x32_bf16(pf00, ones, s0, 0, 0, 0);
    s0 = __builtin_amdgcn_mfma_f32_16x16x32_bf16(pf01, ones, s0, 0, 0, 0);
    s1 = __builtin_amdgcn_mfma_f32_16x16x32_bf16(pf10, ones, s1, 0, 0, 0);
    s1 = __builtin_amdgcn_mfma_f32_16x16x32_bf16(pf11, ones, s1, 0, 0, 0);
  }

  // ---- epilogue: O = Q + oacc/l ; Q re-read directly (L2-hot) ----
#pragma unroll
  for (int g = 0; g < 2; ++g) {
    const f32x4 oS = g ? s1 : s0;
    const f32x4 oa = g ? o10 : o00;
    const f32x4 ob = g ? o11 : o01;
    const size_t row0 =
        (size_t)(b * NSEQ + qt * 128 + wave * 32 + g * 16 + quad * 4);
#pragma unroll
    for (int r = 0; r < 4; ++r) {
      const float il = 1.0f / oS[r];
      const size_t ro = (row0 + r) * 256 + h * HDIM + l16;
      O[ro] = bf16_to_f(Qh[ro]) * QINV + oa[r] * il;
      O[ro + 16] = bf16_to_f(Qh[ro + 16]) * QINV + ob[r] * il;
    }
  }
}

extern "C" void kernel_launch(void* const* d_in, const int* in_sizes, int n_in,
                              void* d_out, int out_size, void* d_ws, size_t ws_size,
                              hipStream_t stream) {
  const float* x = (const float*)d_in[0];
  const float* y = (const float*)d_in[1];
  const float* Wq = (const float*)d_in[2];
  const float* bq = (const float*)d_in[3];
  const float* Wk = (const float*)d_in[4];
  const float* bk = (const float*)d_in[5];
  const float* Wv = (const float*)d_in[6];
  const float* bv = (const float*)d_in[7];
  const float* W1 = (const float*)d_in[8];
  const float* b1 = (const float*)d_in[9];
  const float* W2 = (const float*)d_in[10];
  const float* b2 = (const float*)d_in[11];
  const float* ln0g = (const float*)d_in[12];
  const float* ln0b = (const float*)d_in[13];
  const float* ln1g = (const float*)d_in[14];
  const float* ln1b = (const float*)d_in[15];
  float* out = (float*)d_out;
  char* base = (char*)d_ws;

  const size_t RM = (size_t)RTOT * 256;
  // region0: yh (bf16, stage0->qkv) then overwritten by Ob (fp32, attn out)
  ushort* yh = (ushort*)base;
  float* Ob = (float*)base;
  ushort* Qh = (ushort*)(base + 2 * RM * 4);
  ushort* Kh = (ushort*)(base + 2 * RM * 4 + RM * 2);
  ushort* VhT = (ushort*)(base + 3 * RM * 4);
  ushort* xh = (ushort*)(base + 3 * RM * 4 + RM * 2);  // LN0 out; reused as On
  ushort* Onh = xh;
  ushort* Hidh = Qh;  // [R,512] bf16 overlays Qh+Kh (dead after attn)
  char* wbase = base + 4 * RM * 4;
  ushort* Wqt = (ushort*)wbase;  // [256,256]
  ushort* Wkt = Wqt + 65536;
  ushort* Wvt = Wkt + 65536;
  ushort* W1t = Wvt + 65536;   // [512,256]
  ushort* W2t = W1t + 131072;  // [256,512]

  stage0_kernel<<<8304, 256, 0, stream>>>(x, y, Wq, Wk, Wv, W1, W2, ln0g, ln0b,
                                          Wqt, Wkt, Wvt, W1t, W2t, yh, xh);
  qkv_kernel<<<dim3(128, 6), 256, 0, stream>>>(xh, yh, Wqt, Wkt, Wvt, bq, bk,
                                               bv, Qh, Kh, VhT);
  attn_kernel<<<1024, 256, 0, stream>>>(Qh, Kh, VhT, Ob);
  ln_kernel<<<RTOT / 4, 256, 0, stream>>>(Ob, ln1g, ln1b, Onh);
  mgemm_kernel<2><<<dim3(128, 4), 256, 0, stream>>>(Onh, W1t, b1, nullptr,
                                                    nullptr, Hidh, 256, 512);
  mgemm_kernel<3><<<dim3(128, 2), 256, 0, stream>>>(Hidh, W2t, b2, Ob, out,
                                                    nullptr, 512, 256);
}

// Round 7
// 216.120 us; speedup vs baseline: 1.2957x; 1.0738x over previous
//
#include <hip/hip_runtime.h>
#include <math.h>

// Problem constants (B=8, N=2048, D_IN=D_V=256, H=8, HD=32, D_FF=512)
#define RTOT 16384   // B*N rows
#define NSEQ 2048
#define NHEAD 8
#define HDIM 32
// Q pre-scale: log2(e)/sqrt(256) so S_mfma = S_true*log2e, softmax via exp2
#define QSCALE 0.09017132252479462f
#define QINV (1.0f / QSCALE)

typedef __attribute__((ext_vector_type(8))) short short8;
typedef __attribute__((ext_vector_type(4))) float f32x4;
typedef __attribute__((ext_vector_type(4))) unsigned uint4v;

#define GLOBAL_AS(p) ((__attribute__((address_space(1))) void*)(p))
#define LDS_AS(p) ((__attribute__((address_space(3))) void*)(p))

__device__ __forceinline__ unsigned pack_bf16(float a, float b) {
  unsigned ua = __float_as_uint(a) + 0x8000u;
  unsigned ub = __float_as_uint(b) + 0x8000u;
  return (ua >> 16) | (ub & 0xffff0000u);
}
// truncating pack via byte-perm (positive values; bias cancels in softmax ratio)
// result = [a.b2,a.b3,b.b2,b.b3] : low16 = bf16(a), high16 = bf16(b)
__device__ __forceinline__ unsigned pack_bf16_perm(float a, float b) {
  return __builtin_amdgcn_perm(__float_as_uint(b), __float_as_uint(a),
                               0x07060302u);
}
__device__ __forceinline__ ushort bf16_1(float a) {
  return (ushort)((__float_as_uint(a) + 0x8000u) >> 16);
}
__device__ __forceinline__ float bf16_to_f(ushort u) {
  return __uint_as_float(((unsigned)u) << 16);
}
__device__ __forceinline__ short8 frag4(unsigned a0, unsigned a1, unsigned a2,
                                        unsigned a3) {
  uint4v t = {a0, a1, a2, a3};
  return __builtin_bit_cast(short8, t);
}

// ---------------- stage0: fused weight-transpose + cvt(y) + ln0(x) ----------------
// blocks [0,112): weight transpose; [112,4208): y->bf16; [4208,8304): LN0(x)->bf16
__global__ __launch_bounds__(256) void stage0_kernel(
    const float* __restrict__ x, const float* __restrict__ y,
    const float* __restrict__ Wq, const float* __restrict__ Wk,
    const float* __restrict__ Wv, const float* __restrict__ W1,
    const float* __restrict__ W2, const float* __restrict__ ln0g,
    const float* __restrict__ ln0b, ushort* __restrict__ Wqt,
    ushort* __restrict__ Wkt, ushort* __restrict__ Wvt,
    ushort* __restrict__ W1t, ushort* __restrict__ W2t,
    ushort* __restrict__ yh, ushort* __restrict__ xh) {
  const int bid = blockIdx.x;
  const int t = threadIdx.x;
  if (bid < 112) {
    const float* W;
    ushort* Wt;
    int K, N, tile;
    if (bid < 16) { W = Wq; Wt = Wqt; K = 256; N = 256; tile = bid; }
    else if (bid < 32) { W = Wk; Wt = Wkt; K = 256; N = 256; tile = bid - 16; }
    else if (bid < 48) { W = Wv; Wt = Wvt; K = 256; N = 256; tile = bid - 32; }
    else if (bid < 80) { W = W1; Wt = W1t; K = 256; N = 512; tile = bid - 48; }
    else { W = W2; Wt = W2t; K = 512; N = 256; tile = bid - 80; }
    const int tn = N >> 6;
    const int k0 = (tile / tn) << 6, n0 = (tile % tn) << 6;
    __shared__ float T[64][65];
#pragma unroll
    for (int i = 0; i < 16; ++i) {
      const int idx = t + i * 256;
      const int r = idx >> 6, c = idx & 63;
      T[r][c] = W[(size_t)(k0 + r) * N + n0 + c];
    }
    __syncthreads();
#pragma unroll
    for (int i = 0; i < 16; ++i) {
      const int idx = t + i * 256;
      const int r = idx >> 6, c = idx & 63;
      Wt[(size_t)(n0 + r) * K + k0 + c] = bf16_1(T[c][r]);
    }
  } else if (bid < 4208) {
    const size_t i = ((size_t)(bid - 112) * 256 + t) * 4;
    const float4 v = *(const float4*)&y[i];
    uint2 pk;
    pk.x = pack_bf16(v.x, v.y);
    pk.y = pack_bf16(v.z, v.w);
    *(uint2*)&yh[i] = pk;
  } else {
    const int lane = t & 63, wave = t >> 6;
    const size_t row = (size_t)(bid - 4208) * 4 + wave;
    const float* xr = x + row * 256;
    float4 v = *(const float4*)&xr[lane * 4];
    float s = v.x + v.y + v.z + v.w;
#pragma unroll
    for (int m = 1; m < 64; m <<= 1) s += __shfl_xor(s, m, 64);
    const float mu = s * (1.0f / 256.0f);
    const float dx = v.x - mu, dy = v.y - mu, dz = v.z - mu, dw = v.w - mu;
    float ss = dx * dx + dy * dy + dz * dz + dw * dw;
#pragma unroll
    for (int m = 1; m < 64; m <<= 1) ss += __shfl_xor(ss, m, 64);
    const float rstd = rsqrtf(ss * (1.0f / 256.0f) + 1e-5f);
    const float4 gv = *(const float4*)&ln0g[lane * 4];
    const float4 bv = *(const float4*)&ln0b[lane * 4];
    uint2 pk;
    pk.x = pack_bf16(dx * rstd * gv.x + bv.x, dy * rstd * gv.y + bv.y);
    pk.y = pack_bf16(dz * rstd * gv.z + bv.z, dw * rstd * gv.w + bv.w);
    *(uint2*)&xh[row * 256 + lane * 4] = pk;
  }
}

// ---------------- LayerNorm over D=256, bf16 output ----------------
__global__ __launch_bounds__(256) void ln_kernel(
    const float* __restrict__ X, const float* __restrict__ g,
    const float* __restrict__ bt, ushort* __restrict__ Yh) {
  const int lane = threadIdx.x & 63;
  const int wave = threadIdx.x >> 6;
  const size_t row = (size_t)blockIdx.x * 4 + wave;
  const float* xr = X + row * 256;
  float4 v = *(const float4*)&xr[lane * 4];
  float s = v.x + v.y + v.z + v.w;
#pragma unroll
  for (int m = 1; m < 64; m <<= 1) s += __shfl_xor(s, m, 64);
  const float mu = s * (1.0f / 256.0f);
  const float dx = v.x - mu, dy = v.y - mu, dz = v.z - mu, dw = v.w - mu;
  float ss = dx * dx + dy * dy + dz * dz + dw * dw;
#pragma unroll
  for (int m = 1; m < 64; m <<= 1) ss += __shfl_xor(ss, m, 64);
  const float rstd = rsqrtf(ss * (1.0f / 256.0f) + 1e-5f);
  const float4 gv = *(const float4*)&g[lane * 4];
  const float4 bv = *(const float4*)&bt[lane * 4];
  uint2 pk;
  pk.x = pack_bf16(dx * rstd * gv.x + bv.x, dy * rstd * gv.y + bv.y);
  pk.y = pack_bf16(dz * rstd * gv.z + bv.z, dw * rstd * gv.w + bv.w);
  *(uint2*)&Yh[row * 256 + lane * 4] = pk;
}

// ---------------- merged QKV GEMM ----------------
// grid (128, 12): ny>>2 = 0:K 1:V 2:Q ; 128x64 tile, BK=32, 4 waves.
// K: Kh=bf16(v) ; Q: Qh=bf16(v*QSCALE) ; V: transpose -> VhT[b*256+n][nseq]
__global__ __launch_bounds__(256) void qkv_kernel(
    const ushort* __restrict__ xh, const ushort* __restrict__ yh,
    const ushort* __restrict__ Wqt, const ushort* __restrict__ Wkt,
    const ushort* __restrict__ Wvt, const float* __restrict__ bq,
    const float* __restrict__ bk, const float* __restrict__ bv,
    ushort* __restrict__ Qh, ushort* __restrict__ Kh,
    ushort* __restrict__ VhT) {
  __shared__ union UU {
    struct { ushort As[128 * 32]; ushort Bs[64 * 32]; } s;
    ushort Ct[64 * 136];  // V-transpose tile [n_local][m_local]
  } u;
  const int t = threadIdx.x;
  const int lane = t & 63, wave = t >> 6;
  const int l16 = lane & 15, quad = lane >> 4;
  const int row0 = blockIdx.x * 128;
  const int ny = blockIdx.y;
  const int which = ny >> 2;  // 0=K 1=V 2=Q
  const int n0 = (ny & 3) << 6;
  const ushort* A = (which == 2) ? xh : yh;
  const ushort* W = (which == 0) ? Wkt : (which == 1) ? Wvt : Wqt;
  const float* bs = (which == 0) ? bk : (which == 1) ? bv : bq;
  const int mrow = (wave & 1) * 64, ncol = (wave >> 1) * 32;

  const ushort* gA0 = A + (size_t)(row0 + (t >> 2)) * 256 + ((t & 3) << 3);
  const ushort* gA1 = gA0 + (size_t)64 * 256;
  const ushort* gB = W + (size_t)(n0 + (t >> 2)) * 256 + ((t & 3) << 3);
  ushort* lA0 = u.s.As + 8 * t;
  ushort* lA1 = u.s.As + 2048 + 8 * t;
  ushort* lB = u.s.Bs + 8 * t;

  f32x4 acc[4][2] = {};
  for (int kc = 0; kc < 256; kc += 32) {
    __builtin_amdgcn_global_load_lds(GLOBAL_AS(gA0 + kc), LDS_AS(lA0), 16, 0, 0);
    __builtin_amdgcn_global_load_lds(GLOBAL_AS(gA1 + kc), LDS_AS(lA1), 16, 0, 0);
    __builtin_amdgcn_global_load_lds(GLOBAL_AS(gB + kc), LDS_AS(lB), 16, 0, 0);
    __syncthreads();
    short8 af[4], bfr[2];
#pragma unroll
    for (int mi = 0; mi < 4; ++mi)
      af[mi] = *(const short8*)&u.s.As[(mrow + mi * 16 + l16) * 32 + quad * 8];
#pragma unroll
    for (int nj = 0; nj < 2; ++nj)
      bfr[nj] = *(const short8*)&u.s.Bs[(ncol + nj * 16 + l16) * 32 + quad * 8];
#pragma unroll
    for (int mi = 0; mi < 4; ++mi)
#pragma unroll
      for (int nj = 0; nj < 2; ++nj)
        acc[mi][nj] = __builtin_amdgcn_mfma_f32_16x16x32_bf16(
            af[mi], bfr[nj], acc[mi][nj], 0, 0, 0);
    __syncthreads();
  }

  if (which == 1) {
    // V: bias + transpose via LDS, coalesced write to VhT[b*256+n][nseq]
#pragma unroll
    for (int nj = 0; nj < 2; ++nj) {
      const int nloc = ncol + nj * 16 + l16;
      const float bvv = bs[n0 + nloc];
#pragma unroll
      for (int mi = 0; mi < 4; ++mi)
#pragma unroll
        for (int r = 0; r < 4; ++r)
          u.Ct[nloc * 136 + mrow + mi * 16 + quad * 4 + r] =
              bf16_1(acc[mi][nj][r] + bvv);
    }
    __syncthreads();
    const int bb = row0 >> 11, ns0 = row0 & 2047;
#pragma unroll
    for (int i = 0; i < 4; ++i) {
      const int c = t + i * 256;
      const int rr = c >> 4, c8 = (c & 15) << 3;
      *(float4*)&VhT[(size_t)(bb * 256 + n0 + rr) * 2048 + ns0 + c8] =
          *(const float4*)&u.Ct[rr * 136 + c8];
    }
  } else {
#pragma unroll
    for (int nj = 0; nj < 2; ++nj) {
      const int n = n0 + ncol + nj * 16 + l16;
      const float bvv = bs[n];
#pragma unroll
      for (int mi = 0; mi < 4; ++mi) {
#pragma unroll
        for (int r = 0; r < 4; ++r) {
          const size_t m = (size_t)row0 + mrow + mi * 16 + quad * 4 + r;
          const float v = acc[mi][nj][r] + bvv;
          if (which == 2) Qh[m * 256 + n] = bf16_1(v * QSCALE);
          else Kh[m * 256 + n] = bf16_1(v);
        }
      }
    }
  }
}

// ---------------- FFN GEMM: 128x64 tile, BK=32 ----------------
// MODE 2: Ch=bf16(gelu(v)) (FFN1) ; MODE 3: Cf=v+res (FFN2 -> out)
template <int MODE>
__global__ __launch_bounds__(256) void mgemm_kernel(
    const ushort* __restrict__ A, const ushort* __restrict__ Wt,
    const float* __restrict__ bias, const float* __restrict__ res,
    float* __restrict__ Cf, ushort* __restrict__ Ch, int K, int N) {
  __shared__ ushort As[128 * 32];
  __shared__ ushort Bs[64 * 32];
  const int t = threadIdx.x;
  const int lane = t & 63, wave = t >> 6;
  const int l16 = lane & 15, quad = lane >> 4;
  const int row0 = blockIdx.x * 128;
  const int n0 = blockIdx.y << 6;
  const int mrow = (wave & 1) * 64, ncol = (wave >> 1) * 32;

  const ushort* gA0 = A + (size_t)(row0 + (t >> 2)) * K + ((t & 3) << 3);
  const ushort* gA1 = gA0 + (size_t)64 * K;
  const ushort* gB = Wt + (size_t)(n0 + (t >> 2)) * K + ((t & 3) << 3);
  ushort* lA0 = As + 8 * t;
  ushort* lA1 = As + 2048 + 8 * t;
  ushort* lB = Bs + 8 * t;

  f32x4 acc[4][2] = {};
  for (int kc = 0; kc < K; kc += 32) {
    __builtin_amdgcn_global_load_lds(GLOBAL_AS(gA0 + kc), LDS_AS(lA0), 16, 0, 0);
    __builtin_amdgcn_global_load_lds(GLOBAL_AS(gA1 + kc), LDS_AS(lA1), 16, 0, 0);
    __builtin_amdgcn_global_load_lds(GLOBAL_AS(gB + kc), LDS_AS(lB), 16, 0, 0);
    __syncthreads();
    short8 af[4], bfr[2];
#pragma unroll
    for (int mi = 0; mi < 4; ++mi)
      af[mi] = *(const short8*)&As[(mrow + mi * 16 + l16) * 32 + quad * 8];
#pragma unroll
    for (int nj = 0; nj < 2; ++nj)
      bfr[nj] = *(const short8*)&Bs[(ncol + nj * 16 + l16) * 32 + quad * 8];
#pragma unroll
    for (int mi = 0; mi < 4; ++mi)
#pragma unroll
      for (int nj = 0; nj < 2; ++nj)
        acc[mi][nj] = __builtin_amdgcn_mfma_f32_16x16x32_bf16(
            af[mi], bfr[nj], acc[mi][nj], 0, 0, 0);
    __syncthreads();
  }
#pragma unroll
  for (int nj = 0; nj < 2; ++nj) {
    const int n = n0 + ncol + nj * 16 + l16;
    const float bvv = bias[n];
#pragma unroll
    for (int mi = 0; mi < 4; ++mi) {
#pragma unroll
      for (int r = 0; r < 4; ++r) {
        const size_t m = (size_t)row0 + mrow + mi * 16 + quad * 4 + r;
        float v = acc[mi][nj][r] + bvv;
        if (MODE == 2) {
          v = 0.5f * v * (1.0f + erff(v * 0.70710678118654752f));
          Ch[m * N + n] = bf16_1(v);
        }
        if (MODE == 3) Cf[m * N + n] = v + res[m * N + n];
      }
    }
  }
}

// ---------------- Flash attention (bf16 MFMA, zero-max, 128q, KVBLK=128) ----
// O = Q + softmax(Q K^T / 16) V.  Qh pre-scaled by log2(e)/16 (bf16); residual
// recovered as Qh/QSCALE. No max shift (p = exp2(S*log2e), ratio-invariant);
// l via ones-MFMA.  Round-1 structure (128q, 4 waves, 2 q-groups/wave) with
// KVBLK widened 64->128: one barrier per 128 keys (half the lockstep rate),
// inner 64-key body repeated twice per buffer. LDS 37.9KB -> 4 blocks/CU
// (unchanged: VGPR in (64,128] pins 16 waves/CU regardless). T5 setprio wraps
// the PV MFMA clusters (blocks are mutually unsynchronized => T5 regime).
// K rows staged with bits 2<=>3 swapped so P routing is permlane32-only.
__global__ __launch_bounds__(256) void attn_kernel(
    const ushort* __restrict__ Qh, const ushort* __restrict__ Kh,
    const ushort* __restrict__ VhT, float* __restrict__ O) {
  __shared__ ushort Ks[2][128][40];  // 20480 B
  __shared__ ushort Vt[2][32][136];  // 17408 B (total 37888)

  const int t = threadIdx.x;
  const int lane = t & 63, wave = t >> 6;
  const int l16 = lane & 15, quad = lane >> 4;
  const int bh = blockIdx.x & 63;
  const int qt = blockIdx.x >> 6;  // 0..15
  const int b = bh >> 3, h = bh & 7;

  const size_t rowQ0 = (size_t)(b * NSEQ + qt * 128 + wave * 32 + l16);
  const short8 qfrag0 = *(const short8*)&Qh[rowQ0 * 256 + h * HDIM + quad * 8];
  const short8 qfrag1 =
      *(const short8*)&Qh[(rowQ0 + 16) * 256 + h * HDIM + quad * 8];
  const short8 ones = {16256, 16256, 16256, 16256,
                       16256, 16256, 16256, 16256};  // bf16 1.0 x8
  const f32x4 zf = {0.f, 0.f, 0.f, 0.f};

  f32x4 o00 = zf, o01 = zf, o10 = zf, o11 = zf;
  f32x4 s0 = zf, s1 = zf;

  // staging coords (cooperative, coalesced): K tile [128][32], V tile [32][128]
  // K rows land permuted: LDS row p holds logical key with bits 2<=>3 swapped
  // (self-inverse; commutes with +64), making the post-QK^T shuffle
  // permlane32-only.
  const int kr = t >> 2, kc8 = (t & 3) << 3;
  const int krL = (kr & ~12) | ((kr & 4) << 1) | ((kr & 8) >> 1);
  const int vd = t >> 3, vc8 = (t & 7) << 3;
  const ushort* gK = Kh + ((size_t)(b * NSEQ + krL)) * 256 + h * HDIM + kc8;
  const ushort* gK2 = gK + (size_t)64 * 256;
  const ushort* gV = VhT + ((size_t)(bh * 32 + vd)) * 2048 + vc8;

  float4 kreg0 = *(const float4*)gK;
  float4 kreg1 = *(const float4*)gK2;
  float4 vreg0 = *(const float4*)gV;
  float4 vreg1 = *(const float4*)(gV + 64);

  for (int kt = 0; kt < 16; ++kt) {
    const int bf = kt & 1;
    *(float4*)&Ks[bf][kr][kc8] = kreg0;
    *(float4*)&Ks[bf][64 + kr][kc8] = kreg1;
    *(float4*)&Vt[bf][vd][vc8] = vreg0;
    *(float4*)&Vt[bf][vd][64 + vc8] = vreg1;
    __syncthreads();  // buf visible; prev readers done (prev barrier)
    if (kt < 15) {    // register prefetch, in flight over compute
      const size_t ko = (size_t)(kt + 1) * 128 * 256;
      kreg0 = *(const float4*)(gK + ko);
      kreg1 = *(const float4*)(gK2 + ko);
      vreg0 = *(const float4*)(gV + (kt + 1) * 128);
      vreg1 = *(const float4*)(gV + (kt + 1) * 128 + 64);
    }

#pragma unroll
    for (int half = 0; half < 2; ++half) {
      const int r0 = half * 64;   // key-row base in Ks
      const int c0 = half * 64;   // key-col base in Vt

      // shared fragments for both q-groups (wave-independent LDS reads)
      short8 kf[4];
#pragma unroll
      for (int sub = 0; sub < 4; ++sub)
        kf[sub] = *(const short8*)&Ks[bf][r0 + sub * 16 + l16][quad * 8];
      const short8 vf00 = *(const short8*)&Vt[bf][l16][c0 + quad * 8];
      const short8 vf01 = *(const short8*)&Vt[bf][l16][c0 + 32 + quad * 8];
      const short8 vf10 = *(const short8*)&Vt[bf][16 + l16][c0 + quad * 8];
      const short8 vf11 = *(const short8*)&Vt[bf][16 + l16][c0 + 32 + quad * 8];

      // ---- S-MFMAs for BOTH groups (MFMA latency overlaps exp2 below) ----
      f32x4 sa0[4], sa1[4];
#pragma unroll
      for (int sub = 0; sub < 4; ++sub)
        sa0[sub] = __builtin_amdgcn_mfma_f32_16x16x32_bf16(kf[sub], qfrag0, zf,
                                                           0, 0, 0);
#pragma unroll
      for (int sub = 0; sub < 4; ++sub)
        sa1[sub] = __builtin_amdgcn_mfma_f32_16x16x32_bf16(kf[sub], qfrag1, zf,
                                                           0, 0, 0);

      // ---- exp2 + pack + in-register route (permlane32 swap) ----
      unsigned p0[4][2], p1[4][2];
#pragma unroll
      for (int sub = 0; sub < 4; ++sub) {
        p0[sub][0] = pack_bf16_perm(__builtin_amdgcn_exp2f(sa0[sub][0]),
                                    __builtin_amdgcn_exp2f(sa0[sub][1]));
        p0[sub][1] = pack_bf16_perm(__builtin_amdgcn_exp2f(sa0[sub][2]),
                                    __builtin_amdgcn_exp2f(sa0[sub][3]));
      }
#pragma unroll
      for (int sub = 0; sub < 4; ++sub) {
        p1[sub][0] = pack_bf16_perm(__builtin_amdgcn_exp2f(sa1[sub][0]),
                                    __builtin_amdgcn_exp2f(sa1[sub][1]));
        p1[sub][1] = pack_bf16_perm(__builtin_amdgcn_exp2f(sa1[sub][2]),
                                    __builtin_amdgcn_exp2f(sa1[sub][3]));
      }
      unsigned u00 = p0[0][0], w00 = p0[1][0];
      asm("v_permlane32_swap_b32 %0, %1" : "+v"(u00), "+v"(w00));
      unsigned u01 = p0[0][1], w01 = p0[1][1];
      asm("v_permlane32_swap_b32 %0, %1" : "+v"(u01), "+v"(w01));
      unsigned u02 = p0[2][0], w02 = p0[3][0];
      asm("v_permlane32_swap_b32 %0, %1" : "+v"(u02), "+v"(w02));
      unsigned u03 = p0[2][1], w03 = p0[3][1];
      asm("v_permlane32_swap_b32 %0, %1" : "+v"(u03), "+v"(w03));
      const short8 pf00 = frag4(u00, u01, w00, w01);
      const short8 pf01 = frag4(u02, u03, w02, w03);

      unsigned u10 = p1[0][0], w10 = p1[1][0];
      asm("v_permlane32_swap_b32 %0, %1" : "+v"(u10), "+v"(w10));
      unsigned u11 = p1[0][1], w11 = p1[1][1];
      asm("v_permlane32_swap_b32 %0, %1" : "+v"(u11), "+v"(w11));
      unsigned u12 = p1[2][0], w12 = p1[3][0];
      asm("v_permlane32_swap_b32 %0, %1" : "+v"(u12), "+v"(w12));
      unsigned u13 = p1[2][1], w13 = p1[3][1];
      asm("v_permlane32_swap_b32 %0, %1" : "+v"(u13), "+v"(w13));
      const short8 pf10 = frag4(u10, u11, w10, w11);
      const short8 pf11 = frag4(u12, u13, w12, w13);

      // ---- PV + row-sum MFMAs, both groups (pure-MFMA cluster; T5) ----
      __builtin_amdgcn_s_setprio(1);
      o00 = __builtin_amdgcn_mfma_f32_16x16x32_bf16(pf00, vf00, o00, 0, 0, 0);
      o00 = __builtin_amdgcn_mfma_f32_16x16x32_bf16(pf01, vf01, o00, 0, 0, 0);
      o01 = __builtin_amdgcn_mfma_f32_16x16x32_bf16(pf00, vf10, o01, 0, 0, 0);
      o01 = __builtin_amdgcn_mfma_f32_16x16x32_bf16(pf01, vf11, o01, 0, 0, 0);
      o10 = __builtin_amdgcn_mfma_f32_16x16x32_bf16(pf10, vf00, o10, 0, 0, 0);
      o10 = __builtin_amdgcn_mfma_f32_16x16x32_bf16(pf11, vf01, o10, 0, 0, 0);
      o11 = __builtin_amdgcn_mfma_f32_16x16x32_bf16(pf10, vf10, o11, 0, 0, 0);
      o11 = __builtin_amdgcn_mfma_f32_16x16x32_bf16(pf11, vf11, o11, 0, 0, 0);
      s0 = __builtin_amdgcn_mfma_f32_16x16x32_bf16(pf00, ones, s0, 0, 0, 0);
      s0 = __builtin_amdgcn_mfma_f32_16x16x32_bf16(pf01, ones, s0, 0, 0, 0);
      s1 = __builtin_amdgcn_mfma_f32_16x16x32_bf16(pf10, ones, s1, 0, 0, 0);
      s1 = __builtin_amdgcn_mfma_f32_16x16x32_bf16(pf11, ones, s1, 0, 0, 0);
      __builtin_amdgcn_s_setprio(0);
    }
  }

  // ---- epilogue: O = Q + oacc/l ; Q re-read directly (L2-hot) ----
#pragma unroll
  for (int g = 0; g < 2; ++g) {
    const f32x4 oS = g ? s1 : s0;
    const f32x4 oa = g ? o10 : o00;
    const f32x4 ob = g ? o11 : o01;
    const size_t row0 =
        (size_t)(b * NSEQ + qt * 128 + wave * 32 + g * 16 + quad * 4);
#pragma unroll
    for (int r = 0; r < 4; ++r) {
      const float il = 1.0f / oS[r];
      const size_t ro = (row0 + r) * 256 + h * HDIM + l16;
      O[ro] = bf16_to_f(Qh[ro]) * QINV + oa[r] * il;
      O[ro + 16] = bf16_to_f(Qh[ro + 16]) * QINV + ob[r] * il;
    }
  }
}

extern "C" void kernel_launch(void* const* d_in, const int* in_sizes, int n_in,
                              void* d_out, int out_size, void* d_ws, size_t ws_size,
                              hipStream_t stream) {
  const float* x = (const float*)d_in[0];
  const float* y = (const float*)d_in[1];
  const float* Wq = (const float*)d_in[2];
  const float* bq = (const float*)d_in[3];
  const float* Wk = (const float*)d_in[4];
  const float* bk = (const float*)d_in[5];
  const float* Wv = (const float*)d_in[6];
  const float* bv = (const float*)d_in[7];
  const float* W1 = (const float*)d_in[8];
  const float* b1 = (const float*)d_in[9];
  const float* W2 = (const float*)d_in[10];
  const float* b2 = (const float*)d_in[11];
  const float* ln0g = (const float*)d_in[12];
  const float* ln0b = (const float*)d_in[13];
  const float* ln1g = (const float*)d_in[14];
  const float* ln1b = (const float*)d_in[15];
  float* out = (float*)d_out;
  char* base = (char*)d_ws;

  const size_t RM = (size_t)RTOT * 256;
  // region0: yh (bf16, stage0->qkv) then overwritten by Ob (fp32, attn out)
  ushort* yh = (ushort*)base;
  float* Ob = (float*)base;
  ushort* Qh = (ushort*)(base + 2 * RM * 4);
  ushort* Kh = (ushort*)(base + 2 * RM * 4 + RM * 2);
  ushort* VhT = (ushort*)(base + 3 * RM * 4);
  ushort* xh = (ushort*)(base + 3 * RM * 4 + RM * 2);  // LN0 out; reused as On
  ushort* Onh = xh;
  ushort* Hidh = Qh;  // [R,512] bf16 overlays Qh+Kh (dead after attn)
  char* wbase = base + 4 * RM * 4;
  ushort* Wqt = (ushort*)wbase;  // [256,256]
  ushort* Wkt = Wqt + 65536;
  ushort* Wvt = Wkt + 65536;
  ushort* W1t = Wvt + 65536;   // [512,256]
  ushort* W2t = W1t + 131072;  // [256,512]

  stage0_kernel<<<8304, 256, 0, stream>>>(x, y, Wq, Wk, Wv, W1, W2, ln0g, ln0b,
                                          Wqt, Wkt, Wvt, W1t, W2t, yh, xh);
  qkv_kernel<<<dim3(128, 12), 256, 0, stream>>>(xh, yh, Wqt, Wkt, Wvt, bq, bk,
                                                bv, Qh, Kh, VhT);
  attn_kernel<<<1024, 256, 0, stream>>>(Qh, Kh, VhT, Ob);
  ln_kernel<<<RTOT / 4, 256, 0, stream>>>(Ob, ln1g, ln1b, Onh);
  mgemm_kernel<2><<<dim3(128, 8), 256, 0, stream>>>(Onh, W1t, b1, nullptr,
                                                    nullptr, Hidh, 256, 512);
  mgemm_kernel<3><<<dim3(128, 4), 256, 0, stream>>>(Hidh, W2t, b2, Ob, out,
                                                    nullptr, 512, 256);
}

// Round 8
// 212.577 us; speedup vs baseline: 1.3173x; 1.0167x over previous
//
#include <hip/hip_runtime.h>
#include <math.h>

// Problem constants (B=8, N=2048, D_IN=D_V=256, H=8, HD=32, D_FF=512)
#define RTOT 16384   // B*N rows
#define NSEQ 2048
#define NHEAD 8
#define HDIM 32
// Q pre-scale: log2(e)/sqrt(256) so S_mfma = S_true*log2e, softmax via exp2
#define QSCALE 0.09017132252479462f
#define QINV (1.0f / QSCALE)

typedef __attribute__((ext_vector_type(8))) short short8;
typedef __attribute__((ext_vector_type(4))) float f32x4;
typedef __attribute__((ext_vector_type(4))) unsigned uint4v;

#define GLOBAL_AS(p) ((__attribute__((address_space(1))) void*)(p))
#define LDS_AS(p) ((__attribute__((address_space(3))) void*)(p))

__device__ __forceinline__ unsigned pack_bf16(float a, float b) {
  unsigned ua = __float_as_uint(a) + 0x8000u;
  unsigned ub = __float_as_uint(b) + 0x8000u;
  return (ua >> 16) | (ub & 0xffff0000u);
}
// truncating pack via byte-perm (positive values; bias cancels in softmax ratio)
// result = [a.b2,a.b3,b.b2,b.b3] : low16 = bf16(a), high16 = bf16(b)
__device__ __forceinline__ unsigned pack_bf16_perm(float a, float b) {
  return __builtin_amdgcn_perm(__float_as_uint(b), __float_as_uint(a),
                               0x07060302u);
}
__device__ __forceinline__ ushort bf16_1(float a) {
  return (ushort)((__float_as_uint(a) + 0x8000u) >> 16);
}
__device__ __forceinline__ float bf16_to_f(ushort u) {
  return __uint_as_float(((unsigned)u) << 16);
}
__device__ __forceinline__ short8 frag4(unsigned a0, unsigned a1, unsigned a2,
                                        unsigned a3) {
  uint4v t = {a0, a1, a2, a3};
  return __builtin_bit_cast(short8, t);
}

// ---------------- stage0: fused weight-transpose + cvt(y) + ln0(x) ----------------
// blocks [0,112): weight transpose; [112,4208): y->bf16; [4208,8304): LN0(x)->bf16
__global__ __launch_bounds__(256) void stage0_kernel(
    const float* __restrict__ x, const float* __restrict__ y,
    const float* __restrict__ Wq, const float* __restrict__ Wk,
    const float* __restrict__ Wv, const float* __restrict__ W1,
    const float* __restrict__ W2, const float* __restrict__ ln0g,
    const float* __restrict__ ln0b, ushort* __restrict__ Wqt,
    ushort* __restrict__ Wkt, ushort* __restrict__ Wvt,
    ushort* __restrict__ W1t, ushort* __restrict__ W2t,
    ushort* __restrict__ yh, ushort* __restrict__ xh) {
  const int bid = blockIdx.x;
  const int t = threadIdx.x;
  if (bid < 112) {
    const float* W;
    ushort* Wt;
    int K, N, tile;
    if (bid < 16) { W = Wq; Wt = Wqt; K = 256; N = 256; tile = bid; }
    else if (bid < 32) { W = Wk; Wt = Wkt; K = 256; N = 256; tile = bid - 16; }
    else if (bid < 48) { W = Wv; Wt = Wvt; K = 256; N = 256; tile = bid - 32; }
    else if (bid < 80) { W = W1; Wt = W1t; K = 256; N = 512; tile = bid - 48; }
    else { W = W2; Wt = W2t; K = 512; N = 256; tile = bid - 80; }
    const int tn = N >> 6;
    const int k0 = (tile / tn) << 6, n0 = (tile % tn) << 6;
    __shared__ float T[64][65];
#pragma unroll
    for (int i = 0; i < 16; ++i) {
      const int idx = t + i * 256;
      const int r = idx >> 6, c = idx & 63;
      T[r][c] = W[(size_t)(k0 + r) * N + n0 + c];
    }
    __syncthreads();
#pragma unroll
    for (int i = 0; i < 16; ++i) {
      const int idx = t + i * 256;
      const int r = idx >> 6, c = idx & 63;
      Wt[(size_t)(n0 + r) * K + k0 + c] = bf16_1(T[c][r]);
    }
  } else if (bid < 4208) {
    const size_t i = ((size_t)(bid - 112) * 256 + t) * 4;
    const float4 v = *(const float4*)&y[i];
    uint2 pk;
    pk.x = pack_bf16(v.x, v.y);
    pk.y = pack_bf16(v.z, v.w);
    *(uint2*)&yh[i] = pk;
  } else {
    const int lane = t & 63, wave = t >> 6;
    const size_t row = (size_t)(bid - 4208) * 4 + wave;
    const float* xr = x + row * 256;
    float4 v = *(const float4*)&xr[lane * 4];
    float s = v.x + v.y + v.z + v.w;
#pragma unroll
    for (int m = 1; m < 64; m <<= 1) s += __shfl_xor(s, m, 64);
    const float mu = s * (1.0f / 256.0f);
    const float dx = v.x - mu, dy = v.y - mu, dz = v.z - mu, dw = v.w - mu;
    float ss = dx * dx + dy * dy + dz * dz + dw * dw;
#pragma unroll
    for (int m = 1; m < 64; m <<= 1) ss += __shfl_xor(ss, m, 64);
    const float rstd = rsqrtf(ss * (1.0f / 256.0f) + 1e-5f);
    const float4 gv = *(const float4*)&ln0g[lane * 4];
    const float4 bv = *(const float4*)&ln0b[lane * 4];
    uint2 pk;
    pk.x = pack_bf16(dx * rstd * gv.x + bv.x, dy * rstd * gv.y + bv.y);
    pk.y = pack_bf16(dz * rstd * gv.z + bv.z, dw * rstd * gv.w + bv.w);
    *(uint2*)&xh[row * 256 + lane * 4] = pk;
  }
}

// ---------------- LayerNorm over D=256, bf16 output ----------------
__global__ __launch_bounds__(256) void ln_kernel(
    const float* __restrict__ X, const float* __restrict__ g,
    const float* __restrict__ bt, ushort* __restrict__ Yh) {
  const int lane = threadIdx.x & 63;
  const int wave = threadIdx.x >> 6;
  const size_t row = (size_t)blockIdx.x * 4 + wave;
  const float* xr = X + row * 256;
  float4 v = *(const float4*)&xr[lane * 4];
  float s = v.x + v.y + v.z + v.w;
#pragma unroll
  for (int m = 1; m < 64; m <<= 1) s += __shfl_xor(s, m, 64);
  const float mu = s * (1.0f / 256.0f);
  const float dx = v.x - mu, dy = v.y - mu, dz = v.z - mu, dw = v.w - mu;
  float ss = dx * dx + dy * dy + dz * dz + dw * dw;
#pragma unroll
  for (int m = 1; m < 64; m <<= 1) ss += __shfl_xor(ss, m, 64);
  const float rstd = rsqrtf(ss * (1.0f / 256.0f) + 1e-5f);
  const float4 gv = *(const float4*)&g[lane * 4];
  const float4 bv = *(const float4*)&bt[lane * 4];
  uint2 pk;
  pk.x = pack_bf16(dx * rstd * gv.x + bv.x, dy * rstd * gv.y + bv.y);
  pk.y = pack_bf16(dz * rstd * gv.z + bv.z, dw * rstd * gv.w + bv.w);
  *(uint2*)&Yh[row * 256 + lane * 4] = pk;
}

// ---------------- merged QKV GEMM, K/V fused ----------------
// grid (128, 8): ny<4 = KV block (computes K AND V for n0, sharing the yh
// A-tile staging: 16 MFMA per barrier pair, half the yh traffic);
// ny>=4 = Q block (xh A, as before). 128x64 tiles, BK=32, 4 waves.
// K: Kh=bf16(v) ; Q: Qh=bf16(v*QSCALE) ; V: transpose -> VhT[b*256+n][nseq]
__global__ __launch_bounds__(256) void qkv_kernel(
    const ushort* __restrict__ xh, const ushort* __restrict__ yh,
    const ushort* __restrict__ Wqt, const ushort* __restrict__ Wkt,
    const ushort* __restrict__ Wvt, const float* __restrict__ bq,
    const float* __restrict__ bk, const float* __restrict__ bv,
    ushort* __restrict__ Qh, ushort* __restrict__ Kh,
    ushort* __restrict__ VhT) {
  __shared__ union UU {
    struct { ushort As[128 * 32]; ushort Bs[2][64 * 32]; } s;  // 16 KB
    ushort Ct[64 * 136];  // V-transpose tile [n_local][m_local], 17.4 KB
  } u;
  const int t = threadIdx.x;
  const int lane = t & 63, wave = t >> 6;
  const int l16 = lane & 15, quad = lane >> 4;
  const int row0 = blockIdx.x * 128;
  const int ny = blockIdx.y;
  const bool isQ = ny >= 4;
  const int n0 = (ny & 3) << 6;
  const ushort* A = isQ ? xh : yh;
  const int mrow = (wave & 1) * 64, ncol = (wave >> 1) * 32;

  const ushort* gA0 = A + (size_t)(row0 + (t >> 2)) * 256 + ((t & 3) << 3);
  const ushort* gA1 = gA0 + (size_t)64 * 256;
  const ushort* gB0 = (isQ ? Wqt : Wkt) +
                      (size_t)(n0 + (t >> 2)) * 256 + ((t & 3) << 3);
  const ushort* gB1 = Wvt + (size_t)(n0 + (t >> 2)) * 256 + ((t & 3) << 3);
  ushort* lA0 = u.s.As + 8 * t;
  ushort* lA1 = u.s.As + 2048 + 8 * t;
  ushort* lB0 = u.s.Bs[0] + 8 * t;
  ushort* lB1 = u.s.Bs[1] + 8 * t;

  f32x4 acc0[4][2] = {};  // K (or Q)
  f32x4 acc1[4][2] = {};  // V (KV blocks only)
  for (int kc = 0; kc < 256; kc += 32) {
    __builtin_amdgcn_global_load_lds(GLOBAL_AS(gA0 + kc), LDS_AS(lA0), 16, 0, 0);
    __builtin_amdgcn_global_load_lds(GLOBAL_AS(gA1 + kc), LDS_AS(lA1), 16, 0, 0);
    __builtin_amdgcn_global_load_lds(GLOBAL_AS(gB0 + kc), LDS_AS(lB0), 16, 0, 0);
    if (!isQ)
      __builtin_amdgcn_global_load_lds(GLOBAL_AS(gB1 + kc), LDS_AS(lB1), 16, 0,
                                       0);
    __syncthreads();
    short8 af[4], bfr0[2];
#pragma unroll
    for (int mi = 0; mi < 4; ++mi)
      af[mi] = *(const short8*)&u.s.As[(mrow + mi * 16 + l16) * 32 + quad * 8];
#pragma unroll
    for (int nj = 0; nj < 2; ++nj)
      bfr0[nj] =
          *(const short8*)&u.s.Bs[0][(ncol + nj * 16 + l16) * 32 + quad * 8];
#pragma unroll
    for (int mi = 0; mi < 4; ++mi)
#pragma unroll
      for (int nj = 0; nj < 2; ++nj)
        acc0[mi][nj] = __builtin_amdgcn_mfma_f32_16x16x32_bf16(
            af[mi], bfr0[nj], acc0[mi][nj], 0, 0, 0);
    if (!isQ) {
      short8 bfr1[2];
#pragma unroll
      for (int nj = 0; nj < 2; ++nj)
        bfr1[nj] =
            *(const short8*)&u.s.Bs[1][(ncol + nj * 16 + l16) * 32 + quad * 8];
#pragma unroll
      for (int mi = 0; mi < 4; ++mi)
#pragma unroll
        for (int nj = 0; nj < 2; ++nj)
          acc1[mi][nj] = __builtin_amdgcn_mfma_f32_16x16x32_bf16(
              af[mi], bfr1[nj], acc1[mi][nj], 0, 0, 0);
    }
    __syncthreads();
  }

  if (isQ) {
#pragma unroll
    for (int nj = 0; nj < 2; ++nj) {
      const int n = n0 + ncol + nj * 16 + l16;
      const float bvv = bq[n];
#pragma unroll
      for (int mi = 0; mi < 4; ++mi)
#pragma unroll
        for (int r = 0; r < 4; ++r) {
          const size_t m = (size_t)row0 + mrow + mi * 16 + quad * 4 + r;
          Qh[m * 256 + n] = bf16_1((acc0[mi][nj][r] + bvv) * QSCALE);
        }
    }
  } else {
    // K epilogue (register-only, no LDS)
#pragma unroll
    for (int nj = 0; nj < 2; ++nj) {
      const int n = n0 + ncol + nj * 16 + l16;
      const float bvv = bk[n];
#pragma unroll
      for (int mi = 0; mi < 4; ++mi)
#pragma unroll
        for (int r = 0; r < 4; ++r) {
          const size_t m = (size_t)row0 + mrow + mi * 16 + quad * 4 + r;
          Kh[m * 256 + n] = bf16_1(acc0[mi][nj][r] + bvv);
        }
    }
    // V: bias + transpose via LDS (Ct overlays As/Bs, dead after barrier)
    __syncthreads();
#pragma unroll
    for (int nj = 0; nj < 2; ++nj) {
      const int nloc = ncol + nj * 16 + l16;
      const float bvv = bv[n0 + nloc];
#pragma unroll
      for (int mi = 0; mi < 4; ++mi)
#pragma unroll
        for (int r = 0; r < 4; ++r)
          u.Ct[nloc * 136 + mrow + mi * 16 + quad * 4 + r] =
              bf16_1(acc1[mi][nj][r] + bvv);
    }
    __syncthreads();
    const int bb = row0 >> 11, ns0 = row0 & 2047;
#pragma unroll
    for (int i = 0; i < 4; ++i) {
      const int c = t + i * 256;
      const int rr = c >> 4, c8 = (c & 15) << 3;
      *(float4*)&VhT[(size_t)(bb * 256 + n0 + rr) * 2048 + ns0 + c8] =
          *(const float4*)&u.Ct[rr * 136 + c8];
    }
  }
}

// ---------------- FFN1 GEMM: 128x64 tile, BK=32 ----------------
// Ch = bf16(gelu(v))
__global__ __launch_bounds__(256) void mgemm_kernel(
    const ushort* __restrict__ A, const ushort* __restrict__ Wt,
    const float* __restrict__ bias, ushort* __restrict__ Ch, int K, int N) {
  __shared__ ushort As[128 * 32];
  __shared__ ushort Bs[64 * 32];
  const int t = threadIdx.x;
  const int lane = t & 63, wave = t >> 6;
  const int l16 = lane & 15, quad = lane >> 4;
  const int row0 = blockIdx.x * 128;
  const int n0 = blockIdx.y << 6;
  const int mrow = (wave & 1) * 64, ncol = (wave >> 1) * 32;

  const ushort* gA0 = A + (size_t)(row0 + (t >> 2)) * K + ((t & 3) << 3);
  const ushort* gA1 = gA0 + (size_t)64 * K;
  const ushort* gB = Wt + (size_t)(n0 + (t >> 2)) * K + ((t & 3) << 3);
  ushort* lA0 = As + 8 * t;
  ushort* lA1 = As + 2048 + 8 * t;
  ushort* lB = Bs + 8 * t;

  f32x4 acc[4][2] = {};
  for (int kc = 0; kc < K; kc += 32) {
    __builtin_amdgcn_global_load_lds(GLOBAL_AS(gA0 + kc), LDS_AS(lA0), 16, 0, 0);
    __builtin_amdgcn_global_load_lds(GLOBAL_AS(gA1 + kc), LDS_AS(lA1), 16, 0, 0);
    __builtin_amdgcn_global_load_lds(GLOBAL_AS(gB + kc), LDS_AS(lB), 16, 0, 0);
    __syncthreads();
    short8 af[4], bfr[2];
#pragma unroll
    for (int mi = 0; mi < 4; ++mi)
      af[mi] = *(const short8*)&As[(mrow + mi * 16 + l16) * 32 + quad * 8];
#pragma unroll
    for (int nj = 0; nj < 2; ++nj)
      bfr[nj] = *(const short8*)&Bs[(ncol + nj * 16 + l16) * 32 + quad * 8];
#pragma unroll
    for (int mi = 0; mi < 4; ++mi)
#pragma unroll
      for (int nj = 0; nj < 2; ++nj)
        acc[mi][nj] = __builtin_amdgcn_mfma_f32_16x16x32_bf16(
            af[mi], bfr[nj], acc[mi][nj], 0, 0, 0);
    __syncthreads();
  }
#pragma unroll
  for (int nj = 0; nj < 2; ++nj) {
    const int n = n0 + ncol + nj * 16 + l16;
    const float bvv = bias[n];
#pragma unroll
    for (int mi = 0; mi < 4; ++mi) {
#pragma unroll
      for (int r = 0; r < 4; ++r) {
        const size_t m = (size_t)row0 + mrow + mi * 16 + quad * 4 + r;
        float v = acc[mi][nj][r] + bvv;
        v = 0.5f * v * (1.0f + erff(v * 0.70710678118654752f));
        Ch[m * N + n] = bf16_1(v);
      }
    }
  }
}

// ---------------- FFN2 GEMM: 64x64 tile, BK=32 (occupancy: 1024 blocks) -----
// Cf = v + res.  grid (256, 4): 4 blocks/CU (vs 2 at 128-row tiles).
__global__ __launch_bounds__(256) void mgemm64_kernel(
    const ushort* __restrict__ A, const ushort* __restrict__ Wt,
    const float* __restrict__ bias, const float* __restrict__ res,
    float* __restrict__ Cf, int K, int N) {
  __shared__ ushort As[64 * 32];
  __shared__ ushort Bs[64 * 32];
  const int t = threadIdx.x;
  const int lane = t & 63, wave = t >> 6;
  const int l16 = lane & 15, quad = lane >> 4;
  const int row0 = blockIdx.x * 64;
  const int n0 = blockIdx.y << 6;
  const int mrow = (wave & 1) * 32, ncol = (wave >> 1) * 32;

  const ushort* gA = A + (size_t)(row0 + (t >> 2)) * K + ((t & 3) << 3);
  const ushort* gB = Wt + (size_t)(n0 + (t >> 2)) * K + ((t & 3) << 3);
  ushort* lA = As + 8 * t;
  ushort* lB = Bs + 8 * t;

  f32x4 acc[2][2] = {};
  for (int kc = 0; kc < K; kc += 32) {
    __builtin_amdgcn_global_load_lds(GLOBAL_AS(gA + kc), LDS_AS(lA), 16, 0, 0);
    __builtin_amdgcn_global_load_lds(GLOBAL_AS(gB + kc), LDS_AS(lB), 16, 0, 0);
    __syncthreads();
    short8 af[2], bfr[2];
#pragma unroll
    for (int mi = 0; mi < 2; ++mi)
      af[mi] = *(const short8*)&As[(mrow + mi * 16 + l16) * 32 + quad * 8];
#pragma unroll
    for (int nj = 0; nj < 2; ++nj)
      bfr[nj] = *(const short8*)&Bs[(ncol + nj * 16 + l16) * 32 + quad * 8];
#pragma unroll
    for (int mi = 0; mi < 2; ++mi)
#pragma unroll
      for (int nj = 0; nj < 2; ++nj)
        acc[mi][nj] = __builtin_amdgcn_mfma_f32_16x16x32_bf16(
            af[mi], bfr[nj], acc[mi][nj], 0, 0, 0);
    __syncthreads();
  }
#pragma unroll
  for (int nj = 0; nj < 2; ++nj) {
    const int n = n0 + ncol + nj * 16 + l16;
    const float bvv = bias[n];
#pragma unroll
    for (int mi = 0; mi < 2; ++mi) {
#pragma unroll
      for (int r = 0; r < 4; ++r) {
        const size_t m = (size_t)row0 + mrow + mi * 16 + quad * 4 + r;
        Cf[m * N + n] = acc[mi][nj][r] + bvv + res[m * N + n];
      }
    }
  }
}

// ---------------- Flash attention (bf16 MFMA, zero-max, 128q, KVBLK=128) ----
// O = Q + softmax(Q K^T / 16) V.  Qh pre-scaled by log2(e)/16 (bf16); residual
// recovered as Qh/QSCALE. No max shift (p = exp2(S*log2e), ratio-invariant);
// l via ones-MFMA.  Round-7 verified (65.5us): 128q, 4 waves, 2 q-groups/wave,
// KVBLK=128 (one barrier per 128 keys), T5 setprio on PV clusters.
// Ledger: VGPR in (64,128] pins 16 waves/CU (m69 granule); occupancy levers
// exhausted (r2,r4,r5); barrier halving ~1us (r7). Trans-pipe (exp2) demand
// at VALUBusy~61% is the structural floor of this formulation.
// K rows staged with bits 2<=>3 swapped so P routing is permlane32-only.
__global__ __launch_bounds__(256) void attn_kernel(
    const ushort* __restrict__ Qh, const ushort* __restrict__ Kh,
    const ushort* __restrict__ VhT, float* __restrict__ O) {
  __shared__ ushort Ks[2][128][40];  // 20480 B
  __shared__ ushort Vt[2][32][136];  // 17408 B (total 37888)

  const int t = threadIdx.x;
  const int lane = t & 63, wave = t >> 6;
  const int l16 = lane & 15, quad = lane >> 4;
  const int bh = blockIdx.x & 63;
  const int qt = blockIdx.x >> 6;  // 0..15
  const int b = bh >> 3, h = bh & 7;

  const size_t rowQ0 = (size_t)(b * NSEQ + qt * 128 + wave * 32 + l16);
  const short8 qfrag0 = *(const short8*)&Qh[rowQ0 * 256 + h * HDIM + quad * 8];
  const short8 qfrag1 =
      *(const short8*)&Qh[(rowQ0 + 16) * 256 + h * HDIM + quad * 8];
  const short8 ones = {16256, 16256, 16256, 16256,
                       16256, 16256, 16256, 16256};  // bf16 1.0 x8
  const f32x4 zf = {0.f, 0.f, 0.f, 0.f};

  f32x4 o00 = zf, o01 = zf, o10 = zf, o11 = zf;
  f32x4 s0 = zf, s1 = zf;

  // staging coords (cooperative, coalesced): K tile [128][32], V tile [32][128]
  // K rows land permuted: LDS row p holds logical key with bits 2<=>3 swapped
  // (self-inverse; commutes with +64), making the post-QK^T shuffle
  // permlane32-only.
  const int kr = t >> 2, kc8 = (t & 3) << 3;
  const int krL = (kr & ~12) | ((kr & 4) << 1) | ((kr & 8) >> 1);
  const int vd = t >> 3, vc8 = (t & 7) << 3;
  const ushort* gK = Kh + ((size_t)(b * NSEQ + krL)) * 256 + h * HDIM + kc8;
  const ushort* gK2 = gK + (size_t)64 * 256;
  const ushort* gV = VhT + ((size_t)(bh * 32 + vd)) * 2048 + vc8;

  float4 kreg0 = *(const float4*)gK;
  float4 kreg1 = *(const float4*)gK2;
  float4 vreg0 = *(const float4*)gV;
  float4 vreg1 = *(const float4*)(gV + 64);

  for (int kt = 0; kt < 16; ++kt) {
    const int bf = kt & 1;
    *(float4*)&Ks[bf][kr][kc8] = kreg0;
    *(float4*)&Ks[bf][64 + kr][kc8] = kreg1;
    *(float4*)&Vt[bf][vd][vc8] = vreg0;
    *(float4*)&Vt[bf][vd][64 + vc8] = vreg1;
    __syncthreads();  // buf visible; prev readers done (prev barrier)
    if (kt < 15) {    // register prefetch, in flight over compute
      const size_t ko = (size_t)(kt + 1) * 128 * 256;
      kreg0 = *(const float4*)(gK + ko);
      kreg1 = *(const float4*)(gK2 + ko);
      vreg0 = *(const float4*)(gV + (kt + 1) * 128);
      vreg1 = *(const float4*)(gV + (kt + 1) * 128 + 64);
    }

#pragma unroll
    for (int half = 0; half < 2; ++half) {
      const int r0 = half * 64;   // key-row base in Ks
      const int c0 = half * 64;   // key-col base in Vt

      // shared fragments for both q-groups (wave-independent LDS reads)
      short8 kf[4];
#pragma unroll
      for (int sub = 0; sub < 4; ++sub)
        kf[sub] = *(const short8*)&Ks[bf][r0 + sub * 16 + l16][quad * 8];
      const short8 vf00 = *(const short8*)&Vt[bf][l16][c0 + quad * 8];
      const short8 vf01 = *(const short8*)&Vt[bf][l16][c0 + 32 + quad * 8];
      const short8 vf10 = *(const short8*)&Vt[bf][16 + l16][c0 + quad * 8];
      const short8 vf11 = *(const short8*)&Vt[bf][16 + l16][c0 + 32 + quad * 8];

      // ---- S-MFMAs for BOTH groups (MFMA latency overlaps exp2 below) ----
      f32x4 sa0[4], sa1[4];
#pragma unroll
      for (int sub = 0; sub < 4; ++sub)
        sa0[sub] = __builtin_amdgcn_mfma_f32_16x16x32_bf16(kf[sub], qfrag0, zf,
                                                           0, 0, 0);
#pragma unroll
      for (int sub = 0; sub < 4; ++sub)
        sa1[sub] = __builtin_amdgcn_mfma_f32_16x16x32_bf16(kf[sub], qfrag1, zf,
                                                           0, 0, 0);

      // ---- exp2 + pack + in-register route (permlane32 swap) ----
      unsigned p0[4][2], p1[4][2];
#pragma unroll
      for (int sub = 0; sub < 4; ++sub) {
        p0[sub][0] = pack_bf16_perm(__builtin_amdgcn_exp2f(sa0[sub][0]),
                                    __builtin_amdgcn_exp2f(sa0[sub][1]));
        p0[sub][1] = pack_bf16_perm(__builtin_amdgcn_exp2f(sa0[sub][2]),
                                    __builtin_amdgcn_exp2f(sa0[sub][3]));
      }
#pragma unroll
      for (int sub = 0; sub < 4; ++sub) {
        p1[sub][0] = pack_bf16_perm(__builtin_amdgcn_exp2f(sa1[sub][0]),
                                    __builtin_amdgcn_exp2f(sa1[sub][1]));
        p1[sub][1] = pack_bf16_perm(__builtin_amdgcn_exp2f(sa1[sub][2]),
                                    __builtin_amdgcn_exp2f(sa1[sub][3]));
      }
      unsigned u00 = p0[0][0], w00 = p0[1][0];
      asm("v_permlane32_swap_b32 %0, %1" : "+v"(u00), "+v"(w00));
      unsigned u01 = p0[0][1], w01 = p0[1][1];
      asm("v_permlane32_swap_b32 %0, %1" : "+v"(u01), "+v"(w01));
      unsigned u02 = p0[2][0], w02 = p0[3][0];
      asm("v_permlane32_swap_b32 %0, %1" : "+v"(u02), "+v"(w02));
      unsigned u03 = p0[2][1], w03 = p0[3][1];
      asm("v_permlane32_swap_b32 %0, %1" : "+v"(u03), "+v"(w03));
      const short8 pf00 = frag4(u00, u01, w00, w01);
      const short8 pf01 = frag4(u02, u03, w02, w03);

      unsigned u10 = p1[0][0], w10 = p1[1][0];
      asm("v_permlane32_swap_b32 %0, %1" : "+v"(u10), "+v"(w10));
      unsigned u11 = p1[0][1], w11 = p1[1][1];
      asm("v_permlane32_swap_b32 %0, %1" : "+v"(u11), "+v"(w11));
      unsigned u12 = p1[2][0], w12 = p1[3][0];
      asm("v_permlane32_swap_b32 %0, %1" : "+v"(u12), "+v"(w12));
      unsigned u13 = p1[2][1], w13 = p1[3][1];
      asm("v_permlane32_swap_b32 %0, %1" : "+v"(u13), "+v"(w13));
      const short8 pf10 = frag4(u10, u11, w10, w11);
      const short8 pf11 = frag4(u12, u13, w12, w13);

      // ---- PV + row-sum MFMAs, both groups (pure-MFMA cluster; T5) ----
      __builtin_amdgcn_s_setprio(1);
      o00 = __builtin_amdgcn_mfma_f32_16x16x32_bf16(pf00, vf00, o00, 0, 0, 0);
      o00 = __builtin_amdgcn_mfma_f32_16x16x32_bf16(pf01, vf01, o00, 0, 0, 0);
      o01 = __builtin_amdgcn_mfma_f32_16x16x32_bf16(pf00, vf10, o01, 0, 0, 0);
      o01 = __builtin_amdgcn_mfma_f32_16x16x32_bf16(pf01, vf11, o01, 0, 0, 0);
      o10 = __builtin_amdgcn_mfma_f32_16x16x32_bf16(pf10, vf00, o10, 0, 0, 0);
      o10 = __builtin_amdgcn_mfma_f32_16x16x32_bf16(pf11, vf01, o10, 0, 0, 0);
      o11 = __builtin_amdgcn_mfma_f32_16x16x32_bf16(pf10, vf10, o11, 0, 0, 0);
      o11 = __builtin_amdgcn_mfma_f32_16x16x32_bf16(pf11, vf11, o11, 0, 0, 0);
      s0 = __builtin_amdgcn_mfma_f32_16x16x32_bf16(pf00, ones, s0, 0, 0, 0);
      s0 = __builtin_amdgcn_mfma_f32_16x16x32_bf16(pf01, ones, s0, 0, 0, 0);
      s1 = __builtin_amdgcn_mfma_f32_16x16x32_bf16(pf10, ones, s1, 0, 0, 0);
      s1 = __builtin_amdgcn_mfma_f32_16x16x32_bf16(pf11, ones, s1, 0, 0, 0);
      __builtin_amdgcn_s_setprio(0);
    }
  }

  // ---- epilogue: O = Q + oacc/l ; Q re-read directly (L2-hot) ----
#pragma unroll
  for (int g = 0; g < 2; ++g) {
    const f32x4 oS = g ? s1 : s0;
    const f32x4 oa = g ? o10 : o00;
    const f32x4 ob = g ? o11 : o01;
    const size_t row0 =
        (size_t)(b * NSEQ + qt * 128 + wave * 32 + g * 16 + quad * 4);
#pragma unroll
    for (int r = 0; r < 4; ++r) {
      const float il = 1.0f / oS[r];
      const size_t ro = (row0 + r) * 256 + h * HDIM + l16;
      O[ro] = bf16_to_f(Qh[ro]) * QINV + oa[r] * il;
      O[ro + 16] = bf16_to_f(Qh[ro + 16]) * QINV + ob[r] * il;
    }
  }
}

extern "C" void kernel_launch(void* const* d_in, const int* in_sizes, int n_in,
                              void* d_out, int out_size, void* d_ws, size_t ws_size,
                              hipStream_t stream) {
  const float* x = (const float*)d_in[0];
  const float* y = (const float*)d_in[1];
  const float* Wq = (const float*)d_in[2];
  const float* bq = (const float*)d_in[3];
  const float* Wk = (const float*)d_in[4];
  const float* bk = (const float*)d_in[5];
  const float* Wv = (const float*)d_in[6];
  const float* bv = (const float*)d_in[7];
  const float* W1 = (const float*)d_in[8];
  const float* b1 = (const float*)d_in[9];
  const float* W2 = (const float*)d_in[10];
  const float* b2 = (const float*)d_in[11];
  const float* ln0g = (const float*)d_in[12];
  const float* ln0b = (const float*)d_in[13];
  const float* ln1g = (const float*)d_in[14];
  const float* ln1b = (const float*)d_in[15];
  float* out = (float*)d_out;
  char* base = (char*)d_ws;

  const size_t RM = (size_t)RTOT * 256;
  // region0: yh (bf16, stage0->qkv) then overwritten by Ob (fp32, attn out)
  ushort* yh = (ushort*)base;
  float* Ob = (float*)base;
  ushort* Qh = (ushort*)(base + 2 * RM * 4);
  ushort* Kh = (ushort*)(base + 2 * RM * 4 + RM * 2);
  ushort* VhT = (ushort*)(base + 3 * RM * 4);
  ushort* xh = (ushort*)(base + 3 * RM * 4 + RM * 2);  // LN0 out; reused as On
  ushort* Onh = xh;
  ushort* Hidh = Qh;  // [R,512] bf16 overlays Qh+Kh (dead after attn)
  char* wbase = base + 4 * RM * 4;
  ushort* Wqt = (ushort*)wbase;  // [256,256]
  ushort* Wkt = Wqt + 65536;
  ushort* Wvt = Wkt + 65536;
  ushort* W1t = Wvt + 65536;   // [512,256]
  ushort* W2t = W1t + 131072;  // [256,512]

  stage0_kernel<<<8304, 256, 0, stream>>>(x, y, Wq, Wk, Wv, W1, W2, ln0g, ln0b,
                                          Wqt, Wkt, Wvt, W1t, W2t, yh, xh);
  qkv_kernel<<<dim3(128, 8), 256, 0, stream>>>(xh, yh, Wqt, Wkt, Wvt, bq, bk,
                                               bv, Qh, Kh, VhT);
  attn_kernel<<<1024, 256, 0, stream>>>(Qh, Kh, VhT, Ob);
  ln_kernel<<<RTOT / 4, 256, 0, stream>>>(Ob, ln1g, ln1b, Onh);
  mgemm_kernel<<<dim3(128, 8), 256, 0, stream>>>(Onh, W1t, b1, Hidh, 256, 512);
  mgemm64_kernel<<<dim3(256, 4), 256, 0, stream>>>(Hidh, W2t, b2, Ob, out, 512,
                                                   256);
}

// Round 9
// 211.586 us; speedup vs baseline: 1.3235x; 1.0047x over previous
//
#include <hip/hip_runtime.h>
#include <math.h>

// Problem constants (B=8, N=2048, D_IN=D_V=256, H=8, HD=32, D_FF=512)
#define RTOT 16384   // B*N rows
#define NSEQ 2048
#define NHEAD 8
#define HDIM 32
// Q pre-scale: log2(e)/sqrt(256) so S_mfma = S_true*log2e, softmax via exp2
#define QSCALE 0.09017132252479462f
#define QINV (1.0f / QSCALE)

typedef __attribute__((ext_vector_type(8))) short short8;
typedef __attribute__((ext_vector_type(4))) float f32x4;
typedef __attribute__((ext_vector_type(4))) unsigned uint4v;

#define GLOBAL_AS(p) ((__attribute__((address_space(1))) void*)(p))
#define LDS_AS(p) ((__attribute__((address_space(3))) void*)(p))

__device__ __forceinline__ unsigned pack_bf16(float a, float b) {
  unsigned ua = __float_as_uint(a) + 0x8000u;
  unsigned ub = __float_as_uint(b) + 0x8000u;
  return (ua >> 16) | (ub & 0xffff0000u);
}
// truncating pack via byte-perm (positive values; bias cancels in softmax ratio)
// result = [a.b2,a.b3,b.b2,b.b3] : low16 = bf16(a), high16 = bf16(b)
__device__ __forceinline__ unsigned pack_bf16_perm(float a, float b) {
  return __builtin_amdgcn_perm(__float_as_uint(b), __float_as_uint(a),
                               0x07060302u);
}
__device__ __forceinline__ ushort bf16_1(float a) {
  return (ushort)((__float_as_uint(a) + 0x8000u) >> 16);
}
__device__ __forceinline__ float bf16_to_f(ushort u) {
  return __uint_as_float(((unsigned)u) << 16);
}
__device__ __forceinline__ short8 frag4(unsigned a0, unsigned a1, unsigned a2,
                                        unsigned a3) {
  uint4v t = {a0, a1, a2, a3};
  return __builtin_bit_cast(short8, t);
}

// ---------------- stage0: fused weight-transpose + cvt(y) + ln0(x) ----------------
// blocks [0,112): weight transpose; [112,4208): y->bf16; [4208,8304): LN0(x)->bf16
__global__ __launch_bounds__(256) void stage0_kernel(
    const float* __restrict__ x, const float* __restrict__ y,
    const float* __restrict__ Wq, const float* __restrict__ Wk,
    const float* __restrict__ Wv, const float* __restrict__ W1,
    const float* __restrict__ W2, const float* __restrict__ ln0g,
    const float* __restrict__ ln0b, ushort* __restrict__ Wqt,
    ushort* __restrict__ Wkt, ushort* __restrict__ Wvt,
    ushort* __restrict__ W1t, ushort* __restrict__ W2t,
    ushort* __restrict__ yh, ushort* __restrict__ xh) {
  const int bid = blockIdx.x;
  const int t = threadIdx.x;
  if (bid < 112) {
    const float* W;
    ushort* Wt;
    int K, N, tile;
    if (bid < 16) { W = Wq; Wt = Wqt; K = 256; N = 256; tile = bid; }
    else if (bid < 32) { W = Wk; Wt = Wkt; K = 256; N = 256; tile = bid - 16; }
    else if (bid < 48) { W = Wv; Wt = Wvt; K = 256; N = 256; tile = bid - 32; }
    else if (bid < 80) { W = W1; Wt = W1t; K = 256; N = 512; tile = bid - 48; }
    else { W = W2; Wt = W2t; K = 512; N = 256; tile = bid - 80; }
    const int tn = N >> 6;
    const int k0 = (tile / tn) << 6, n0 = (tile % tn) << 6;
    __shared__ float T[64][65];
#pragma unroll
    for (int i = 0; i < 16; ++i) {
      const int idx = t + i * 256;
      const int r = idx >> 6, c = idx & 63;
      T[r][c] = W[(size_t)(k0 + r) * N + n0 + c];
    }
    __syncthreads();
#pragma unroll
    for (int i = 0; i < 16; ++i) {
      const int idx = t + i * 256;
      const int r = idx >> 6, c = idx & 63;
      Wt[(size_t)(n0 + r) * K + k0 + c] = bf16_1(T[c][r]);
    }
  } else if (bid < 4208) {
    const size_t i = ((size_t)(bid - 112) * 256 + t) * 4;
    const float4 v = *(const float4*)&y[i];
    uint2 pk;
    pk.x = pack_bf16(v.x, v.y);
    pk.y = pack_bf16(v.z, v.w);
    *(uint2*)&yh[i] = pk;
  } else {
    const int lane = t & 63, wave = t >> 6;
    const size_t row = (size_t)(bid - 4208) * 4 + wave;
    const float* xr = x + row * 256;
    float4 v = *(const float4*)&xr[lane * 4];
    float s = v.x + v.y + v.z + v.w;
#pragma unroll
    for (int m = 1; m < 64; m <<= 1) s += __shfl_xor(s, m, 64);
    const float mu = s * (1.0f / 256.0f);
    const float dx = v.x - mu, dy = v.y - mu, dz = v.z - mu, dw = v.w - mu;
    float ss = dx * dx + dy * dy + dz * dz + dw * dw;
#pragma unroll
    for (int m = 1; m < 64; m <<= 1) ss += __shfl_xor(ss, m, 64);
    const float rstd = rsqrtf(ss * (1.0f / 256.0f) + 1e-5f);
    const float4 gv = *(const float4*)&ln0g[lane * 4];
    const float4 bv = *(const float4*)&ln0b[lane * 4];
    uint2 pk;
    pk.x = pack_bf16(dx * rstd * gv.x + bv.x, dy * rstd * gv.y + bv.y);
    pk.y = pack_bf16(dz * rstd * gv.z + bv.z, dw * rstd * gv.w + bv.w);
    *(uint2*)&xh[row * 256 + lane * 4] = pk;
  }
}

// ---------------- LayerNorm over D=256, bf16 output ----------------
__global__ __launch_bounds__(256) void ln_kernel(
    const float* __restrict__ X, const float* __restrict__ g,
    const float* __restrict__ bt, ushort* __restrict__ Yh) {
  const int lane = threadIdx.x & 63;
  const int wave = threadIdx.x >> 6;
  const size_t row = (size_t)blockIdx.x * 4 + wave;
  const float* xr = X + row * 256;
  float4 v = *(const float4*)&xr[lane * 4];
  float s = v.x + v.y + v.z + v.w;
#pragma unroll
  for (int m = 1; m < 64; m <<= 1) s += __shfl_xor(s, m, 64);
  const float mu = s * (1.0f / 256.0f);
  const float dx = v.x - mu, dy = v.y - mu, dz = v.z - mu, dw = v.w - mu;
  float ss = dx * dx + dy * dy + dz * dz + dw * dw;
#pragma unroll
  for (int m = 1; m < 64; m <<= 1) ss += __shfl_xor(ss, m, 64);
  const float rstd = rsqrtf(ss * (1.0f / 256.0f) + 1e-5f);
  const float4 gv = *(const float4*)&g[lane * 4];
  const float4 bv = *(const float4*)&bt[lane * 4];
  uint2 pk;
  pk.x = pack_bf16(dx * rstd * gv.x + bv.x, dy * rstd * gv.y + bv.y);
  pk.y = pack_bf16(dz * rstd * gv.z + bv.z, dw * rstd * gv.w + bv.w);
  *(uint2*)&Yh[row * 256 + lane * 4] = pk;
}

// ---------------- merged QKV GEMM, K/V fused, double-buffered LDS ----------
// grid (128, 8): ny<4 = KV block (K AND V for n0, sharing yh A-staging);
// ny>=4 = Q block. 128x64 tiles, BK=32, 4 waves. T3 2-phase: prefetch tile
// i+1 into buf^1 while computing tile i; ONE barrier per iteration (drain
// covers the prefetch; readers of buf^1 start only after this barrier).
// K: Kh=bf16(v) ; Q: Qh=bf16(v*QSCALE) ; V: transpose -> VhT[b*256+n][nseq]
__global__ __launch_bounds__(256) void qkv_kernel(
    const ushort* __restrict__ xh, const ushort* __restrict__ yh,
    const ushort* __restrict__ Wqt, const ushort* __restrict__ Wkt,
    const ushort* __restrict__ Wvt, const float* __restrict__ bq,
    const float* __restrict__ bk, const float* __restrict__ bv,
    ushort* __restrict__ Qh, ushort* __restrict__ Kh,
    ushort* __restrict__ VhT) {
  __shared__ union UU {
    struct { ushort As[2][128 * 32]; ushort Bs[2][2][64 * 32]; } s;  // 32 KB
    ushort Ct[64 * 136];  // V-transpose tile [n_local][m_local], 17.4 KB
  } u;
  const int t = threadIdx.x;
  const int lane = t & 63, wave = t >> 6;
  const int l16 = lane & 15, quad = lane >> 4;
  const int row0 = blockIdx.x * 128;
  const int ny = blockIdx.y;
  const bool isQ = ny >= 4;
  const int n0 = (ny & 3) << 6;
  const ushort* A = isQ ? xh : yh;
  const int mrow = (wave & 1) * 64, ncol = (wave >> 1) * 32;

  const ushort* gA0 = A + (size_t)(row0 + (t >> 2)) * 256 + ((t & 3) << 3);
  const ushort* gA1 = gA0 + (size_t)64 * 256;
  const ushort* gB0 = (isQ ? Wqt : Wkt) +
                      (size_t)(n0 + (t >> 2)) * 256 + ((t & 3) << 3);
  const ushort* gB1 = Wvt + (size_t)(n0 + (t >> 2)) * 256 + ((t & 3) << 3);

  auto stage = [&](int buf, int kc) {
    __builtin_amdgcn_global_load_lds(GLOBAL_AS(gA0 + kc),
                                     LDS_AS(u.s.As[buf] + 8 * t), 16, 0, 0);
    __builtin_amdgcn_global_load_lds(GLOBAL_AS(gA1 + kc),
                                     LDS_AS(u.s.As[buf] + 2048 + 8 * t), 16, 0,
                                     0);
    __builtin_amdgcn_global_load_lds(GLOBAL_AS(gB0 + kc),
                                     LDS_AS(u.s.Bs[buf][0] + 8 * t), 16, 0, 0);
    if (!isQ)
      __builtin_amdgcn_global_load_lds(GLOBAL_AS(gB1 + kc),
                                       LDS_AS(u.s.Bs[buf][1] + 8 * t), 16, 0,
                                       0);
  };

  f32x4 acc0[4][2] = {};  // K (or Q)
  f32x4 acc1[4][2] = {};  // V (KV blocks only)
  stage(0, 0);
  __syncthreads();
  for (int i = 0; i < 8; ++i) {
    const int cur = i & 1;
    if (i < 7) stage(cur ^ 1, (i + 1) * 32);
    short8 af[4], bfr0[2];
#pragma unroll
    for (int mi = 0; mi < 4; ++mi)
      af[mi] =
          *(const short8*)&u.s.As[cur][(mrow + mi * 16 + l16) * 32 + quad * 8];
#pragma unroll
    for (int nj = 0; nj < 2; ++nj)
      bfr0[nj] = *(const short8*)&u.s
                      .Bs[cur][0][(ncol + nj * 16 + l16) * 32 + quad * 8];
#pragma unroll
    for (int mi = 0; mi < 4; ++mi)
#pragma unroll
      for (int nj = 0; nj < 2; ++nj)
        acc0[mi][nj] = __builtin_amdgcn_mfma_f32_16x16x32_bf16(
            af[mi], bfr0[nj], acc0[mi][nj], 0, 0, 0);
    if (!isQ) {
      short8 bfr1[2];
#pragma unroll
      for (int nj = 0; nj < 2; ++nj)
        bfr1[nj] = *(const short8*)&u.s
                        .Bs[cur][1][(ncol + nj * 16 + l16) * 32 + quad * 8];
#pragma unroll
      for (int mi = 0; mi < 4; ++mi)
#pragma unroll
        for (int nj = 0; nj < 2; ++nj)
          acc1[mi][nj] = __builtin_amdgcn_mfma_f32_16x16x32_bf16(
              af[mi], bfr1[nj], acc1[mi][nj], 0, 0, 0);
    }
    __syncthreads();
  }

  if (isQ) {
#pragma unroll
    for (int nj = 0; nj < 2; ++nj) {
      const int n = n0 + ncol + nj * 16 + l16;
      const float bvv = bq[n];
#pragma unroll
      for (int mi = 0; mi < 4; ++mi)
#pragma unroll
        for (int r = 0; r < 4; ++r) {
          const size_t m = (size_t)row0 + mrow + mi * 16 + quad * 4 + r;
          Qh[m * 256 + n] = bf16_1((acc0[mi][nj][r] + bvv) * QSCALE);
        }
    }
  } else {
    // K epilogue (register-only, no LDS)
#pragma unroll
    for (int nj = 0; nj < 2; ++nj) {
      const int n = n0 + ncol + nj * 16 + l16;
      const float bvv = bk[n];
#pragma unroll
      for (int mi = 0; mi < 4; ++mi)
#pragma unroll
        for (int r = 0; r < 4; ++r) {
          const size_t m = (size_t)row0 + mrow + mi * 16 + quad * 4 + r;
          Kh[m * 256 + n] = bf16_1(acc0[mi][nj][r] + bvv);
        }
    }
    // V: bias + transpose via LDS (Ct overlays As/Bs, dead after barrier)
    __syncthreads();
#pragma unroll
    for (int nj = 0; nj < 2; ++nj) {
      const int nloc = ncol + nj * 16 + l16;
      const float bvv = bv[n0 + nloc];
#pragma unroll
      for (int mi = 0; mi < 4; ++mi)
#pragma unroll
        for (int r = 0; r < 4; ++r)
          u.Ct[nloc * 136 + mrow + mi * 16 + quad * 4 + r] =
              bf16_1(acc1[mi][nj][r] + bvv);
    }
    __syncthreads();
    const int bb = row0 >> 11, ns0 = row0 & 2047;
#pragma unroll
    for (int i = 0; i < 4; ++i) {
      const int c = t + i * 256;
      const int rr = c >> 4, c8 = (c & 15) << 3;
      *(float4*)&VhT[(size_t)(bb * 256 + n0 + rr) * 2048 + ns0 + c8] =
          *(const float4*)&u.Ct[rr * 136 + c8];
    }
  }
}

// ---------------- FFN1 GEMM: 128x64 tile, BK=32, double-buffered ----------
// Ch = bf16(gelu(v))
__global__ __launch_bounds__(256) void mgemm_kernel(
    const ushort* __restrict__ A, const ushort* __restrict__ Wt,
    const float* __restrict__ bias, ushort* __restrict__ Ch, int K, int N) {
  __shared__ ushort As[2][128 * 32];  // 16 KB
  __shared__ ushort Bs[2][64 * 32];   // 8 KB
  const int t = threadIdx.x;
  const int lane = t & 63, wave = t >> 6;
  const int l16 = lane & 15, quad = lane >> 4;
  const int row0 = blockIdx.x * 128;
  const int n0 = blockIdx.y << 6;
  const int mrow = (wave & 1) * 64, ncol = (wave >> 1) * 32;

  const ushort* gA0 = A + (size_t)(row0 + (t >> 2)) * K + ((t & 3) << 3);
  const ushort* gA1 = gA0 + (size_t)64 * K;
  const ushort* gB = Wt + (size_t)(n0 + (t >> 2)) * K + ((t & 3) << 3);

  auto stage = [&](int buf, int kc) {
    __builtin_amdgcn_global_load_lds(GLOBAL_AS(gA0 + kc),
                                     LDS_AS(As[buf] + 8 * t), 16, 0, 0);
    __builtin_amdgcn_global_load_lds(GLOBAL_AS(gA1 + kc),
                                     LDS_AS(As[buf] + 2048 + 8 * t), 16, 0, 0);
    __builtin_amdgcn_global_load_lds(GLOBAL_AS(gB + kc),
                                     LDS_AS(Bs[buf] + 8 * t), 16, 0, 0);
  };

  f32x4 acc[4][2] = {};
  const int nt = K >> 5;
  stage(0, 0);
  __syncthreads();
  for (int i = 0; i < nt; ++i) {
    const int cur = i & 1;
    if (i < nt - 1) stage(cur ^ 1, (i + 1) * 32);
    short8 af[4], bfr[2];
#pragma unroll
    for (int mi = 0; mi < 4; ++mi)
      af[mi] = *(const short8*)&As[cur][(mrow + mi * 16 + l16) * 32 + quad * 8];
#pragma unroll
    for (int nj = 0; nj < 2; ++nj)
      bfr[nj] =
          *(const short8*)&Bs[cur][(ncol + nj * 16 + l16) * 32 + quad * 8];
#pragma unroll
    for (int mi = 0; mi < 4; ++mi)
#pragma unroll
      for (int nj = 0; nj < 2; ++nj)
        acc[mi][nj] = __builtin_amdgcn_mfma_f32_16x16x32_bf16(
            af[mi], bfr[nj], acc[mi][nj], 0, 0, 0);
    __syncthreads();
  }
#pragma unroll
  for (int nj = 0; nj < 2; ++nj) {
    const int n = n0 + ncol + nj * 16 + l16;
    const float bvv = bias[n];
#pragma unroll
    for (int mi = 0; mi < 4; ++mi) {
#pragma unroll
      for (int r = 0; r < 4; ++r) {
        const size_t m = (size_t)row0 + mrow + mi * 16 + quad * 4 + r;
        float v = acc[mi][nj][r] + bvv;
        v = 0.5f * v * (1.0f + erff(v * 0.70710678118654752f));
        Ch[m * N + n] = bf16_1(v);
      }
    }
  }
}

// ---------------- FFN2 GEMM: 64x64 tile, BK=32, double-buffered ------------
// Cf = v + res.  grid (256, 4).
__global__ __launch_bounds__(256) void mgemm64_kernel(
    const ushort* __restrict__ A, const ushort* __restrict__ Wt,
    const float* __restrict__ bias, const float* __restrict__ res,
    float* __restrict__ Cf, int K, int N) {
  __shared__ ushort As[2][64 * 32];  // 8 KB
  __shared__ ushort Bs[2][64 * 32];  // 8 KB
  const int t = threadIdx.x;
  const int lane = t & 63, wave = t >> 6;
  const int l16 = lane & 15, quad = lane >> 4;
  const int row0 = blockIdx.x * 64;
  const int n0 = blockIdx.y << 6;
  const int mrow = (wave & 1) * 32, ncol = (wave >> 1) * 32;

  const ushort* gA = A + (size_t)(row0 + (t >> 2)) * K + ((t & 3) << 3);
  const ushort* gB = Wt + (size_t)(n0 + (t >> 2)) * K + ((t & 3) << 3);

  auto stage = [&](int buf, int kc) {
    __builtin_amdgcn_global_load_lds(GLOBAL_AS(gA + kc),
                                     LDS_AS(As[buf] + 8 * t), 16, 0, 0);
    __builtin_amdgcn_global_load_lds(GLOBAL_AS(gB + kc),
                                     LDS_AS(Bs[buf] + 8 * t), 16, 0, 0);
  };

  f32x4 acc[2][2] = {};
  const int nt = K >> 5;
  stage(0, 0);
  __syncthreads();
  for (int i = 0; i < nt; ++i) {
    const int cur = i & 1;
    if (i < nt - 1) stage(cur ^ 1, (i + 1) * 32);
    short8 af[2], bfr[2];
#pragma unroll
    for (int mi = 0; mi < 2; ++mi)
      af[mi] = *(const short8*)&As[cur][(mrow + mi * 16 + l16) * 32 + quad * 8];
#pragma unroll
    for (int nj = 0; nj < 2; ++nj)
      bfr[nj] =
          *(const short8*)&Bs[cur][(ncol + nj * 16 + l16) * 32 + quad * 8];
#pragma unroll
    for (int mi = 0; mi < 2; ++mi)
#pragma unroll
      for (int nj = 0; nj < 2; ++nj)
        acc[mi][nj] = __builtin_amdgcn_mfma_f32_16x16x32_bf16(
            af[mi], bfr[nj], acc[mi][nj], 0, 0, 0);
    __syncthreads();
  }
#pragma unroll
  for (int nj = 0; nj < 2; ++nj) {
    const int n = n0 + ncol + nj * 16 + l16;
    const float bvv = bias[n];
#pragma unroll
    for (int mi = 0; mi < 2; ++mi) {
#pragma unroll
      for (int r = 0; r < 4; ++r) {
        const size_t m = (size_t)row0 + mrow + mi * 16 + quad * 4 + r;
        Cf[m * N + n] = acc[mi][nj][r] + bvv + res[m * N + n];
      }
    }
  }
}

// ---------------- Flash attention (bf16 MFMA, zero-max, 128q, KVBLK=128) ----
// O = Q + softmax(Q K^T / 16) V.  Qh pre-scaled by log2(e)/16 (bf16); residual
// recovered as Qh/QSCALE. No max shift (p = exp2(S*log2e), ratio-invariant);
// l via ones-MFMA.  Round-7 verified (64.5us): 128q, 4 waves, 2 q-groups/wave,
// KVBLK=128 (one barrier per 128 keys), T5 setprio on PV clusters.
// Ledger: VGPR in (64,128] pins 16 waves/CU (m69 granule); occupancy levers
// exhausted (r2,r4,r5); barrier halving ~1us (r7). Trans-pipe (exp2) demand
// at VALUBusy~61% is the structural floor of this formulation.
// K rows staged with bits 2<=>3 swapped so P routing is permlane32-only.
__global__ __launch_bounds__(256) void attn_kernel(
    const ushort* __restrict__ Qh, const ushort* __restrict__ Kh,
    const ushort* __restrict__ VhT, float* __restrict__ O) {
  __shared__ ushort Ks[2][128][40];  // 20480 B
  __shared__ ushort Vt[2][32][136];  // 17408 B (total 37888)

  const int t = threadIdx.x;
  const int lane = t & 63, wave = t >> 6;
  const int l16 = lane & 15, quad = lane >> 4;
  const int bh = blockIdx.x & 63;
  const int qt = blockIdx.x >> 6;  // 0..15
  const int b = bh >> 3, h = bh & 7;

  const size_t rowQ0 = (size_t)(b * NSEQ + qt * 128 + wave * 32 + l16);
  const short8 qfrag0 = *(const short8*)&Qh[rowQ0 * 256 + h * HDIM + quad * 8];
  const short8 qfrag1 =
      *(const short8*)&Qh[(rowQ0 + 16) * 256 + h * HDIM + quad * 8];
  const short8 ones = {16256, 16256, 16256, 16256,
                       16256, 16256, 16256, 16256};  // bf16 1.0 x8
  const f32x4 zf = {0.f, 0.f, 0.f, 0.f};

  f32x4 o00 = zf, o01 = zf, o10 = zf, o11 = zf;
  f32x4 s0 = zf, s1 = zf;

  // staging coords (cooperative, coalesced): K tile [128][32], V tile [32][128]
  // K rows land permuted: LDS row p holds logical key with bits 2<=>3 swapped
  // (self-inverse; commutes with +64), making the post-QK^T shuffle
  // permlane32-only.
  const int kr = t >> 2, kc8 = (t & 3) << 3;
  const int krL = (kr & ~12) | ((kr & 4) << 1) | ((kr & 8) >> 1);
  const int vd = t >> 3, vc8 = (t & 7) << 3;
  const ushort* gK = Kh + ((size_t)(b * NSEQ + krL)) * 256 + h * HDIM + kc8;
  const ushort* gK2 = gK + (size_t)64 * 256;
  const ushort* gV = VhT + ((size_t)(bh * 32 + vd)) * 2048 + vc8;

  float4 kreg0 = *(const float4*)gK;
  float4 kreg1 = *(const float4*)gK2;
  float4 vreg0 = *(const float4*)gV;
  float4 vreg1 = *(const float4*)(gV + 64);

  for (int kt = 0; kt < 16; ++kt) {
    const int bf = kt & 1;
    *(float4*)&Ks[bf][kr][kc8] = kreg0;
    *(float4*)&Ks[bf][64 + kr][kc8] = kreg1;
    *(float4*)&Vt[bf][vd][vc8] = vreg0;
    *(float4*)&Vt[bf][vd][64 + vc8] = vreg1;
    __syncthreads();  // buf visible; prev readers done (prev barrier)
    if (kt < 15) {    // register prefetch, in flight over compute
      const size_t ko = (size_t)(kt + 1) * 128 * 256;
      kreg0 = *(const float4*)(gK + ko);
      kreg1 = *(const float4*)(gK2 + ko);
      vreg0 = *(const float4*)(gV + (kt + 1) * 128);
      vreg1 = *(const float4*)(gV + (kt + 1) * 128 + 64);
    }

#pragma unroll
    for (int half = 0; half < 2; ++half) {
      const int r0 = half * 64;   // key-row base in Ks
      const int c0 = half * 64;   // key-col base in Vt

      // shared fragments for both q-groups (wave-independent LDS reads)
      short8 kf[4];
#pragma unroll
      for (int sub = 0; sub < 4; ++sub)
        kf[sub] = *(const short8*)&Ks[bf][r0 + sub * 16 + l16][quad * 8];
      const short8 vf00 = *(const short8*)&Vt[bf][l16][c0 + quad * 8];
      const short8 vf01 = *(const short8*)&Vt[bf][l16][c0 + 32 + quad * 8];
      const short8 vf10 = *(const short8*)&Vt[bf][16 + l16][c0 + quad * 8];
      const short8 vf11 = *(const short8*)&Vt[bf][16 + l16][c0 + 32 + quad * 8];

      // ---- S-MFMAs for BOTH groups (MFMA latency overlaps exp2 below) ----
      f32x4 sa0[4], sa1[4];
#pragma unroll
      for (int sub = 0; sub < 4; ++sub)
        sa0[sub] = __builtin_amdgcn_mfma_f32_16x16x32_bf16(kf[sub], qfrag0, zf,
                                                           0, 0, 0);
#pragma unroll
      for (int sub = 0; sub < 4; ++sub)
        sa1[sub] = __builtin_amdgcn_mfma_f32_16x16x32_bf16(kf[sub], qfrag1, zf,
                                                           0, 0, 0);

      // ---- exp2 + pack + in-register route (permlane32 swap) ----
      unsigned p0[4][2], p1[4][2];
#pragma unroll
      for (int sub = 0; sub < 4; ++sub) {
        p0[sub][0] = pack_bf16_perm(__builtin_amdgcn_exp2f(sa0[sub][0]),
                                    __builtin_amdgcn_exp2f(sa0[sub][1]));
        p0[sub][1] = pack_bf16_perm(__builtin_amdgcn_exp2f(sa0[sub][2]),
                                    __builtin_amdgcn_exp2f(sa0[sub][3]));
      }
#pragma unroll
      for (int sub = 0; sub < 4; ++sub) {
        p1[sub][0] = pack_bf16_perm(__builtin_amdgcn_exp2f(sa1[sub][0]),
                                    __builtin_amdgcn_exp2f(sa1[sub][1]));
        p1[sub][1] = pack_bf16_perm(__builtin_amdgcn_exp2f(sa1[sub][2]),
                                    __builtin_amdgcn_exp2f(sa1[sub][3]));
      }
      unsigned u00 = p0[0][0], w00 = p0[1][0];
      asm("v_permlane32_swap_b32 %0, %1" : "+v"(u00), "+v"(w00));
      unsigned u01 = p0[0][1], w01 = p0[1][1];
      asm("v_permlane32_swap_b32 %0, %1" : "+v"(u01), "+v"(w01));
      unsigned u02 = p0[2][0], w02 = p0[3][0];
      asm("v_permlane32_swap_b32 %0, %1" : "+v"(u02), "+v"(w02));
      unsigned u03 = p0[2][1], w03 = p0[3][1];
      asm("v_permlane32_swap_b32 %0, %1" : "+v"(u03), "+v"(w03));
      const short8 pf00 = frag4(u00, u01, w00, w01);
      const short8 pf01 = frag4(u02, u03, w02, w03);

      unsigned u10 = p1[0][0], w10 = p1[1][0];
      asm("v_permlane32_swap_b32 %0, %1" : "+v"(u10), "+v"(w10));
      unsigned u11 = p1[0][1], w11 = p1[1][1];
      asm("v_permlane32_swap_b32 %0, %1" : "+v"(u11), "+v"(w11));
      unsigned u12 = p1[2][0], w12 = p1[3][0];
      asm("v_permlane32_swap_b32 %0, %1" : "+v"(u12), "+v"(w12));
      unsigned u13 = p1[2][1], w13 = p1[3][1];
      asm("v_permlane32_swap_b32 %0, %1" : "+v"(u13), "+v"(w13));
      const short8 pf10 = frag4(u10, u11, w10, w11);
      const short8 pf11 = frag4(u12, u13, w12, w13);

      // ---- PV + row-sum MFMAs, both groups (pure-MFMA cluster; T5) ----
      __builtin_amdgcn_s_setprio(1);
      o00 = __builtin_amdgcn_mfma_f32_16x16x32_bf16(pf00, vf00, o00, 0, 0, 0);
      o00 = __builtin_amdgcn_mfma_f32_16x16x32_bf16(pf01, vf01, o00, 0, 0, 0);
      o01 = __builtin_amdgcn_mfma_f32_16x16x32_bf16(pf00, vf10, o01, 0, 0, 0);
      o01 = __builtin_amdgcn_mfma_f32_16x16x32_bf16(pf01, vf11, o01, 0, 0, 0);
      o10 = __builtin_amdgcn_mfma_f32_16x16x32_bf16(pf10, vf00, o10, 0, 0, 0);
      o10 = __builtin_amdgcn_mfma_f32_16x16x32_bf16(pf11, vf01, o10, 0, 0, 0);
      o11 = __builtin_amdgcn_mfma_f32_16x16x32_bf16(pf10, vf10, o11, 0, 0, 0);
      o11 = __builtin_amdgcn_mfma_f32_16x16x32_bf16(pf11, vf11, o11, 0, 0, 0);
      s0 = __builtin_amdgcn_mfma_f32_16x16x32_bf16(pf00, ones, s0, 0, 0, 0);
      s0 = __builtin_amdgcn_mfma_f32_16x16x32_bf16(pf01, ones, s0, 0, 0, 0);
      s1 = __builtin_amdgcn_mfma_f32_16x16x32_bf16(pf10, ones, s1, 0, 0, 0);
      s1 = __builtin_amdgcn_mfma_f32_16x16x32_bf16(pf11, ones, s1, 0, 0, 0);
      __builtin_amdgcn_s_setprio(0);
    }
  }

  // ---- epilogue: O = Q + oacc/l ; Q re-read directly (L2-hot) ----
#pragma unroll
  for (int g = 0; g < 2; ++g) {
    const f32x4 oS = g ? s1 : s0;
    const f32x4 oa = g ? o10 : o00;
    const f32x4 ob = g ? o11 : o01;
    const size_t row0 =
        (size_t)(b * NSEQ + qt * 128 + wave * 32 + g * 16 + quad * 4);
#pragma unroll
    for (int r = 0; r < 4; ++r) {
      const float il = 1.0f / oS[r];
      const size_t ro = (row0 + r) * 256 + h * HDIM + l16;
      O[ro] = bf16_to_f(Qh[ro]) * QINV + oa[r] * il;
      O[ro + 16] = bf16_to_f(Qh[ro + 16]) * QINV + ob[r] * il;
    }
  }
}

extern "C" void kernel_launch(void* const* d_in, const int* in_sizes, int n_in,
                              void* d_out, int out_size, void* d_ws, size_t ws_size,
                              hipStream_t stream) {
  const float* x = (const float*)d_in[0];
  const float* y = (const float*)d_in[1];
  const float* Wq = (const float*)d_in[2];
  const float* bq = (const float*)d_in[3];
  const float* Wk = (const float*)d_in[4];
  const float* bk = (const float*)d_in[5];
  const float* Wv = (const float*)d_in[6];
  const float* bv = (const float*)d_in[7];
  const float* W1 = (const float*)d_in[8];
  const float* b1 = (const float*)d_in[9];
  const float* W2 = (const float*)d_in[10];
  const float* b2 = (const float*)d_in[11];
  const float* ln0g = (const float*)d_in[12];
  const float* ln0b = (const float*)d_in[13];
  const float* ln1g = (const float*)d_in[14];
  const float* ln1b = (const float*)d_in[15];
  float* out = (float*)d_out;
  char* base = (char*)d_ws;

  const size_t RM = (size_t)RTOT * 256;
  // region0: yh (bf16, stage0->qkv) then overwritten by Ob (fp32, attn out)
  ushort* yh = (ushort*)base;
  float* Ob = (float*)base;
  ushort* Qh = (ushort*)(base + 2 * RM * 4);
  ushort* Kh = (ushort*)(base + 2 * RM * 4 + RM * 2);
  ushort* VhT = (ushort*)(base + 3 * RM * 4);
  ushort* xh = (ushort*)(base + 3 * RM * 4 + RM * 2);  // LN0 out; reused as On
  ushort* Onh = xh;
  ushort* Hidh = Qh;  // [R,512] bf16 overlays Qh+Kh (dead after attn)
  char* wbase = base + 4 * RM * 4;
  ushort* Wqt = (ushort*)wbase;  // [256,256]
  ushort* Wkt = Wqt + 65536;
  ushort* Wvt = Wkt + 65536;
  ushort* W1t = Wvt + 65536;   // [512,256]
  ushort* W2t = W1t + 131072;  // [256,512]

  stage0_kernel<<<8304, 256, 0, stream>>>(x, y, Wq, Wk, Wv, W1, W2, ln0g, ln0b,
                                          Wqt, Wkt, Wvt, W1t, W2t, yh, xh);
  qkv_kernel<<<dim3(128, 8), 256, 0, stream>>>(xh, yh, Wqt, Wkt, Wvt, bq, bk,
                                               bv, Qh, Kh, VhT);
  attn_kernel<<<1024, 256, 0, stream>>>(Qh, Kh, VhT, Ob);
  ln_kernel<<<RTOT / 4, 256, 0, stream>>>(Ob, ln1g, ln1b, Onh);
  mgemm_kernel<<<dim3(128, 8), 256, 0, stream>>>(Onh, W1t, b1, Hidh, 256, 512);
  mgemm64_kernel<<<dim3(256, 4), 256, 0, stream>>>(Hidh, W2t, b2, Ob, out, 512,
                                                   256);
}